// Round 10
// baseline (4244.644 us; speedup 1.0000x reference)
//
#include <hip/hip_runtime.h>
#include <hip/hip_cooperative_groups.h>
#include <stdint.h>

namespace cg = cooperative_groups;

#define NB 512
#define NT 20
#define NH 256
#define NO 128
#define MUO_OFF (2*NB*NT*NO)
#define VARO_OFF (MUO_OFF + NB*NT*NH)

// ===== LEDGER =====
//  R6 6587us f32-serial -> R7 1557us f32-tiled -> R8 FAIL bf16 drift ->
//  R9 PASS 1627us absmax 0.0625 (split-bf16 MFMA) — launch-bound: ~1-2us kernels,
//  13.8us/launch wall, 118 serial launches. BN-over-batch forces 5 syncs/step.
//  R10 (this): ONE cooperative kernel, 256 blk x 256 thr, grid.sync between
//  phases (~97 syncs). Same arithmetic as R9. Predict 350-700us, absmax 0.0625.
//  Fallback if capture rejects cooperative: hand-rolled device barrier.
// ==================

typedef __attribute__((ext_vector_type(8))) short short8v;
typedef __attribute__((ext_vector_type(4))) float f32x4;
typedef unsigned short ushort_t;

// ws float offsets
#define O_PS   0
#define O_A1   (O_PS + NB*NH)
#define O_A2   (O_A1 + 512*512)
#define O_E1   (O_A2 + 512*512)
#define O_P1   (O_E1 + 512*512)
#define O_P2   (O_P1 + 512*32*2)
#define O_PSD  (O_P2 + 512*32*2)
#define O_PE   (O_PSD + 256*32*2)
#define O_PIS  (O_PE + 512*32*2)
#define O_USH  (O_PIS + NT*NB)
// ushort offsets within U
#define U_WT1H 0
#define U_WT1L 131072
#define U_WT2H 262144
#define U_WT2L 557056
#define U_WMSH 851968
#define U_WMSL 1114112
#define U_WE1H 1376256
#define U_WE1L 1507328
#define U_WESH 1638400
#define U_WESL 1769472
#define U_HHI  1900544
#define U_HLO  2031616

// shared scratch layout (bytes)
#define SM_ALO   18688           // Ahi: 16*584*2 = 18688
#define SM_SCSH  37376           // Alo ends at 37376
#define SM_EXTRA 41472           // scsh: 512*8 = 4096
#define SM_BYTES 45568           // extra: mean/std 2*2048

struct Params {
  const float *x, *s, *h_gru, *mu0, *var0, *h0;
  const float *tb1, *tg1, *tbe1, *tb2, *tg2, *tbe2;
  const float *tbm, *tbs, *tgs, *tbes;
  const float *eb1, *eg1, *ebe1, *ebm, *ebs;
  const float *tW1, *tW2, *tWm, *tWs, *eW1, *eWm, *eWs;
  float* out;
  float *psf, *a1f, *a2f, *e1f, *part1, *part2, *partS, *partE;
  int* pisA;
  ushort_t* U;
};

__device__ __forceinline__ void tf2x32(uint32_t k0, uint32_t k1,
                                       uint32_t x0, uint32_t x1,
                                       uint32_t& o0, uint32_t& o1)
{
  uint32_t k2 = k0 ^ k1 ^ 0x1BD11BDAu;
  x0 += k0; x1 += k1;
#define TF_R(r) x0 += x1; x1 = (x1 << (r)) | (x1 >> (32 - (r))); x1 ^= x0;
  TF_R(13) TF_R(15) TF_R(26) TF_R(6)
  x0 += k1; x1 += k2 + 1u;
  TF_R(17) TF_R(29) TF_R(16) TF_R(24)
  x0 += k2; x1 += k0 + 2u;
  TF_R(13) TF_R(15) TF_R(26) TF_R(6)
  x0 += k0; x1 += k1 + 3u;
  TF_R(17) TF_R(29) TF_R(16) TF_R(24)
  x0 += k1; x1 += k2 + 4u;
  TF_R(13) TF_R(15) TF_R(26) TF_R(6)
  x0 += k2; x1 += k0 + 5u;
#undef TF_R
  o0 = x0; o1 = x1;
}

__device__ __forceinline__ uint32_t rbits(uint32_t ka, uint32_t kb, uint32_t i)
{
  uint32_t o0, o1;
  tf2x32(ka, kb, 0u, i, o0, o1);
  return o0 ^ o1;
}

__device__ __forceinline__ float erfinv_xla(float x)
{
  float w = -log1pf(-__fmul_rn(x, x));
  float p;
  if (w < 5.0f) {
    w = __fsub_rn(w, 2.5f);
    p = 2.81022636e-08f;
    p = __fadd_rn( 3.43273939e-07f, __fmul_rn(p, w));
    p = __fadd_rn(-3.5233877e-06f,  __fmul_rn(p, w));
    p = __fadd_rn(-4.39150654e-06f, __fmul_rn(p, w));
    p = __fadd_rn( 0.00021858087f,  __fmul_rn(p, w));
    p = __fadd_rn(-0.00125372503f,  __fmul_rn(p, w));
    p = __fadd_rn(-0.00417768164f,  __fmul_rn(p, w));
    p = __fadd_rn( 0.246640727f,    __fmul_rn(p, w));
    p = __fadd_rn( 1.50140941f,     __fmul_rn(p, w));
  } else {
    w = __fsub_rn(sqrtf(w), 3.0f);
    p = -0.000200214257f;
    p = __fadd_rn( 0.000100950558f, __fmul_rn(p, w));
    p = __fadd_rn( 0.00134934322f,  __fmul_rn(p, w));
    p = __fadd_rn(-0.00367342844f,  __fmul_rn(p, w));
    p = __fadd_rn( 0.00573950773f,  __fmul_rn(p, w));
    p = __fadd_rn(-0.0076224613f,   __fmul_rn(p, w));
    p = __fadd_rn( 0.00943887047f,  __fmul_rn(p, w));
    p = __fadd_rn( 1.00167406f,     __fmul_rn(p, w));
    p = __fadd_rn( 2.83297682f,     __fmul_rn(p, w));
  }
  return __fmul_rn(p, x);
}

__device__ __forceinline__ float jax_normal(uint32_t bits)
{
  float f = __fsub_rn(__uint_as_float((bits >> 9) | 0x3F800000u), 1.0f);
  const float lo = -0.99999994f;
  float u = __fadd_rn(__fmul_rn(f, 2.0f), lo);
  u = fmaxf(lo, u);
  return __fmul_rn(1.41421356f, erfinv_xla(u));
}

__device__ __forceinline__ ushort_t f2bf(float x)
{
  uint32_t u = __float_as_uint(x);
  return (ushort_t)((u + 0x7FFFu + ((u >> 16) & 1u)) >> 16);
}

__device__ __forceinline__ void bfsplit(float x, ushort_t& hi, ushort_t& lo)
{
  uint32_t u = __float_as_uint(x);
  hi = (ushort_t)(u >> 16);
  float r = x - __uint_as_float(u & 0xFFFF0000u);
  lo = f2bf(r);
}

// ---- phase: G1/G4 (hstate pre-split in global, K=256, relu epi + partials) ----
__device__ __forceinline__ void ph_mfh(
    const ushort_t* __restrict__ Ahi_g, const ushort_t* __restrict__ Alo_g,
    const ushort_t* __restrict__ Whi, const ushort_t* __restrict__ Wlo,
    const float* __restrict__ b0,
    float* __restrict__ Of32, float* __restrict__ partOut, int task)
{
  const int tid = threadIdx.x;
  const int w = tid >> 6, l = tid & 63;
  const int mt = task >> 3, M0 = mt * 16;
  const int N0 = (task & 7) * 64 + w * 16;
  const int lm = l & 15, lk = l >> 4;

  const ushort_t* ah_r = Ahi_g + (M0 + lm) * 256;
  const ushort_t* al_r = Alo_g + (M0 + lm) * 256;
  const ushort_t* wh_r = Whi + (N0 + lm) * 256;
  const ushort_t* wl_r = Wlo + (N0 + lm) * 256;
  f32x4 acc = {0.0f, 0.0f, 0.0f, 0.0f};
  #pragma unroll
  for (int ks = 0; ks < 8; ++ks) {
    const int kb = ks * 32 + lk * 8;
    short8v ah = *reinterpret_cast<const short8v*>(ah_r + kb);
    short8v al = *reinterpret_cast<const short8v*>(al_r + kb);
    short8v wh = *reinterpret_cast<const short8v*>(wh_r + kb);
    short8v wl = *reinterpret_cast<const short8v*>(wl_r + kb);
    acc = __builtin_amdgcn_mfma_f32_16x16x32_bf16(ah, wh, acc, 0, 0, 0);
    acc = __builtin_amdgcn_mfma_f32_16x16x32_bf16(ah, wl, acc, 0, 0, 0);
    acc = __builtin_amdgcn_mfma_f32_16x16x32_bf16(al, wh, acc, 0, 0, 0);
  }

  const int n = N0 + lm;
  float bias = b0[n];
  float s = 0.0f, q = 0.0f;
  #pragma unroll
  for (int j = 0; j < 4; ++j) {
    float xv = fmaxf(acc[j] + bias, 0.0f);
    s += xv; q += xv * xv;
    Of32[(M0 + lk * 4 + j) * 512 + n] = xv;
  }
  s += __shfl_xor(s, 16); s += __shfl_xor(s, 32);
  q += __shfl_xor(q, 16); q += __shfl_xor(q, 32);
  if (l < 16) ((float2*)partOut)[n * 32 + mt] = make_float2(s, q);
}

// ---- phase: G2/G3 (f32 A staged+BN+split into LDS; split-bf16 MFMA) ----
template<int K, int CONC, int EPI>
__device__ __forceinline__ void ph_mfs(
    const float* __restrict__ Af, const float* __restrict__ Sf,
    const float* __restrict__ partIn, const float* __restrict__ g,
    const float* __restrict__ be,
    const ushort_t* __restrict__ Whi, const ushort_t* __restrict__ Wlo,
    const float* __restrict__ b0, const float* __restrict__ b1,
    float* __restrict__ Of32, float* __restrict__ partOut,
    float* __restrict__ ps, float* __restrict__ outp, int t,
    int task, char* smem)
{
  constexpr int KP = K + 8;
  const int tid = threadIdx.x;
  const int w = tid >> 6, l = tid & 63;
  const int mt = task >> 3, M0 = mt * 16;
  const int N0 = (task & 7) * 64 + w * 16;
  const int lm = l & 15, lk = l >> 4;

  ushort_t (*Ahi)[KP] = (ushort_t(*)[KP])smem;
  ushort_t (*Alo)[KP] = (ushort_t(*)[KP])(smem + SM_ALO);
  float2* scsh = (float2*)(smem + SM_SCSH);

  for (int c = tid; c < 512; c += 256) {
    const float2* pp = (const float2*)partIn + c * 32;
    float s = 0.0f, q = 0.0f;
    #pragma unroll
    for (int m = 0; m < 32; ++m) { float2 v = pp[m]; s += v.x; q += v.y; }
    float mn  = s * (1.0f / 512.0f);
    float var = q * (1.0f / 512.0f) - mn * mn;
    float inv = 1.0f / sqrtf(var + 1e-5f);
    float sc  = inv * g[c];
    scsh[c] = make_float2(sc, be[c] - mn * sc);
  }
  __syncthreads();

  for (int r = 0; r < 16; ++r) {
    for (int c = tid; c < K; c += 256) {
      float v;
      if constexpr (CONC) {
        if (c < 512) { float2 ss = scsh[c];
          v = __builtin_fmaf(Af[(M0 + r) * 512 + c], ss.x, ss.y); }
        else v = Sf[(M0 + r) * 64 + (c - 512)];
      } else {
        float2 ss = scsh[c];
        v = __builtin_fmaf(Af[(M0 + r) * K + c], ss.x, ss.y);
      }
      ushort_t hi, lo;
      bfsplit(v, hi, lo);
      Ahi[r][c] = hi; Alo[r][c] = lo;
    }
  }
  __syncthreads();

  const ushort_t* bhrow = Whi + (N0 + lm) * K;
  const ushort_t* blrow = Wlo + (N0 + lm) * K;
  f32x4 acc = {0.0f, 0.0f, 0.0f, 0.0f};
  #pragma unroll
  for (int ks = 0; ks < K / 32; ++ks) {
    const int kb = ks * 32 + lk * 8;
    short8v ah = *reinterpret_cast<const short8v*>(&Ahi[lm][kb]);
    short8v al = *reinterpret_cast<const short8v*>(&Alo[lm][kb]);
    short8v wh = *reinterpret_cast<const short8v*>(bhrow + kb);
    short8v wl = *reinterpret_cast<const short8v*>(blrow + kb);
    acc = __builtin_amdgcn_mfma_f32_16x16x32_bf16(ah, wh, acc, 0, 0, 0);
    acc = __builtin_amdgcn_mfma_f32_16x16x32_bf16(ah, wl, acc, 0, 0, 0);
    acc = __builtin_amdgcn_mfma_f32_16x16x32_bf16(al, wh, acc, 0, 0, 0);
  }

  const int n = N0 + lm;
  if constexpr (EPI == 0) {
    float bias = b0[n];
    float s = 0.0f, q = 0.0f;
    #pragma unroll
    for (int j = 0; j < 4; ++j) {
      float xv = fmaxf(acc[j] + bias, 0.0f);
      s += xv; q += xv * xv;
      Of32[(M0 + lk * 4 + j) * 512 + n] = xv;
    }
    s += __shfl_xor(s, 16); s += __shfl_xor(s, 32);
    q += __shfl_xor(q, 16); q += __shfl_xor(q, 32);
    if (l < 16) ((float2*)partOut)[n * 32 + mt] = make_float2(s, q);
  } else {
    if (N0 < 256) {
      float bias = b0[n];
      #pragma unroll
      for (int j = 0; j < 4; ++j) {
        float xv = acc[j] + bias;
        int m = M0 + lk * 4 + j;
        outp[MUO_OFF + (m * NT + t) * NH + n] = xv;
      }
    } else {
      float bias = b1[n - 256];
      float s = 0.0f, q = 0.0f;
      #pragma unroll
      for (int j = 0; j < 4; ++j) {
        float xv = acc[j] + bias;
        xv = (xv > 0.0f ? xv : expm1f(xv)) + 1.0f + 1e-12f;
        s += xv; q += xv * xv;
        ps[(M0 + lk * 4 + j) * NH + (n - 256)] = xv;
      }
      s += __shfl_xor(s, 16); s += __shfl_xor(s, 32);
      q += __shfl_xor(q, 16); q += __shfl_xor(q, 32);
      if (l < 16) ((float2*)partOut)[(n - 256) * 32 + mt] = make_float2(s, q);
    }
  }
}

// ---- phase: sdht (per batch row) ----
__device__ __forceinline__ void ph_sdht(
    const float* __restrict__ partS, const float* __restrict__ psv,
    const float* __restrict__ gs, const float* __restrict__ bes,
    const int* __restrict__ pisA,
    ushort_t* __restrict__ hhi, ushort_t* __restrict__ hlo,
    uint32_t k2a, uint32_t k2b, float* __restrict__ outp, int t, int b)
{
  int c = threadIdx.x;
  const float2* pp = (const float2*)partS + c * 32;
  float s = 0.0f, q = 0.0f;
  #pragma unroll
  for (int m = 0; m < 32; ++m) { float2 v = pp[m]; s += v.x; q += v.y; }
  float mn  = s * (1.0f / 512.0f);
  float var = q * (1.0f / 512.0f) - mn * mn;
  float inv = 1.0f / sqrtf(var + 1e-5f);
  float sc  = inv * gs[c];
  float sh  = bes[c] - mn * sc;
  float v = psv[b * NH + c] * sc + sh;
  outp[VARO_OFF + (b * NT + t) * NH + c] = v;
  int p = pisA[t * NB + b];
  float mu = outp[MUO_OFF + (b * NT + p + 1) * NH + c];
  float sd = (p == t - 1) ? v : outp[VARO_OFF + (b * NT + p + 1) * NH + c];
  float z = jax_normal(rbits(k2a, k2b, (uint32_t)(b * NH + c)));
  float ht = __fadd_rn(mu, __fmul_rn(sd, z));
  ushort_t hi, lo;
  bfsplit(ht, hi, lo);
  hhi[b * NH + c] = hi; hlo[b * NH + c] = lo;
}

// ---- phase: G5 emission heads + sample (128 tasks) ----
__device__ __forceinline__ void ph_g5(
    const float* __restrict__ Ef, const ushort_t* __restrict__ Whi,
    const ushort_t* __restrict__ Wlo,
    const float* __restrict__ partIn, const float* __restrict__ g,
    const float* __restrict__ be,
    const float* __restrict__ bm, const float* __restrict__ bs,
    uint32_t k3a, uint32_t k3b, float* __restrict__ outp, int t,
    int task, char* smem)
{
  constexpr int K = 512, KP = 520;
  const int tid = threadIdx.x;
  const int w = tid >> 6, l = tid & 63;
  const int mt = task >> 2, jg = task & 3;
  const int M0 = mt * 16;
  const int lm = l & 15, lk = l >> 4;
  const bool isStd = (w >= 2);
  const int jl0 = (w & 1) * 16;
  const int N0 = (isStd ? 128 : 0) + jg * 32 + jl0;

  ushort_t (*Ahi)[KP] = (ushort_t(*)[KP])smem;
  ushort_t (*Alo)[KP] = (ushort_t(*)[KP])(smem + SM_ALO);
  float2* scsh = (float2*)(smem + SM_SCSH);
  float (*mean_s)[32] = (float(*)[32])(smem + SM_EXTRA);
  float (*std_s)[32]  = (float(*)[32])(smem + SM_EXTRA + 2048);

  for (int c = tid; c < 512; c += 256) {
    const float2* pp = (const float2*)partIn + c * 32;
    float s = 0.0f, q = 0.0f;
    #pragma unroll
    for (int m = 0; m < 32; ++m) { float2 v = pp[m]; s += v.x; q += v.y; }
    float mn  = s * (1.0f / 512.0f);
    float var = q * (1.0f / 512.0f) - mn * mn;
    float inv = 1.0f / sqrtf(var + 1e-5f);
    float sc  = inv * g[c];
    scsh[c] = make_float2(sc, be[c] - mn * sc);
  }
  __syncthreads();

  for (int r = 0; r < 16; ++r) {
    for (int c = tid; c < K; c += 256) {
      float2 ss = scsh[c];
      float v = __builtin_fmaf(Ef[(M0 + r) * 512 + c], ss.x, ss.y);
      ushort_t hi, lo;
      bfsplit(v, hi, lo);
      Ahi[r][c] = hi; Alo[r][c] = lo;
    }
  }
  __syncthreads();

  const ushort_t* bhrow = Whi + (N0 + lm) * K;
  const ushort_t* blrow = Wlo + (N0 + lm) * K;
  f32x4 acc = {0.0f, 0.0f, 0.0f, 0.0f};
  #pragma unroll
  for (int ks = 0; ks < 16; ++ks) {
    const int kb = ks * 32 + lk * 8;
    short8v ah = *reinterpret_cast<const short8v*>(&Ahi[lm][kb]);
    short8v al = *reinterpret_cast<const short8v*>(&Alo[lm][kb]);
    short8v wh = *reinterpret_cast<const short8v*>(bhrow + kb);
    short8v wl = *reinterpret_cast<const short8v*>(blrow + kb);
    acc = __builtin_amdgcn_mfma_f32_16x16x32_bf16(ah, wh, acc, 0, 0, 0);
    acc = __builtin_amdgcn_mfma_f32_16x16x32_bf16(ah, wl, acc, 0, 0, 0);
    acc = __builtin_amdgcn_mfma_f32_16x16x32_bf16(al, wh, acc, 0, 0, 0);
  }

  const int n = N0 + lm;
  float bias = isStd ? bs[n - 128] : bm[n];
  #pragma unroll
  for (int j = 0; j < 4; ++j) {
    float xv = acc[j] + bias;
    if (isStd) xv = (xv > 0.0f ? xv : expm1f(xv)) + 1.0f + 1e-12f;
    int r = lk * 4 + j, jl = jl0 + lm;
    if (isStd) std_s[r][jl] = xv; else mean_s[r][jl] = xv;
  }
  __syncthreads();

  for (int e = tid; e < 512; e += 256) {
    int r = e >> 5, jl = e & 31;
    int bb = M0 + r, j = jg * 32 + jl;
    float z = jax_normal(rbits(k3a, k3b, (uint32_t)(bb * NO + j)));
    outp[(bb * NT + t) * NO + j] = __fadd_rn(mean_s[r][jl], __fmul_rn(std_s[r][jl], z));
  }
}

// ---------------- the mega-kernel ----------------

__global__ __launch_bounds__(256) void k_mega(Params p)
{
  cg::grid_group grid = cg::this_grid();
  __shared__ __align__(16) char smem[SM_BYTES];
  const int tid = threadIdx.x;
  const int gtid = blockIdx.x * 256 + tid;
  const int gsz = gridDim.x * 256;
  ushort_t* hhi = p.U + U_HHI;
  ushort_t* hlo = p.U + U_HLO;

  // ---- init: x copy, h0, weight split, pis ----
  for (int i = gtid; i < NB * NT * NO; i += gsz) {
    float v = p.x[i];
    p.out[NB * NT * NO + i] = v;
    if ((i % (NT * NO)) < NO) p.out[i] = v;
  }
  for (int i = gtid; i < NB * NH; i += gsz) {
    int b = i >> 8, h = i & 255;
    p.out[MUO_OFF  + (b * NT) * NH + h] = p.mu0[h];
    p.out[VARO_OFF + (b * NT) * NH + h] = p.var0[h];
    ushort_t hi, lo;
    bfsplit(p.h0[h], hi, lo);
    hhi[i] = hi; hlo[i] = lo;
  }
  for (int i = gtid; i < 950272; i += gsz) {
    float v; int ho, lo_;
    if (i < 131072) { v = p.tW1[i]; ho = U_WT1H + i; lo_ = U_WT1L + i; }
    else if (i < 425984) { int j = i - 131072; v = p.tW2[j]; ho = U_WT2H + j; lo_ = U_WT2L + j; }
    else if (i < 688128) { int j = i - 425984; int n = j >> 9, k = j & 511;
      v = (n < 256) ? p.tWm[n * 512 + k] : p.tWs[(n - 256) * 512 + k];
      ho = U_WMSH + j; lo_ = U_WMSL + j; }
    else if (i < 819200) { int j = i - 688128; v = p.eW1[j]; ho = U_WE1H + j; lo_ = U_WE1L + j; }
    else { int j = i - 819200; int n = j >> 9, k = j & 511;
      v = (n < 128) ? p.eWm[n * 512 + k] : p.eWs[(n - 128) * 512 + k];
      ho = U_WESH + j; lo_ = U_WESL + j; }
    ushort_t h, l;
    bfsplit(v, h, l);
    p.U[ho] = h; p.U[lo_] = l;
  }
  {
    const int wid = tid >> 6, lane = tid & 63;
    for (int wt = blockIdx.x * 4 + wid; wt < 19 * NB; wt += gridDim.x * 4) {
      int t = wt / NB + 1;
      int b = wt - (t - 1) * NB;
      uint32_t kt0, kt1, k1a, k1b;
      tf2x32(0u, 42u, 0u, (uint32_t)t, kt0, kt1);
      tf2x32(kt0, kt1, 0u, 0u, k1a, k1b);
      float v = -__builtin_inff();
      int idx = 0x7FFFFFFF;
      if (lane < t) {
        const float* hq = p.h_gru + (b * NT + t) * NH;
        const float* hu = p.h_gru + (b * NT + lane) * NH;
        float d = 0.0f;
        for (int h = 0; h < NH; ++h) d += hq[h] * hu[h];
        float logit = d * 0.0625f;
        uint32_t bits = rbits(k1a, k1b, (uint32_t)(b * t + lane));
        float f = __fsub_rn(__uint_as_float((bits >> 9) | 0x3F800000u), 1.0f);
        const float tinyf = 1.1754943508222875e-38f;
        float u = fmaxf(tinyf, __fadd_rn(f, tinyf));
        float gmb = -logf(-logf(u));
        v = gmb + logit;
        idx = lane;
      }
      for (int off = 32; off; off >>= 1) {
        float ov = __shfl_xor(v, off);
        int oi = __shfl_xor(idx, off);
        if (ov > v || (ov == v && oi < idx)) { v = ov; idx = oi; }
      }
      if (lane == 0) p.pisA[t * NB + b] = idx;
    }
  }
  grid.sync();

  // ---- recurrence ----
  for (int t = 1; t < NT; ++t) {
    uint32_t kt0, kt1, k2a, k2b;
    tf2x32(0u, 42u, 0u, (uint32_t)t, kt0, kt1);
    tf2x32(kt0, kt1, 0u, 1u, k2a, k2b);

    // Phase A: G1(t) everywhere; G5(t-1) on blocks < 128
    for (int task = blockIdx.x; task < 256; task += gridDim.x)
      ph_mfh(hhi, hlo, p.U + U_WT1H, p.U + U_WT1L, p.tb1, p.a1f, p.part1, task);
    if (t > 1) {
      for (int task = blockIdx.x; task < 128; task += gridDim.x) {
        uint32_t pt0, pt1, k3a, k3b;
        tf2x32(0u, 42u, 0u, (uint32_t)(t - 1), pt0, pt1);
        tf2x32(pt0, pt1, 0u, 2u, k3a, k3b);
        ph_g5(p.e1f, p.U + U_WESH, p.U + U_WESL, p.partE, p.eg1, p.ebe1,
              p.ebm, p.ebs, k3a, k3b, p.out, t - 1, task, smem);
      }
    }
    grid.sync();

    // Phase B: G2
    for (int task = blockIdx.x; task < 256; task += gridDim.x)
      ph_mfs<576, 1, 0>(p.a1f, p.s, p.part1, p.tg1, p.tbe1,
                        p.U + U_WT2H, p.U + U_WT2L, p.tb2, nullptr,
                        p.a2f, p.part2, nullptr, nullptr, t, task, smem);
    grid.sync();

    // Phase C: G3 (mu -> out table; sd-raw -> ps)
    for (int task = blockIdx.x; task < 256; task += gridDim.x)
      ph_mfs<512, 0, 1>(p.a2f, nullptr, p.part2, p.tg2, p.tbe2,
                        p.U + U_WMSH, p.U + U_WMSL, p.tbm, p.tbs,
                        nullptr, p.partS, p.psf, p.out, t, task, smem);
    grid.sync();

    // Phase D: sd finalize + ht sample
    for (int b = blockIdx.x; b < NB; b += gridDim.x)
      ph_sdht(p.partS, p.psf, p.tgs, p.tbes, p.pisA, hhi, hlo,
              k2a, k2b, p.out, t, b);
    grid.sync();

    // Phase E: G4
    for (int task = blockIdx.x; task < 256; task += gridDim.x)
      ph_mfh(hhi, hlo, p.U + U_WE1H, p.U + U_WE1L, p.eb1, p.e1f, p.partE, task);
    grid.sync();
  }

  // tail: G5(19)
  for (int task = blockIdx.x; task < 128; task += gridDim.x) {
    uint32_t pt0, pt1, k3a, k3b;
    tf2x32(0u, 42u, 0u, 19u, pt0, pt1);
    tf2x32(pt0, pt1, 0u, 2u, k3a, k3b);
    ph_g5(p.e1f, p.U + U_WESH, p.U + U_WESL, p.partE, p.eg1, p.ebe1,
          p.ebm, p.ebs, k3a, k3b, p.out, 19, task, smem);
  }
}

// ---------------- host ----------------

extern "C" void kernel_launch(void* const* d_in, const int* in_sizes, int n_in,
                              void* d_out, int out_size, void* d_ws, size_t ws_size,
                              hipStream_t stream)
{
  Params P;
  P.x    = (const float*)d_in[0];
  P.s    = (const float*)d_in[1];
  P.h_gru= (const float*)d_in[2];
  P.mu0  = (const float*)d_in[3];
  P.var0 = (const float*)d_in[4];
  P.h0   = (const float*)d_in[5];
  P.tW1  = (const float*)d_in[6];
  P.tb1  = (const float*)d_in[7];
  P.tg1  = (const float*)d_in[8];
  P.tbe1 = (const float*)d_in[9];
  P.tW2  = (const float*)d_in[10];
  P.tb2  = (const float*)d_in[11];
  P.tg2  = (const float*)d_in[12];
  P.tbe2 = (const float*)d_in[13];
  P.tWm  = (const float*)d_in[14];
  P.tbm  = (const float*)d_in[15];
  P.tWs  = (const float*)d_in[16];
  P.tbs  = (const float*)d_in[17];
  P.tgs  = (const float*)d_in[18];
  P.tbes = (const float*)d_in[19];
  P.eW1  = (const float*)d_in[20];
  P.eb1  = (const float*)d_in[21];
  P.eg1  = (const float*)d_in[22];
  P.ebe1 = (const float*)d_in[23];
  P.eWm  = (const float*)d_in[24];
  P.ebm  = (const float*)d_in[25];
  P.eWs  = (const float*)d_in[26];
  P.ebs  = (const float*)d_in[27];

  float* ws = (float*)d_ws;
  P.out   = (float*)d_out;
  P.psf   = ws + O_PS;
  P.a1f   = ws + O_A1;
  P.a2f   = ws + O_A2;
  P.e1f   = ws + O_E1;
  P.part1 = ws + O_P1;
  P.part2 = ws + O_P2;
  P.partS = ws + O_PSD;
  P.partE = ws + O_PE;
  P.pisA  = (int*)(ws + O_PIS);
  P.U     = (ushort_t*)(ws + O_USH);

  void* kargs[] = { (void*)&P };
  hipLaunchCooperativeKernel((const void*)k_mega, dim3(256), dim3(256),
                             kargs, 0, stream);
}

// Round 12
// 1474.861 us; speedup vs baseline: 2.8780x; 2.8780x over previous
//
#include <hip/hip_runtime.h>
#include <stdint.h>

#define NB 512
#define NT 20
#define NH 256
#define NO 128
#define MUO_OFF (2*NB*NT*NO)
#define VARO_OFF (MUO_OFF + NB*NT*NH)

// ===== LEDGER =====
//  R6 6587 f32-serial; R7 1557 f32-tiled; R8 FAIL bf16 drift; R9 PASS 1627
//  absmax 0.0625 (split-bf16 MFMA, 6 launches/step); R10 cooperative FAIL-slow
//  4245us: grid.sync ~30-45us each (XCD L2 flush; FETCH 305MB/dispatch).
//  R11: 3-kernel/step schedule — container died (infra flake, no bench signal).
//  R12 (this): RESUBMIT of R11 unchanged. KA(t)=G3 | KB(t)=[ht+G1(t+1)]∥[ht+G4(t)]
//  | KC(t)=[G2(t+1)]∥[G5(t)]; ht recomputed in-consumer. 60 launches.
//  Predict: PASS, absmax 0.0625, 700-950us.
// ==================

typedef __attribute__((ext_vector_type(8))) short short8v;
typedef __attribute__((ext_vector_type(4))) float f32x4;
typedef unsigned short ushort_t;

// ws float offsets
#define O_PS   0
#define O_A1   (O_PS + NB*NH)
#define O_A2   (O_A1 + 512*512)
#define O_E1   (O_A2 + 512*512)
#define O_P1   (O_E1 + 512*512)
#define O_P2   (O_P1 + 512*32*2)
#define O_PSD  (O_P2 + 512*32*2)
#define O_PE   (O_PSD + 256*32*2)
#define O_PIS  (O_PE + 512*32*2)
#define O_USH  (O_PIS + NT*NB)
// ushort offsets within U (weight hi/lo splits)
#define U_WT1H 0
#define U_WT1L 131072
#define U_WT2H 262144
#define U_WT2L 557056
#define U_WMSH 851968
#define U_WMSL 1114112
#define U_WE1H 1376256
#define U_WE1L 1507328
#define U_WESH 1638400
#define U_WESL 1769472

// shared scratch layout (bytes) for K<=576 phases
#define SM_ALO   18688
#define SM_SCSH  37376
#define SM_EXTRA 41472
#define SM_BYTES 45568

struct Params {
  const float *x, *s, *h_gru, *mu0, *var0, *h0;
  const float *tb1, *tg1, *tbe1, *tb2, *tg2, *tbe2;
  const float *tbm, *tbs, *tgs, *tbes;
  const float *eb1, *eg1, *ebe1, *ebm, *ebs;
  const float *tW1, *tW2, *tWm, *tWs, *eW1, *eWm, *eWs;
  float* out;
  float *psf, *a1f, *a2f, *e1f, *part1, *part2, *partS, *partE;
  int* pisA;
  ushort_t* U;
};

__device__ __forceinline__ void tf2x32(uint32_t k0, uint32_t k1,
                                       uint32_t x0, uint32_t x1,
                                       uint32_t& o0, uint32_t& o1)
{
  uint32_t k2 = k0 ^ k1 ^ 0x1BD11BDAu;
  x0 += k0; x1 += k1;
#define TF_R(r) x0 += x1; x1 = (x1 << (r)) | (x1 >> (32 - (r))); x1 ^= x0;
  TF_R(13) TF_R(15) TF_R(26) TF_R(6)
  x0 += k1; x1 += k2 + 1u;
  TF_R(17) TF_R(29) TF_R(16) TF_R(24)
  x0 += k2; x1 += k0 + 2u;
  TF_R(13) TF_R(15) TF_R(26) TF_R(6)
  x0 += k0; x1 += k1 + 3u;
  TF_R(17) TF_R(29) TF_R(16) TF_R(24)
  x0 += k1; x1 += k2 + 4u;
  TF_R(13) TF_R(15) TF_R(26) TF_R(6)
  x0 += k2; x1 += k0 + 5u;
#undef TF_R
  o0 = x0; o1 = x1;
}

__host__ __forceinline__ static void tf2x32_h(uint32_t k0, uint32_t k1,
                                              uint32_t x0, uint32_t x1,
                                              uint32_t& o0, uint32_t& o1)
{
  uint32_t k2 = k0 ^ k1 ^ 0x1BD11BDAu;
  x0 += k0; x1 += k1;
#define TF_R(r) x0 += x1; x1 = (x1 << (r)) | (x1 >> (32 - (r))); x1 ^= x0;
  TF_R(13) TF_R(15) TF_R(26) TF_R(6)
  x0 += k1; x1 += k2 + 1u;
  TF_R(17) TF_R(29) TF_R(16) TF_R(24)
  x0 += k2; x1 += k0 + 2u;
  TF_R(13) TF_R(15) TF_R(26) TF_R(6)
  x0 += k0; x1 += k1 + 3u;
  TF_R(17) TF_R(29) TF_R(16) TF_R(24)
  x0 += k1; x1 += k2 + 4u;
  TF_R(13) TF_R(15) TF_R(26) TF_R(6)
  x0 += k2; x1 += k0 + 5u;
#undef TF_R
  o0 = x0; o1 = x1;
}

__device__ __forceinline__ uint32_t rbits(uint32_t ka, uint32_t kb, uint32_t i)
{
  uint32_t o0, o1;
  tf2x32(ka, kb, 0u, i, o0, o1);
  return o0 ^ o1;
}

__device__ __forceinline__ float erfinv_xla(float x)
{
  float w = -log1pf(-__fmul_rn(x, x));
  float p;
  if (w < 5.0f) {
    w = __fsub_rn(w, 2.5f);
    p = 2.81022636e-08f;
    p = __fadd_rn( 3.43273939e-07f, __fmul_rn(p, w));
    p = __fadd_rn(-3.5233877e-06f,  __fmul_rn(p, w));
    p = __fadd_rn(-4.39150654e-06f, __fmul_rn(p, w));
    p = __fadd_rn( 0.00021858087f,  __fmul_rn(p, w));
    p = __fadd_rn(-0.00125372503f,  __fmul_rn(p, w));
    p = __fadd_rn(-0.00417768164f,  __fmul_rn(p, w));
    p = __fadd_rn( 0.246640727f,    __fmul_rn(p, w));
    p = __fadd_rn( 1.50140941f,     __fmul_rn(p, w));
  } else {
    w = __fsub_rn(sqrtf(w), 3.0f);
    p = -0.000200214257f;
    p = __fadd_rn( 0.000100950558f, __fmul_rn(p, w));
    p = __fadd_rn( 0.00134934322f,  __fmul_rn(p, w));
    p = __fadd_rn(-0.00367342844f,  __fmul_rn(p, w));
    p = __fadd_rn( 0.00573950773f,  __fmul_rn(p, w));
    p = __fadd_rn(-0.0076224613f,   __fmul_rn(p, w));
    p = __fadd_rn( 0.00943887047f,  __fmul_rn(p, w));
    p = __fadd_rn( 1.00167406f,     __fmul_rn(p, w));
    p = __fadd_rn( 2.83297682f,     __fmul_rn(p, w));
  }
  return __fmul_rn(p, x);
}

__device__ __forceinline__ float jax_normal(uint32_t bits)
{
  float f = __fsub_rn(__uint_as_float((bits >> 9) | 0x3F800000u), 1.0f);
  const float lo = -0.99999994f;
  float u = __fadd_rn(__fmul_rn(f, 2.0f), lo);
  u = fmaxf(lo, u);
  return __fmul_rn(1.41421356f, erfinv_xla(u));
}

__device__ __forceinline__ ushort_t f2bf(float x)
{
  uint32_t u = __float_as_uint(x);
  return (ushort_t)((u + 0x7FFFu + ((u >> 16) & 1u)) >> 16);
}

__device__ __forceinline__ void bfsplit(float x, ushort_t& hi, ushort_t& lo)
{
  uint32_t u = __float_as_uint(x);
  hi = (ushort_t)(u >> 16);
  float r = x - __uint_as_float(u & 0xFFFF0000u);
  lo = f2bf(r);
}

// ---- G2/G3 phase (f32 A staged+BN+split into LDS; split-bf16 MFMA) ----
template<int K, int CONC, int EPI>
__device__ __forceinline__ void ph_mfs(
    const float* __restrict__ Af, const float* __restrict__ Sf,
    const float* __restrict__ partIn, const float* __restrict__ g,
    const float* __restrict__ be,
    const ushort_t* __restrict__ Whi, const ushort_t* __restrict__ Wlo,
    const float* __restrict__ b0, const float* __restrict__ b1,
    float* __restrict__ Of32, float* __restrict__ partOut,
    float* __restrict__ ps, float* __restrict__ outp, int t,
    int task, char* smem)
{
  constexpr int KP = K + 8;
  const int tid = threadIdx.x;
  const int w = tid >> 6, l = tid & 63;
  const int mt = task >> 3, M0 = mt * 16;
  const int N0 = (task & 7) * 64 + w * 16;
  const int lm = l & 15, lk = l >> 4;

  ushort_t (*Ahi)[KP] = (ushort_t(*)[KP])smem;
  ushort_t (*Alo)[KP] = (ushort_t(*)[KP])(smem + SM_ALO);
  float2* scsh = (float2*)(smem + SM_SCSH);

  for (int c = tid; c < 512; c += 256) {
    const float2* pp = (const float2*)partIn + c * 32;
    float s = 0.0f, q = 0.0f;
    #pragma unroll
    for (int m = 0; m < 32; ++m) { float2 v = pp[m]; s += v.x; q += v.y; }
    float mn  = s * (1.0f / 512.0f);
    float var = q * (1.0f / 512.0f) - mn * mn;
    float inv = 1.0f / sqrtf(var + 1e-5f);
    float sc  = inv * g[c];
    scsh[c] = make_float2(sc, be[c] - mn * sc);
  }
  __syncthreads();

  for (int r = 0; r < 16; ++r) {
    for (int c = tid; c < K; c += 256) {
      float v;
      if constexpr (CONC) {
        if (c < 512) { float2 ss = scsh[c];
          v = __builtin_fmaf(Af[(M0 + r) * 512 + c], ss.x, ss.y); }
        else v = Sf[(M0 + r) * 64 + (c - 512)];
      } else {
        float2 ss = scsh[c];
        v = __builtin_fmaf(Af[(M0 + r) * K + c], ss.x, ss.y);
      }
      ushort_t hi, lo;
      bfsplit(v, hi, lo);
      Ahi[r][c] = hi; Alo[r][c] = lo;
    }
  }
  __syncthreads();

  const ushort_t* bhrow = Whi + (N0 + lm) * K;
  const ushort_t* blrow = Wlo + (N0 + lm) * K;
  f32x4 acc = {0.0f, 0.0f, 0.0f, 0.0f};
  #pragma unroll
  for (int ks = 0; ks < K / 32; ++ks) {
    const int kb = ks * 32 + lk * 8;
    short8v ah = *reinterpret_cast<const short8v*>(&Ahi[lm][kb]);
    short8v al = *reinterpret_cast<const short8v*>(&Alo[lm][kb]);
    short8v wh = *reinterpret_cast<const short8v*>(bhrow + kb);
    short8v wl = *reinterpret_cast<const short8v*>(blrow + kb);
    acc = __builtin_amdgcn_mfma_f32_16x16x32_bf16(ah, wh, acc, 0, 0, 0);
    acc = __builtin_amdgcn_mfma_f32_16x16x32_bf16(ah, wl, acc, 0, 0, 0);
    acc = __builtin_amdgcn_mfma_f32_16x16x32_bf16(al, wh, acc, 0, 0, 0);
  }

  const int n = N0 + lm;
  if constexpr (EPI == 0) {
    float bias = b0[n];
    float s = 0.0f, q = 0.0f;
    #pragma unroll
    for (int j = 0; j < 4; ++j) {
      float xv = fmaxf(acc[j] + bias, 0.0f);
      s += xv; q += xv * xv;
      Of32[(M0 + lk * 4 + j) * 512 + n] = xv;
    }
    s += __shfl_xor(s, 16); s += __shfl_xor(s, 32);
    q += __shfl_xor(q, 16); q += __shfl_xor(q, 32);
    if (l < 16) ((float2*)partOut)[n * 32 + mt] = make_float2(s, q);
  } else {
    if (N0 < 256) {
      float bias = b0[n];
      #pragma unroll
      for (int j = 0; j < 4; ++j) {
        float xv = acc[j] + bias;
        int m = M0 + lk * 4 + j;
        outp[MUO_OFF + (m * NT + t) * NH + n] = xv;
      }
    } else {
      float bias = b1[n - 256];
      float s = 0.0f, q = 0.0f;
      #pragma unroll
      for (int j = 0; j < 4; ++j) {
        float xv = acc[j] + bias;
        xv = (xv > 0.0f ? xv : expm1f(xv)) + 1.0f + 1e-12f;
        s += xv; q += xv * xv;
        ps[(M0 + lk * 4 + j) * NH + (n - 256)] = xv;
      }
      s += __shfl_xor(s, 16); s += __shfl_xor(s, 32);
      q += __shfl_xor(q, 16); q += __shfl_xor(q, 32);
      if (l < 16) ((float2*)partOut)[(n - 256) * 32 + mt] = make_float2(s, q);
    }
  }
}

// ---- G5 phase (emission heads + sample; 128 tasks) ----
__device__ __forceinline__ void ph_g5(
    const float* __restrict__ Ef, const ushort_t* __restrict__ Whi,
    const ushort_t* __restrict__ Wlo,
    const float* __restrict__ partIn, const float* __restrict__ g,
    const float* __restrict__ be,
    const float* __restrict__ bm, const float* __restrict__ bs,
    uint32_t k3a, uint32_t k3b, float* __restrict__ outp, int t,
    int task, char* smem)
{
  constexpr int K = 512, KP = 520;
  const int tid = threadIdx.x;
  const int w = tid >> 6, l = tid & 63;
  const int mt = task >> 2, jg = task & 3;
  const int M0 = mt * 16;
  const int lm = l & 15, lk = l >> 4;
  const bool isStd = (w >= 2);
  const int jl0 = (w & 1) * 16;
  const int N0 = (isStd ? 128 : 0) + jg * 32 + jl0;

  ushort_t (*Ahi)[KP] = (ushort_t(*)[KP])smem;
  ushort_t (*Alo)[KP] = (ushort_t(*)[KP])(smem + SM_ALO);
  float2* scsh = (float2*)(smem + SM_SCSH);
  float (*mean_s)[32] = (float(*)[32])(smem + SM_EXTRA);
  float (*std_s)[32]  = (float(*)[32])(smem + SM_EXTRA + 2048);

  for (int c = tid; c < 512; c += 256) {
    const float2* pp = (const float2*)partIn + c * 32;
    float s = 0.0f, q = 0.0f;
    #pragma unroll
    for (int m = 0; m < 32; ++m) { float2 v = pp[m]; s += v.x; q += v.y; }
    float mn  = s * (1.0f / 512.0f);
    float var = q * (1.0f / 512.0f) - mn * mn;
    float inv = 1.0f / sqrtf(var + 1e-5f);
    float sc  = inv * g[c];
    scsh[c] = make_float2(sc, be[c] - mn * sc);
  }
  __syncthreads();

  for (int r = 0; r < 16; ++r) {
    for (int c = tid; c < K; c += 256) {
      float2 ss = scsh[c];
      float v = __builtin_fmaf(Ef[(M0 + r) * 512 + c], ss.x, ss.y);
      ushort_t hi, lo;
      bfsplit(v, hi, lo);
      Ahi[r][c] = hi; Alo[r][c] = lo;
    }
  }
  __syncthreads();

  const ushort_t* bhrow = Whi + (N0 + lm) * K;
  const ushort_t* blrow = Wlo + (N0 + lm) * K;
  f32x4 acc = {0.0f, 0.0f, 0.0f, 0.0f};
  #pragma unroll
  for (int ks = 0; ks < 16; ++ks) {
    const int kb = ks * 32 + lk * 8;
    short8v ah = *reinterpret_cast<const short8v*>(&Ahi[lm][kb]);
    short8v al = *reinterpret_cast<const short8v*>(&Alo[lm][kb]);
    short8v wh = *reinterpret_cast<const short8v*>(bhrow + kb);
    short8v wl = *reinterpret_cast<const short8v*>(blrow + kb);
    acc = __builtin_amdgcn_mfma_f32_16x16x32_bf16(ah, wh, acc, 0, 0, 0);
    acc = __builtin_amdgcn_mfma_f32_16x16x32_bf16(ah, wl, acc, 0, 0, 0);
    acc = __builtin_amdgcn_mfma_f32_16x16x32_bf16(al, wh, acc, 0, 0, 0);
  }

  const int n = N0 + lm;
  float bias = isStd ? bs[n - 128] : bm[n];
  #pragma unroll
  for (int j = 0; j < 4; ++j) {
    float xv = acc[j] + bias;
    if (isStd) xv = (xv > 0.0f ? xv : expm1f(xv)) + 1.0f + 1e-12f;
    int r = lk * 4 + j, jl = jl0 + lm;
    if (isStd) std_s[r][jl] = xv; else mean_s[r][jl] = xv;
  }
  __syncthreads();

  for (int e = tid; e < 512; e += 256) {
    int r = e >> 5, jl = e & 31;
    int bb = M0 + r, j = jg * 32 + jl;
    float z = jax_normal(rbits(k3a, k3b, (uint32_t)(bb * NO + j)));
    outp[(bb * NT + t) * NO + j] = __fadd_rn(mean_s[r][jl], __fmul_rn(std_s[r][jl], z));
  }
}

// ---------------- kernels ----------------

// fused init: x copy, h0 table init, weight split, pis-all
#define EWB 2048
__global__ __launch_bounds__(256) void k_init(Params p)
{
  const int tid = threadIdx.x;
  if (blockIdx.x < EWB) {
    const int gtid = blockIdx.x * 256 + tid;
    const int gsz = EWB * 256;
    for (int i = gtid; i < NB * NT * NO; i += gsz) {
      float v = p.x[i];
      p.out[NB * NT * NO + i] = v;
      if ((i % (NT * NO)) < NO) p.out[i] = v;
    }
    for (int i = gtid; i < NB * NH; i += gsz) {
      int b = i >> 8, h = i & 255;
      p.out[MUO_OFF  + (b * NT) * NH + h] = p.mu0[h];
      p.out[VARO_OFF + (b * NT) * NH + h] = p.var0[h];
    }
    for (int i = gtid; i < 950272; i += gsz) {
      float v; int ho, lo_;
      if (i < 131072) { v = p.tW1[i]; ho = U_WT1H + i; lo_ = U_WT1L + i; }
      else if (i < 425984) { int j = i - 131072; v = p.tW2[j]; ho = U_WT2H + j; lo_ = U_WT2L + j; }
      else if (i < 688128) { int j = i - 425984; int n = j >> 9, k = j & 511;
        v = (n < 256) ? p.tWm[n * 512 + k] : p.tWs[(n - 256) * 512 + k];
        ho = U_WMSH + j; lo_ = U_WMSL + j; }
      else if (i < 819200) { int j = i - 688128; v = p.eW1[j]; ho = U_WE1H + j; lo_ = U_WE1L + j; }
      else { int j = i - 819200; int n = j >> 9, k = j & 511;
        v = (n < 128) ? p.eWm[n * 512 + k] : p.eWs[(n - 128) * 512 + k];
        ho = U_WESH + j; lo_ = U_WESL + j; }
      ushort_t h, l;
      bfsplit(v, h, l);
      p.U[ho] = h; p.U[lo_] = l;
    }
  } else {
    const int wid = tid >> 6, lane = tid & 63;
    int wt = (blockIdx.x - EWB) * 4 + wid;
    if (wt >= 19 * NB) return;
    int t = wt / NB + 1;
    int b = wt - (t - 1) * NB;
    uint32_t kt0, kt1, k1a, k1b;
    tf2x32(0u, 42u, 0u, (uint32_t)t, kt0, kt1);
    tf2x32(kt0, kt1, 0u, 0u, k1a, k1b);
    float v = -__builtin_inff();
    int idx = 0x7FFFFFFF;
    if (lane < t) {
      const float* hq = p.h_gru + (b * NT + t) * NH;
      const float* hu = p.h_gru + (b * NT + lane) * NH;
      float d = 0.0f;
      for (int h = 0; h < NH; ++h) d += hq[h] * hu[h];
      float logit = d * 0.0625f;
      uint32_t bits = rbits(k1a, k1b, (uint32_t)(b * t + lane));
      float f = __fsub_rn(__uint_as_float((bits >> 9) | 0x3F800000u), 1.0f);
      const float tinyf = 1.1754943508222875e-38f;
      float u = fmaxf(tinyf, __fadd_rn(f, tinyf));
      float gmb = -logf(-logf(u));
      v = gmb + logit;
      idx = lane;
    }
    for (int off = 32; off; off >>= 1) {
      float ov = __shfl_xor(v, off);
      int oi = __shfl_xor(idx, off);
      if (ov > v || (ov == v && oi < idx)) { v = ov; idx = oi; }
    }
    if (lane == 0) p.pisA[t * NB + b] = idx;
  }
}

// KA(t): G3(t)
__global__ __launch_bounds__(256) void k_A(Params p, int t)
{
  __shared__ __align__(16) char smem[SM_BYTES];
  ph_mfs<512, 0, 1>(p.a2f, nullptr, p.part2, p.tg2, p.tbe2,
                    p.U + U_WMSH, p.U + U_WMSL, p.tbm, p.tbs,
                    nullptr, p.partS, p.psf, p.out, t, blockIdx.x, smem);
}

// KB(t): [ht(t)-prologue + G1(t+1)] and/or [ht(t)-prologue + G4(t)]
// t==0: no prologue, A = broadcast split(h0).
template<int HASG1, int HASG4>
__global__ __launch_bounds__(256) void k_B(Params p, int t,
                                           uint32_t k2a, uint32_t k2b)
{
  __shared__ __align__(16) char smem[SM_BYTES];
  constexpr int KP = 264;
  ushort_t (*Ahi)[KP] = (ushort_t(*)[KP])smem;
  ushort_t (*Alo)[KP] = (ushort_t(*)[KP])(smem + 16 * KP * 2);
  float2* scsh = (float2*)(smem + 2 * 16 * KP * 2);      // 256 ch
  int* pis_s = (int*)(smem + 2 * 16 * KP * 2 + 2048);

  const int tid = threadIdx.x;
  const bool isG1 = HASG1 && ((int)blockIdx.x < 256);
  const int task = isG1 ? blockIdx.x : (blockIdx.x - (HASG1 ? 256 : 0));
  const int mt = task >> 3, M0 = mt * 16, ng = task & 7;
  const int w = tid >> 6, l = tid & 63;
  const int lm = l & 15, lk = l >> 4;

  if (t == 0) {
    int c = tid;
    ushort_t hi, lo;
    bfsplit(p.h0[c], hi, lo);
    #pragma unroll
    for (int r = 0; r < 16; ++r) { Ahi[r][c] = hi; Alo[r][c] = lo; }
  } else {
    // BN-sd coeffs (exact R9 sdht math/order)
    {
      int c = tid;
      const float2* pp = (const float2*)p.partS + c * 32;
      float s = 0.0f, q = 0.0f;
      #pragma unroll
      for (int m = 0; m < 32; ++m) { float2 v = pp[m]; s += v.x; q += v.y; }
      float mn  = s * (1.0f / 512.0f);
      float var = q * (1.0f / 512.0f) - mn * mn;
      float inv = 1.0f / sqrtf(var + 1e-5f);
      float sc  = inv * p.tgs[c];
      scsh[c] = make_float2(sc, p.tbes[c] - mn * sc);
    }
    if (tid < 16) pis_s[tid] = p.pisA[t * NB + M0 + tid];
    __syncthreads();
    const bool wv = (ng == 0) && (HASG1 ? isG1 : true);
    for (int e = tid; e < 4096; e += 256) {
      int r = e >> 8, c = e & 255;
      int b = M0 + r;
      float2 ss = scsh[c];
      float vt = p.psf[b * NH + c] * ss.x + ss.y;
      if (wv) p.out[VARO_OFF + (b * NT + t) * NH + c] = vt;
      int pp = pis_s[r];
      float mu = p.out[MUO_OFF + (b * NT + pp + 1) * NH + c];
      float sd = (pp == t - 1) ? vt : p.out[VARO_OFF + (b * NT + pp + 1) * NH + c];
      float z = jax_normal(rbits(k2a, k2b, (uint32_t)(b * NH + c)));
      float ht = __fadd_rn(mu, __fmul_rn(sd, z));
      ushort_t hi, lo;
      bfsplit(ht, hi, lo);
      Ahi[r][c] = hi; Alo[r][c] = lo;
    }
  }
  __syncthreads();

  const ushort_t* Whi = isG1 ? (p.U + U_WT1H) : (p.U + U_WE1H);
  const ushort_t* Wlo = isG1 ? (p.U + U_WT1L) : (p.U + U_WE1L);
  const float* bias0  = isG1 ? p.tb1 : p.eb1;
  float* Of32   = isG1 ? p.a1f : p.e1f;
  float* partOut= isG1 ? p.part1 : p.partE;

  const int N0 = ng * 64 + w * 16;
  const ushort_t* bhrow = Whi + (N0 + lm) * 256;
  const ushort_t* blrow = Wlo + (N0 + lm) * 256;
  f32x4 acc = {0.0f, 0.0f, 0.0f, 0.0f};
  #pragma unroll
  for (int ks = 0; ks < 8; ++ks) {
    const int kb = ks * 32 + lk * 8;
    short8v ah = *reinterpret_cast<const short8v*>(&Ahi[lm][kb]);
    short8v al = *reinterpret_cast<const short8v*>(&Alo[lm][kb]);
    short8v wh = *reinterpret_cast<const short8v*>(bhrow + kb);
    short8v wl = *reinterpret_cast<const short8v*>(blrow + kb);
    acc = __builtin_amdgcn_mfma_f32_16x16x32_bf16(ah, wh, acc, 0, 0, 0);
    acc = __builtin_amdgcn_mfma_f32_16x16x32_bf16(ah, wl, acc, 0, 0, 0);
    acc = __builtin_amdgcn_mfma_f32_16x16x32_bf16(al, wh, acc, 0, 0, 0);
  }

  const int n = N0 + lm;
  float bias = bias0[n];
  float s = 0.0f, q = 0.0f;
  #pragma unroll
  for (int j = 0; j < 4; ++j) {
    float xv = fmaxf(acc[j] + bias, 0.0f);
    s += xv; q += xv * xv;
    Of32[(M0 + lk * 4 + j) * 512 + n] = xv;
  }
  s += __shfl_xor(s, 16); s += __shfl_xor(s, 32);
  q += __shfl_xor(q, 16); q += __shfl_xor(q, 32);
  if (l < 16) ((float2*)partOut)[n * 32 + mt] = make_float2(s, q);
}

// KC(t): [G2(t+1)] and/or [G5(t)]
template<int HASG2, int HASG5>
__global__ __launch_bounds__(256) void k_C(Params p, int t,
                                           uint32_t k3a, uint32_t k3b)
{
  __shared__ __align__(16) char smem[SM_BYTES];
  const bool isG2 = HASG2 && ((int)blockIdx.x < 256);
  if (isG2) {
    ph_mfs<576, 1, 0>(p.a1f, p.s, p.part1, p.tg1, p.tbe1,
                      p.U + U_WT2H, p.U + U_WT2L, p.tb2, nullptr,
                      p.a2f, p.part2, nullptr, nullptr, 0, blockIdx.x, smem);
  } else {
    int task = blockIdx.x - (HASG2 ? 256 : 0);
    ph_g5(p.e1f, p.U + U_WESH, p.U + U_WESL, p.partE, p.eg1, p.ebe1,
          p.ebm, p.ebs, k3a, k3b, p.out, t, task, smem);
  }
}

// ---------------- host ----------------

extern "C" void kernel_launch(void* const* d_in, const int* in_sizes, int n_in,
                              void* d_out, int out_size, void* d_ws, size_t ws_size,
                              hipStream_t stream)
{
  Params P;
  P.x    = (const float*)d_in[0];
  P.s    = (const float*)d_in[1];
  P.h_gru= (const float*)d_in[2];
  P.mu0  = (const float*)d_in[3];
  P.var0 = (const float*)d_in[4];
  P.h0   = (const float*)d_in[5];
  P.tW1  = (const float*)d_in[6];
  P.tb1  = (const float*)d_in[7];
  P.tg1  = (const float*)d_in[8];
  P.tbe1 = (const float*)d_in[9];
  P.tW2  = (const float*)d_in[10];
  P.tb2  = (const float*)d_in[11];
  P.tg2  = (const float*)d_in[12];
  P.tbe2 = (const float*)d_in[13];
  P.tWm  = (const float*)d_in[14];
  P.tbm  = (const float*)d_in[15];
  P.tWs  = (const float*)d_in[16];
  P.tbs  = (const float*)d_in[17];
  P.tgs  = (const float*)d_in[18];
  P.tbes = (const float*)d_in[19];
  P.eW1  = (const float*)d_in[20];
  P.eb1  = (const float*)d_in[21];
  P.eg1  = (const float*)d_in[22];
  P.ebe1 = (const float*)d_in[23];
  P.eWm  = (const float*)d_in[24];
  P.ebm  = (const float*)d_in[25];
  P.eWs  = (const float*)d_in[26];
  P.ebs  = (const float*)d_in[27];

  float* ws = (float*)d_ws;
  P.out   = (float*)d_out;
  P.psf   = ws + O_PS;
  P.a1f   = ws + O_A1;
  P.a2f   = ws + O_A2;
  P.e1f   = ws + O_E1;
  P.part1 = ws + O_P1;
  P.part2 = ws + O_P2;
  P.partS = ws + O_PSD;
  P.partE = ws + O_PE;
  P.pisA  = (int*)(ws + O_PIS);
  P.U     = (ushort_t*)(ws + O_USH);

  k_init<<<EWB + 2432, 256, 0, stream>>>(P);

  // t = 0: G1(1) from h0, then G2(1)
  k_B<1, 0><<<256, 256, 0, stream>>>(P, 0, 0u, 0u);
  k_C<1, 0><<<256, 256, 0, stream>>>(P, 0, 0u, 0u);

  for (int t = 1; t < NT; ++t) {
    uint32_t kt0, kt1, k2a, k2b, k3a, k3b;
    tf2x32_h(0u, 42u, 0u, (uint32_t)t, kt0, kt1);
    tf2x32_h(kt0, kt1, 0u, 1u, k2a, k2b);
    tf2x32_h(kt0, kt1, 0u, 2u, k3a, k3b);

    k_A<<<256, 256, 0, stream>>>(P, t);
    if (t < NT - 1) {
      k_B<1, 1><<<512, 256, 0, stream>>>(P, t, k2a, k2b);
      k_C<1, 1><<<384, 256, 0, stream>>>(P, t, k3a, k3b);
    } else {
      k_B<0, 1><<<256, 256, 0, stream>>>(P, t, k2a, k2b);
      k_C<0, 1><<<128, 256, 0, stream>>>(P, t, k3a, k3b);
    }
  }
}

// Round 14
// 1392.409 us; speedup vs baseline: 3.0484x; 1.0592x over previous
//
#include <hip/hip_runtime.h>
#include <stdint.h>

#define NB 512
#define NT 20
#define NH 256
#define NO 128
#define MUO_OFF (2*NB*NT*NO)
#define VARO_OFF (MUO_OFF + NB*NT*NH)

// ===== LEDGER =====
//  R6 6587 f32-serial; R7 1557 f32-tiled; R8 FAIL bf16 drift; R9 PASS 1627
//  (split-bf16 MFMA, 6 l/step); R10 cooperative 4245 (grid.sync 30-45us);
//  R12 PASS 1475 absmax 0.0625 (3 kernels/step; k_init 58us top, uncoalesced pis).
//  R13: coalesced-pis + z-tables — container died AGAIN (same pod as R11 flake;
//  kernel never ran). R14 (this): RESUBMIT R13 byte-identical.
//  Predict: PASS, absmax exactly 0.0625, 1200-1320us; top-5 exposes k_A/k_B/k_C.
// ==================

typedef __attribute__((ext_vector_type(8))) short short8v;
typedef __attribute__((ext_vector_type(4))) float f32x4;
typedef unsigned short ushort_t;

// ws float offsets
#define O_PS   0
#define O_A1   (O_PS + NB*NH)
#define O_A2   (O_A1 + 512*512)
#define O_E1   (O_A2 + 512*512)
#define O_P1   (O_E1 + 512*512)
#define O_P2   (O_P1 + 512*32*2)
#define O_PSD  (O_P2 + 512*32*2)
#define O_PE   (O_PSD + 256*32*2)
#define O_PIS  (O_PE + 512*32*2)
#define O_ZH   (O_PIS + NT*NB)
#define O_ZE   (O_ZH + 19*NB*NH)
#define O_USH  (O_ZE + 19*NB*NO)
// ushort offsets within U (weight hi/lo splits)
#define U_WT1H 0
#define U_WT1L 131072
#define U_WT2H 262144
#define U_WT2L 557056
#define U_WMSH 851968
#define U_WMSL 1114112
#define U_WE1H 1376256
#define U_WE1L 1507328
#define U_WESH 1638400
#define U_WESL 1769472

// shared scratch layout (bytes) for K<=576 phases
#define SM_ALO   18688
#define SM_SCSH  37376
#define SM_EXTRA 41472
#define SM_BYTES 45568

struct Params {
  const float *x, *s, *h_gru, *mu0, *var0, *h0;
  const float *tb1, *tg1, *tbe1, *tb2, *tg2, *tbe2;
  const float *tbm, *tbs, *tgs, *tbes;
  const float *eb1, *eg1, *ebe1, *ebm, *ebs;
  const float *tW1, *tW2, *tWm, *tWs, *eW1, *eWm, *eWs;
  float* out;
  float *psf, *a1f, *a2f, *e1f, *part1, *part2, *partS, *partE;
  float *zh, *ze;
  int* pisA;
  ushort_t* U;
  uint32_t zk2[38];   // per-t (k2a,k2b), t=1..19
  uint32_t zk3[38];   // per-t (k3a,k3b)
};

__device__ __forceinline__ void tf2x32(uint32_t k0, uint32_t k1,
                                       uint32_t x0, uint32_t x1,
                                       uint32_t& o0, uint32_t& o1)
{
  uint32_t k2 = k0 ^ k1 ^ 0x1BD11BDAu;
  x0 += k0; x1 += k1;
#define TF_R(r) x0 += x1; x1 = (x1 << (r)) | (x1 >> (32 - (r))); x1 ^= x0;
  TF_R(13) TF_R(15) TF_R(26) TF_R(6)
  x0 += k1; x1 += k2 + 1u;
  TF_R(17) TF_R(29) TF_R(16) TF_R(24)
  x0 += k2; x1 += k0 + 2u;
  TF_R(13) TF_R(15) TF_R(26) TF_R(6)
  x0 += k0; x1 += k1 + 3u;
  TF_R(17) TF_R(29) TF_R(16) TF_R(24)
  x0 += k1; x1 += k2 + 4u;
  TF_R(13) TF_R(15) TF_R(26) TF_R(6)
  x0 += k2; x1 += k0 + 5u;
#undef TF_R
  o0 = x0; o1 = x1;
}

__host__ __forceinline__ static void tf2x32_h(uint32_t k0, uint32_t k1,
                                              uint32_t x0, uint32_t x1,
                                              uint32_t& o0, uint32_t& o1)
{
  uint32_t k2 = k0 ^ k1 ^ 0x1BD11BDAu;
  x0 += k0; x1 += k1;
#define TF_R(r) x0 += x1; x1 = (x1 << (r)) | (x1 >> (32 - (r))); x1 ^= x0;
  TF_R(13) TF_R(15) TF_R(26) TF_R(6)
  x0 += k1; x1 += k2 + 1u;
  TF_R(17) TF_R(29) TF_R(16) TF_R(24)
  x0 += k2; x1 += k0 + 2u;
  TF_R(13) TF_R(15) TF_R(26) TF_R(6)
  x0 += k0; x1 += k1 + 3u;
  TF_R(17) TF_R(29) TF_R(16) TF_R(24)
  x0 += k1; x1 += k2 + 4u;
  TF_R(13) TF_R(15) TF_R(26) TF_R(6)
  x0 += k2; x1 += k0 + 5u;
#undef TF_R
  o0 = x0; o1 = x1;
}

__device__ __forceinline__ uint32_t rbits(uint32_t ka, uint32_t kb, uint32_t i)
{
  uint32_t o0, o1;
  tf2x32(ka, kb, 0u, i, o0, o1);
  return o0 ^ o1;
}

__device__ __forceinline__ float erfinv_xla(float x)
{
  float w = -log1pf(-__fmul_rn(x, x));
  float p;
  if (w < 5.0f) {
    w = __fsub_rn(w, 2.5f);
    p = 2.81022636e-08f;
    p = __fadd_rn( 3.43273939e-07f, __fmul_rn(p, w));
    p = __fadd_rn(-3.5233877e-06f,  __fmul_rn(p, w));
    p = __fadd_rn(-4.39150654e-06f, __fmul_rn(p, w));
    p = __fadd_rn( 0.00021858087f,  __fmul_rn(p, w));
    p = __fadd_rn(-0.00125372503f,  __fmul_rn(p, w));
    p = __fadd_rn(-0.00417768164f,  __fmul_rn(p, w));
    p = __fadd_rn( 0.246640727f,    __fmul_rn(p, w));
    p = __fadd_rn( 1.50140941f,     __fmul_rn(p, w));
  } else {
    w = __fsub_rn(sqrtf(w), 3.0f);
    p = -0.000200214257f;
    p = __fadd_rn( 0.000100950558f, __fmul_rn(p, w));
    p = __fadd_rn( 0.00134934322f,  __fmul_rn(p, w));
    p = __fadd_rn(-0.00367342844f,  __fmul_rn(p, w));
    p = __fadd_rn( 0.00573950773f,  __fmul_rn(p, w));
    p = __fadd_rn(-0.0076224613f,   __fmul_rn(p, w));
    p = __fadd_rn( 0.00943887047f,  __fmul_rn(p, w));
    p = __fadd_rn( 1.00167406f,     __fmul_rn(p, w));
    p = __fadd_rn( 2.83297682f,     __fmul_rn(p, w));
  }
  return __fmul_rn(p, x);
}

__device__ __forceinline__ float jax_normal(uint32_t bits)
{
  float f = __fsub_rn(__uint_as_float((bits >> 9) | 0x3F800000u), 1.0f);
  const float lo = -0.99999994f;
  float u = __fadd_rn(__fmul_rn(f, 2.0f), lo);
  u = fmaxf(lo, u);
  return __fmul_rn(1.41421356f, erfinv_xla(u));
}

__device__ __forceinline__ ushort_t f2bf(float x)
{
  uint32_t u = __float_as_uint(x);
  return (ushort_t)((u + 0x7FFFu + ((u >> 16) & 1u)) >> 16);
}

__device__ __forceinline__ void bfsplit(float x, ushort_t& hi, ushort_t& lo)
{
  uint32_t u = __float_as_uint(x);
  hi = (ushort_t)(u >> 16);
  float r = x - __uint_as_float(u & 0xFFFF0000u);
  lo = f2bf(r);
}

// ---- G2/G3 phase (f32 A staged+BN+split into LDS; split-bf16 MFMA) ----
template<int K, int CONC, int EPI>
__device__ __forceinline__ void ph_mfs(
    const float* __restrict__ Af, const float* __restrict__ Sf,
    const float* __restrict__ partIn, const float* __restrict__ g,
    const float* __restrict__ be,
    const ushort_t* __restrict__ Whi, const ushort_t* __restrict__ Wlo,
    const float* __restrict__ b0, const float* __restrict__ b1,
    float* __restrict__ Of32, float* __restrict__ partOut,
    float* __restrict__ ps, float* __restrict__ outp, int t,
    int task, char* smem)
{
  constexpr int KP = K + 8;
  const int tid = threadIdx.x;
  const int w = tid >> 6, l = tid & 63;
  const int mt = task >> 3, M0 = mt * 16;
  const int N0 = (task & 7) * 64 + w * 16;
  const int lm = l & 15, lk = l >> 4;

  ushort_t (*Ahi)[KP] = (ushort_t(*)[KP])smem;
  ushort_t (*Alo)[KP] = (ushort_t(*)[KP])(smem + SM_ALO);
  float2* scsh = (float2*)(smem + SM_SCSH);

  for (int c = tid; c < 512; c += 256) {
    const float2* pp = (const float2*)partIn + c * 32;
    float s = 0.0f, q = 0.0f;
    #pragma unroll
    for (int m = 0; m < 32; ++m) { float2 v = pp[m]; s += v.x; q += v.y; }
    float mn  = s * (1.0f / 512.0f);
    float var = q * (1.0f / 512.0f) - mn * mn;
    float inv = 1.0f / sqrtf(var + 1e-5f);
    float sc  = inv * g[c];
    scsh[c] = make_float2(sc, be[c] - mn * sc);
  }
  __syncthreads();

  for (int r = 0; r < 16; ++r) {
    for (int c = tid; c < K; c += 256) {
      float v;
      if constexpr (CONC) {
        if (c < 512) { float2 ss = scsh[c];
          v = __builtin_fmaf(Af[(M0 + r) * 512 + c], ss.x, ss.y); }
        else v = Sf[(M0 + r) * 64 + (c - 512)];
      } else {
        float2 ss = scsh[c];
        v = __builtin_fmaf(Af[(M0 + r) * K + c], ss.x, ss.y);
      }
      ushort_t hi, lo;
      bfsplit(v, hi, lo);
      Ahi[r][c] = hi; Alo[r][c] = lo;
    }
  }
  __syncthreads();

  const ushort_t* bhrow = Whi + (N0 + lm) * K;
  const ushort_t* blrow = Wlo + (N0 + lm) * K;
  f32x4 acc = {0.0f, 0.0f, 0.0f, 0.0f};
  #pragma unroll
  for (int ks = 0; ks < K / 32; ++ks) {
    const int kb = ks * 32 + lk * 8;
    short8v ah = *reinterpret_cast<const short8v*>(&Ahi[lm][kb]);
    short8v al = *reinterpret_cast<const short8v*>(&Alo[lm][kb]);
    short8v wh = *reinterpret_cast<const short8v*>(bhrow + kb);
    short8v wl = *reinterpret_cast<const short8v*>(blrow + kb);
    acc = __builtin_amdgcn_mfma_f32_16x16x32_bf16(ah, wh, acc, 0, 0, 0);
    acc = __builtin_amdgcn_mfma_f32_16x16x32_bf16(ah, wl, acc, 0, 0, 0);
    acc = __builtin_amdgcn_mfma_f32_16x16x32_bf16(al, wh, acc, 0, 0, 0);
  }

  const int n = N0 + lm;
  if constexpr (EPI == 0) {
    float bias = b0[n];
    float s = 0.0f, q = 0.0f;
    #pragma unroll
    for (int j = 0; j < 4; ++j) {
      float xv = fmaxf(acc[j] + bias, 0.0f);
      s += xv; q += xv * xv;
      Of32[(M0 + lk * 4 + j) * 512 + n] = xv;
    }
    s += __shfl_xor(s, 16); s += __shfl_xor(s, 32);
    q += __shfl_xor(q, 16); q += __shfl_xor(q, 32);
    if (l < 16) ((float2*)partOut)[n * 32 + mt] = make_float2(s, q);
  } else {
    if (N0 < 256) {
      float bias = b0[n];
      #pragma unroll
      for (int j = 0; j < 4; ++j) {
        float xv = acc[j] + bias;
        int m = M0 + lk * 4 + j;
        outp[MUO_OFF + (m * NT + t) * NH + n] = xv;
      }
    } else {
      float bias = b1[n - 256];
      float s = 0.0f, q = 0.0f;
      #pragma unroll
      for (int j = 0; j < 4; ++j) {
        float xv = acc[j] + bias;
        xv = (xv > 0.0f ? xv : expm1f(xv)) + 1.0f + 1e-12f;
        s += xv; q += xv * xv;
        ps[(M0 + lk * 4 + j) * NH + (n - 256)] = xv;
      }
      s += __shfl_xor(s, 16); s += __shfl_xor(s, 32);
      q += __shfl_xor(q, 16); q += __shfl_xor(q, 32);
      if (l < 16) ((float2*)partOut)[(n - 256) * 32 + mt] = make_float2(s, q);
    }
  }
}

// ---- G5 phase (emission heads + sample from z-table; 128 tasks) ----
__device__ __forceinline__ void ph_g5(
    const float* __restrict__ Ef, const ushort_t* __restrict__ Whi,
    const ushort_t* __restrict__ Wlo,
    const float* __restrict__ partIn, const float* __restrict__ g,
    const float* __restrict__ be,
    const float* __restrict__ bm, const float* __restrict__ bs,
    const float* __restrict__ ze, float* __restrict__ outp, int t,
    int task, char* smem)
{
  constexpr int K = 512, KP = 520;
  const int tid = threadIdx.x;
  const int w = tid >> 6, l = tid & 63;
  const int mt = task >> 2, jg = task & 3;
  const int M0 = mt * 16;
  const int lm = l & 15, lk = l >> 4;
  const bool isStd = (w >= 2);
  const int jl0 = (w & 1) * 16;
  const int N0 = (isStd ? 128 : 0) + jg * 32 + jl0;

  ushort_t (*Ahi)[KP] = (ushort_t(*)[KP])smem;
  ushort_t (*Alo)[KP] = (ushort_t(*)[KP])(smem + SM_ALO);
  float2* scsh = (float2*)(smem + SM_SCSH);
  float (*mean_s)[32] = (float(*)[32])(smem + SM_EXTRA);
  float (*std_s)[32]  = (float(*)[32])(smem + SM_EXTRA + 2048);

  for (int c = tid; c < 512; c += 256) {
    const float2* pp = (const float2*)partIn + c * 32;
    float s = 0.0f, q = 0.0f;
    #pragma unroll
    for (int m = 0; m < 32; ++m) { float2 v = pp[m]; s += v.x; q += v.y; }
    float mn  = s * (1.0f / 512.0f);
    float var = q * (1.0f / 512.0f) - mn * mn;
    float inv = 1.0f / sqrtf(var + 1e-5f);
    float sc  = inv * g[c];
    scsh[c] = make_float2(sc, be[c] - mn * sc);
  }
  __syncthreads();

  for (int r = 0; r < 16; ++r) {
    for (int c = tid; c < K; c += 256) {
      float2 ss = scsh[c];
      float v = __builtin_fmaf(Ef[(M0 + r) * 512 + c], ss.x, ss.y);
      ushort_t hi, lo;
      bfsplit(v, hi, lo);
      Ahi[r][c] = hi; Alo[r][c] = lo;
    }
  }
  __syncthreads();

  const ushort_t* bhrow = Whi + (N0 + lm) * K;
  const ushort_t* blrow = Wlo + (N0 + lm) * K;
  f32x4 acc = {0.0f, 0.0f, 0.0f, 0.0f};
  #pragma unroll
  for (int ks = 0; ks < 16; ++ks) {
    const int kb = ks * 32 + lk * 8;
    short8v ah = *reinterpret_cast<const short8v*>(&Ahi[lm][kb]);
    short8v al = *reinterpret_cast<const short8v*>(&Alo[lm][kb]);
    short8v wh = *reinterpret_cast<const short8v*>(bhrow + kb);
    short8v wl = *reinterpret_cast<const short8v*>(blrow + kb);
    acc = __builtin_amdgcn_mfma_f32_16x16x32_bf16(ah, wh, acc, 0, 0, 0);
    acc = __builtin_amdgcn_mfma_f32_16x16x32_bf16(ah, wl, acc, 0, 0, 0);
    acc = __builtin_amdgcn_mfma_f32_16x16x32_bf16(al, wh, acc, 0, 0, 0);
  }

  const int n = N0 + lm;
  float bias = isStd ? bs[n - 128] : bm[n];
  #pragma unroll
  for (int j = 0; j < 4; ++j) {
    float xv = acc[j] + bias;
    if (isStd) xv = (xv > 0.0f ? xv : expm1f(xv)) + 1.0f + 1e-12f;
    int r = lk * 4 + j, jl = jl0 + lm;
    if (isStd) std_s[r][jl] = xv; else mean_s[r][jl] = xv;
  }
  __syncthreads();

  for (int e = tid; e < 512; e += 256) {
    int r = e >> 5, jl = e & 31;
    int bb = M0 + r, j = jg * 32 + jl;
    float z = ze[(t - 1) * (NB * NO) + bb * NO + j];
    outp[(bb * NT + t) * NO + j] = __fadd_rn(mean_s[r][jl], __fmul_rn(std_s[r][jl], z));
  }
}

// ---------------- kernels ----------------

// fused init: x copy, tables, weight split, z-tables, coalesced pis
#define EWB 2048
__global__ __launch_bounds__(256) void k_init(Params p)
{
  __shared__ float hgs[20][257];
  const int tid = threadIdx.x;
  if (blockIdx.x < EWB) {
    const int gtid = blockIdx.x * 256 + tid;
    const int gsz = EWB * 256;
    for (int i = gtid; i < NB * NT * NO; i += gsz)
      p.out[NB * NT * NO + i] = p.x[i];
    for (int i = gtid; i < NB * NO; i += gsz) {
      int b = i >> 7, j = i & 127;
      p.out[b * NT * NO + j] = p.x[b * NT * NO + j];
    }
    for (int i = gtid; i < NB * NH; i += gsz) {
      int b = i >> 8, h = i & 255;
      p.out[MUO_OFF  + (b * NT) * NH + h] = p.mu0[h];
      p.out[VARO_OFF + (b * NT) * NH + h] = p.var0[h];
    }
    for (int i = gtid; i < 950272; i += gsz) {
      float v; int ho, lo_;
      if (i < 131072) { v = p.tW1[i]; ho = U_WT1H + i; lo_ = U_WT1L + i; }
      else if (i < 425984) { int j = i - 131072; v = p.tW2[j]; ho = U_WT2H + j; lo_ = U_WT2L + j; }
      else if (i < 688128) { int j = i - 425984; int n = j >> 9, k = j & 511;
        v = (n < 256) ? p.tWm[n * 512 + k] : p.tWs[(n - 256) * 512 + k];
        ho = U_WMSH + j; lo_ = U_WMSL + j; }
      else if (i < 819200) { int j = i - 688128; v = p.eW1[j]; ho = U_WE1H + j; lo_ = U_WE1L + j; }
      else { int j = i - 819200; int n = j >> 9, k = j & 511;
        v = (n < 128) ? p.eWm[n * 512 + k] : p.eWs[(n - 128) * 512 + k];
        ho = U_WESH + j; lo_ = U_WESL + j; }
      ushort_t h, l;
      bfsplit(v, h, l);
      p.U[ho] = h; p.U[lo_] = l;
    }
    // z-tables (data-independent normals)
    for (int i = gtid; i < 19 * NB * NH; i += gsz) {
      int tt = i >> 17;                  // / 131072
      int rem = i & 131071;
      p.zh[i] = jax_normal(rbits(p.zk2[2 * tt], p.zk2[2 * tt + 1], (uint32_t)rem));
    }
    for (int i = gtid; i < 19 * NB * NO; i += gsz) {
      int tt = i >> 16;                  // / 65536
      int rem = i & 65535;
      p.ze[i] = jax_normal(rbits(p.zk3[2 * tt], p.zk3[2 * tt + 1], (uint32_t)rem));
    }
  } else {
    // coalesced pis: one block per batch row b
    const int b = blockIdx.x - EWB;
    for (int i = tid; i < NT * NH; i += 256) {
      int r = i >> 8, c = i & 255;
      hgs[r][c] = p.h_gru[(b * NT + r) * NH + c];
    }
    __syncthreads();
    const int wid = tid >> 6, lane = tid & 63;
    for (int t = 1 + wid; t < NT; t += 4) {
      uint32_t kt0, kt1, k1a, k1b;
      tf2x32(0u, 42u, 0u, (uint32_t)t, kt0, kt1);
      tf2x32(kt0, kt1, 0u, 0u, k1a, k1b);
      float v = -__builtin_inff();
      int idx = 0x7FFFFFFF;
      if (lane < t) {
        float d = 0.0f;
        for (int h = 0; h < NH; ++h) d += hgs[t][h] * hgs[lane][h];
        float logit = d * 0.0625f;
        uint32_t bits = rbits(k1a, k1b, (uint32_t)(b * t + lane));
        float f = __fsub_rn(__uint_as_float((bits >> 9) | 0x3F800000u), 1.0f);
        const float tinyf = 1.1754943508222875e-38f;
        float u = fmaxf(tinyf, __fadd_rn(f, tinyf));
        float gmb = -logf(-logf(u));
        v = gmb + logit;
        idx = lane;
      }
      for (int off = 32; off; off >>= 1) {
        float ov = __shfl_xor(v, off);
        int oi = __shfl_xor(idx, off);
        if (ov > v || (ov == v && oi < idx)) { v = ov; idx = oi; }
      }
      if (lane == 0) p.pisA[t * NB + b] = idx;
    }
  }
}

// KA(t): G3(t)
__global__ __launch_bounds__(256) void k_A(Params p, int t)
{
  __shared__ __align__(16) char smem[SM_BYTES];
  ph_mfs<512, 0, 1>(p.a2f, nullptr, p.part2, p.tg2, p.tbe2,
                    p.U + U_WMSH, p.U + U_WMSL, p.tbm, p.tbs,
                    nullptr, p.partS, p.psf, p.out, t, blockIdx.x, smem);
}

// KB(t): [ht(t)-prologue + G1(t+1)] and/or [ht(t)-prologue + G4(t)]
// t==0: no prologue, A = broadcast split(h0). z from zh table.
template<int HASG1, int HASG4>
__global__ __launch_bounds__(256) void k_B(Params p, int t)
{
  __shared__ __align__(16) char smem[SM_BYTES];
  constexpr int KP = 264;
  ushort_t (*Ahi)[KP] = (ushort_t(*)[KP])smem;
  ushort_t (*Alo)[KP] = (ushort_t(*)[KP])(smem + 16 * KP * 2);
  float2* scsh = (float2*)(smem + 2 * 16 * KP * 2);      // 256 ch
  int* pis_s = (int*)(smem + 2 * 16 * KP * 2 + 2048);

  const int tid = threadIdx.x;
  const bool isG1 = HASG1 && ((int)blockIdx.x < 256);
  const int task = isG1 ? blockIdx.x : (blockIdx.x - (HASG1 ? 256 : 0));
  const int mt = task >> 3, M0 = mt * 16, ng = task & 7;
  const int w = tid >> 6, l = tid & 63;
  const int lm = l & 15, lk = l >> 4;

  if (t == 0) {
    int c = tid;
    ushort_t hi, lo;
    bfsplit(p.h0[c], hi, lo);
    #pragma unroll
    for (int r = 0; r < 16; ++r) { Ahi[r][c] = hi; Alo[r][c] = lo; }
  } else {
    {
      int c = tid;
      const float2* pp = (const float2*)p.partS + c * 32;
      float s = 0.0f, q = 0.0f;
      #pragma unroll
      for (int m = 0; m < 32; ++m) { float2 v = pp[m]; s += v.x; q += v.y; }
      float mn  = s * (1.0f / 512.0f);
      float var = q * (1.0f / 512.0f) - mn * mn;
      float inv = 1.0f / sqrtf(var + 1e-5f);
      float sc  = inv * p.tgs[c];
      scsh[c] = make_float2(sc, p.tbes[c] - mn * sc);
    }
    if (tid < 16) pis_s[tid] = p.pisA[t * NB + M0 + tid];
    __syncthreads();
    const bool wv = (ng == 0) && (HASG1 ? isG1 : true);
    for (int e = tid; e < 4096; e += 256) {
      int r = e >> 8, c = e & 255;
      int b = M0 + r;
      float2 ss = scsh[c];
      float vt = p.psf[b * NH + c] * ss.x + ss.y;
      if (wv) p.out[VARO_OFF + (b * NT + t) * NH + c] = vt;
      int pp = pis_s[r];
      float mu = p.out[MUO_OFF + (b * NT + pp + 1) * NH + c];
      float sd = (pp == t - 1) ? vt : p.out[VARO_OFF + (b * NT + pp + 1) * NH + c];
      float z = p.zh[(t - 1) * (NB * NH) + b * NH + c];
      float ht = __fadd_rn(mu, __fmul_rn(sd, z));
      ushort_t hi, lo;
      bfsplit(ht, hi, lo);
      Ahi[r][c] = hi; Alo[r][c] = lo;
    }
  }
  __syncthreads();

  const ushort_t* Whi = isG1 ? (p.U + U_WT1H) : (p.U + U_WE1H);
  const ushort_t* Wlo = isG1 ? (p.U + U_WT1L) : (p.U + U_WE1L);
  const float* bias0  = isG1 ? p.tb1 : p.eb1;
  float* Of32   = isG1 ? p.a1f : p.e1f;
  float* partOut= isG1 ? p.part1 : p.partE;

  const int N0 = ng * 64 + w * 16;
  const ushort_t* bhrow = Whi + (N0 + lm) * 256;
  const ushort_t* blrow = Wlo + (N0 + lm) * 256;
  f32x4 acc = {0.0f, 0.0f, 0.0f, 0.0f};
  #pragma unroll
  for (int ks = 0; ks < 8; ++ks) {
    const int kb = ks * 32 + lk * 8;
    short8v ah = *reinterpret_cast<const short8v*>(&Ahi[lm][kb]);
    short8v al = *reinterpret_cast<const short8v*>(&Alo[lm][kb]);
    short8v wh = *reinterpret_cast<const short8v*>(bhrow + kb);
    short8v wl = *reinterpret_cast<const short8v*>(blrow + kb);
    acc = __builtin_amdgcn_mfma_f32_16x16x32_bf16(ah, wh, acc, 0, 0, 0);
    acc = __builtin_amdgcn_mfma_f32_16x16x32_bf16(ah, wl, acc, 0, 0, 0);
    acc = __builtin_amdgcn_mfma_f32_16x16x32_bf16(al, wh, acc, 0, 0, 0);
  }

  const int n = N0 + lm;
  float bias = bias0[n];
  float s = 0.0f, q = 0.0f;
  #pragma unroll
  for (int j = 0; j < 4; ++j) {
    float xv = fmaxf(acc[j] + bias, 0.0f);
    s += xv; q += xv * xv;
    Of32[(M0 + lk * 4 + j) * 512 + n] = xv;
  }
  s += __shfl_xor(s, 16); s += __shfl_xor(s, 32);
  q += __shfl_xor(q, 16); q += __shfl_xor(q, 32);
  if (l < 16) ((float2*)partOut)[n * 32 + mt] = make_float2(s, q);
}

// KC(t): [G2(t+1)] and/or [G5(t)]
template<int HASG2, int HASG5>
__global__ __launch_bounds__(256) void k_C(Params p, int t)
{
  __shared__ __align__(16) char smem[SM_BYTES];
  const bool isG2 = HASG2 && ((int)blockIdx.x < 256);
  if (isG2) {
    ph_mfs<576, 1, 0>(p.a1f, p.s, p.part1, p.tg1, p.tbe1,
                      p.U + U_WT2H, p.U + U_WT2L, p.tb2, nullptr,
                      p.a2f, p.part2, nullptr, nullptr, 0, blockIdx.x, smem);
  } else {
    int task = blockIdx.x - (HASG2 ? 256 : 0);
    ph_g5(p.e1f, p.U + U_WESH, p.U + U_WESL, p.partE, p.eg1, p.ebe1,
          p.ebm, p.ebs, p.ze, p.out, t, task, smem);
  }
}

// ---------------- host ----------------

extern "C" void kernel_launch(void* const* d_in, const int* in_sizes, int n_in,
                              void* d_out, int out_size, void* d_ws, size_t ws_size,
                              hipStream_t stream)
{
  Params P;
  P.x    = (const float*)d_in[0];
  P.s    = (const float*)d_in[1];
  P.h_gru= (const float*)d_in[2];
  P.mu0  = (const float*)d_in[3];
  P.var0 = (const float*)d_in[4];
  P.h0   = (const float*)d_in[5];
  P.tW1  = (const float*)d_in[6];
  P.tb1  = (const float*)d_in[7];
  P.tg1  = (const float*)d_in[8];
  P.tbe1 = (const float*)d_in[9];
  P.tW2  = (const float*)d_in[10];
  P.tb2  = (const float*)d_in[11];
  P.tg2  = (const float*)d_in[12];
  P.tbe2 = (const float*)d_in[13];
  P.tWm  = (const float*)d_in[14];
  P.tbm  = (const float*)d_in[15];
  P.tWs  = (const float*)d_in[16];
  P.tbs  = (const float*)d_in[17];
  P.tgs  = (const float*)d_in[18];
  P.tbes = (const float*)d_in[19];
  P.eW1  = (const float*)d_in[20];
  P.eb1  = (const float*)d_in[21];
  P.eg1  = (const float*)d_in[22];
  P.ebe1 = (const float*)d_in[23];
  P.eWm  = (const float*)d_in[24];
  P.ebm  = (const float*)d_in[25];
  P.eWs  = (const float*)d_in[26];
  P.ebs  = (const float*)d_in[27];

  float* ws = (float*)d_ws;
  P.out   = (float*)d_out;
  P.psf   = ws + O_PS;
  P.a1f   = ws + O_A1;
  P.a2f   = ws + O_A2;
  P.e1f   = ws + O_E1;
  P.part1 = ws + O_P1;
  P.part2 = ws + O_P2;
  P.partS = ws + O_PSD;
  P.partE = ws + O_PE;
  P.pisA  = (int*)(ws + O_PIS);
  P.zh    = ws + O_ZH;
  P.ze    = ws + O_ZE;
  P.U     = (ushort_t*)(ws + O_USH);

  for (int t = 1; t < NT; ++t) {
    uint32_t kt0, kt1, a, b;
    tf2x32_h(0u, 42u, 0u, (uint32_t)t, kt0, kt1);
    tf2x32_h(kt0, kt1, 0u, 1u, a, b);
    P.zk2[2 * (t - 1)] = a; P.zk2[2 * (t - 1) + 1] = b;
    tf2x32_h(kt0, kt1, 0u, 2u, a, b);
    P.zk3[2 * (t - 1)] = a; P.zk3[2 * (t - 1) + 1] = b;
  }

  k_init<<<EWB + NB, 256, 0, stream>>>(P);

  // t = 0: G1(1) from h0, then G2(1)
  k_B<1, 0><<<256, 256, 0, stream>>>(P, 0);
  k_C<1, 0><<<256, 256, 0, stream>>>(P, 0);

  for (int t = 1; t < NT; ++t) {
    k_A<<<256, 256, 0, stream>>>(P, t);
    if (t < NT - 1) {
      k_B<1, 1><<<512, 256, 0, stream>>>(P, t);
      k_C<1, 1><<<384, 256, 0, stream>>>(P, t);
    } else {
      k_B<0, 1><<<256, 256, 0, stream>>>(P, t);
      k_C<0, 1><<<128, 256, 0, stream>>>(P, t);
    }
  }
}

// Round 17
// 1365.471 us; speedup vs baseline: 3.1086x; 1.0197x over previous
//
#include <hip/hip_runtime.h>
#include <stdint.h>

#define NB 512
#define NT 20
#define NH 256
#define NO 128
#define MUO_OFF (2*NB*NT*NO)
#define VARO_OFF (MUO_OFF + NB*NT*NH)

// ===== LEDGER =====
//  R6 6587 f32-serial; R7 1557 f32-tiled; R9 1627 split-bf16 MFMA; R10 coop 4245;
//  R12 1475 (3 kernels/step); R14 PASS 1392 absmax 0.0625 (coalesced pis +
//  z-tables; k_init 58us, z-gen latency-bound VALU 50%).
//  R15/R16: z-gen 4-way ILP + KB fusion — pod 'warm-big-subtle-nail' died BOTH
//  rounds (4 flakes total: R11,R13,R15,R16; kernel never ran). Infra, not code.
//  R17 (this): RESUBMIT byte-identical again.
//  Predict: PASS, absmax exactly 0.0625, 1150-1250us, k_init ~30us.
// ==================

typedef __attribute__((ext_vector_type(8))) short short8v;
typedef __attribute__((ext_vector_type(4))) float f32x4;
typedef unsigned short ushort_t;

// ws float offsets
#define O_PS   0
#define O_A1   (O_PS + NB*NH)
#define O_A2   (O_A1 + 512*512)
#define O_E1   (O_A2 + 512*512)
#define O_P1   (O_E1 + 512*512)
#define O_P2   (O_P1 + 512*32*2)
#define O_PSD  (O_P2 + 512*32*2)
#define O_PE   (O_PSD + 256*32*2)
#define O_PIS  (O_PE + 512*32*2)
#define O_ZH   (O_PIS + NT*NB)
#define O_ZE   (O_ZH + 19*NB*NH)
#define O_USH  (O_ZE + 19*NB*NO)
// ushort offsets within U (weight hi/lo splits)
#define U_WT1H 0
#define U_WT1L 131072
#define U_WT2H 262144
#define U_WT2L 557056
#define U_WMSH 851968
#define U_WMSL 1114112
#define U_WE1H 1376256
#define U_WE1L 1507328
#define U_WESH 1638400
#define U_WESL 1769472

// shared scratch layout (bytes) for K<=576 phases
#define SM_ALO   18688
#define SM_SCSH  37376
#define SM_EXTRA 41472
#define SM_BYTES 45568

struct Params {
  const float *x, *s, *h_gru, *mu0, *var0, *h0;
  const float *tb1, *tg1, *tbe1, *tb2, *tg2, *tbe2;
  const float *tbm, *tbs, *tgs, *tbes;
  const float *eb1, *eg1, *ebe1, *ebm, *ebs;
  const float *tW1, *tW2, *tWm, *tWs, *eW1, *eWm, *eWs;
  float* out;
  float *psf, *a1f, *a2f, *e1f, *part1, *part2, *partS, *partE;
  float *zh, *ze;
  int* pisA;
  ushort_t* U;
  uint32_t zk2[38];   // per-t (k2a,k2b), t=1..19
  uint32_t zk3[38];   // per-t (k3a,k3b)
};

__device__ __forceinline__ void tf2x32(uint32_t k0, uint32_t k1,
                                       uint32_t x0, uint32_t x1,
                                       uint32_t& o0, uint32_t& o1)
{
  uint32_t k2 = k0 ^ k1 ^ 0x1BD11BDAu;
  x0 += k0; x1 += k1;
#define TF_R(r) x0 += x1; x1 = (x1 << (r)) | (x1 >> (32 - (r))); x1 ^= x0;
  TF_R(13) TF_R(15) TF_R(26) TF_R(6)
  x0 += k1; x1 += k2 + 1u;
  TF_R(17) TF_R(29) TF_R(16) TF_R(24)
  x0 += k2; x1 += k0 + 2u;
  TF_R(13) TF_R(15) TF_R(26) TF_R(6)
  x0 += k0; x1 += k1 + 3u;
  TF_R(17) TF_R(29) TF_R(16) TF_R(24)
  x0 += k1; x1 += k2 + 4u;
  TF_R(13) TF_R(15) TF_R(26) TF_R(6)
  x0 += k2; x1 += k0 + 5u;
#undef TF_R
  o0 = x0; o1 = x1;
}

__host__ __forceinline__ static void tf2x32_h(uint32_t k0, uint32_t k1,
                                              uint32_t x0, uint32_t x1,
                                              uint32_t& o0, uint32_t& o1)
{
  uint32_t k2 = k0 ^ k1 ^ 0x1BD11BDAu;
  x0 += k0; x1 += k1;
#define TF_R(r) x0 += x1; x1 = (x1 << (r)) | (x1 >> (32 - (r))); x1 ^= x0;
  TF_R(13) TF_R(15) TF_R(26) TF_R(6)
  x0 += k1; x1 += k2 + 1u;
  TF_R(17) TF_R(29) TF_R(16) TF_R(24)
  x0 += k2; x1 += k0 + 2u;
  TF_R(13) TF_R(15) TF_R(26) TF_R(6)
  x0 += k0; x1 += k1 + 3u;
  TF_R(17) TF_R(29) TF_R(16) TF_R(24)
  x0 += k1; x1 += k2 + 4u;
  TF_R(13) TF_R(15) TF_R(26) TF_R(6)
  x0 += k2; x1 += k0 + 5u;
#undef TF_R
  o0 = x0; o1 = x1;
}

__device__ __forceinline__ uint32_t rbits(uint32_t ka, uint32_t kb, uint32_t i)
{
  uint32_t o0, o1;
  tf2x32(ka, kb, 0u, i, o0, o1);
  return o0 ^ o1;
}

__device__ __forceinline__ float erfinv_xla(float x)
{
  float w = -log1pf(-__fmul_rn(x, x));
  float p;
  if (w < 5.0f) {
    w = __fsub_rn(w, 2.5f);
    p = 2.81022636e-08f;
    p = __fadd_rn( 3.43273939e-07f, __fmul_rn(p, w));
    p = __fadd_rn(-3.5233877e-06f,  __fmul_rn(p, w));
    p = __fadd_rn(-4.39150654e-06f, __fmul_rn(p, w));
    p = __fadd_rn( 0.00021858087f,  __fmul_rn(p, w));
    p = __fadd_rn(-0.00125372503f,  __fmul_rn(p, w));
    p = __fadd_rn(-0.00417768164f,  __fmul_rn(p, w));
    p = __fadd_rn( 0.246640727f,    __fmul_rn(p, w));
    p = __fadd_rn( 1.50140941f,     __fmul_rn(p, w));
  } else {
    w = __fsub_rn(sqrtf(w), 3.0f);
    p = -0.000200214257f;
    p = __fadd_rn( 0.000100950558f, __fmul_rn(p, w));
    p = __fadd_rn( 0.00134934322f,  __fmul_rn(p, w));
    p = __fadd_rn(-0.00367342844f,  __fmul_rn(p, w));
    p = __fadd_rn( 0.00573950773f,  __fmul_rn(p, w));
    p = __fadd_rn(-0.0076224613f,   __fmul_rn(p, w));
    p = __fadd_rn( 0.00943887047f,  __fmul_rn(p, w));
    p = __fadd_rn( 1.00167406f,     __fmul_rn(p, w));
    p = __fadd_rn( 2.83297682f,     __fmul_rn(p, w));
  }
  return __fmul_rn(p, x);
}

__device__ __forceinline__ float jax_normal(uint32_t bits)
{
  float f = __fsub_rn(__uint_as_float((bits >> 9) | 0x3F800000u), 1.0f);
  const float lo = -0.99999994f;
  float u = __fadd_rn(__fmul_rn(f, 2.0f), lo);
  u = fmaxf(lo, u);
  return __fmul_rn(1.41421356f, erfinv_xla(u));
}

__device__ __forceinline__ ushort_t f2bf(float x)
{
  uint32_t u = __float_as_uint(x);
  return (ushort_t)((u + 0x7FFFu + ((u >> 16) & 1u)) >> 16);
}

__device__ __forceinline__ void bfsplit(float x, ushort_t& hi, ushort_t& lo)
{
  uint32_t u = __float_as_uint(x);
  hi = (ushort_t)(u >> 16);
  float r = x - __uint_as_float(u & 0xFFFF0000u);
  lo = f2bf(r);
}

// ---- G2/G3 phase (f32 A staged+BN+split into LDS; split-bf16 MFMA) ----
template<int K, int CONC, int EPI>
__device__ __forceinline__ void ph_mfs(
    const float* __restrict__ Af, const float* __restrict__ Sf,
    const float* __restrict__ partIn, const float* __restrict__ g,
    const float* __restrict__ be,
    const ushort_t* __restrict__ Whi, const ushort_t* __restrict__ Wlo,
    const float* __restrict__ b0, const float* __restrict__ b1,
    float* __restrict__ Of32, float* __restrict__ partOut,
    float* __restrict__ ps, float* __restrict__ outp, int t,
    int task, char* smem)
{
  constexpr int KP = K + 8;
  const int tid = threadIdx.x;
  const int w = tid >> 6, l = tid & 63;
  const int mt = task >> 3, M0 = mt * 16;
  const int N0 = (task & 7) * 64 + w * 16;
  const int lm = l & 15, lk = l >> 4;

  ushort_t (*Ahi)[KP] = (ushort_t(*)[KP])smem;
  ushort_t (*Alo)[KP] = (ushort_t(*)[KP])(smem + SM_ALO);
  float2* scsh = (float2*)(smem + SM_SCSH);

  for (int c = tid; c < 512; c += 256) {
    const float2* pp = (const float2*)partIn + c * 32;
    float s = 0.0f, q = 0.0f;
    #pragma unroll
    for (int m = 0; m < 32; ++m) { float2 v = pp[m]; s += v.x; q += v.y; }
    float mn  = s * (1.0f / 512.0f);
    float var = q * (1.0f / 512.0f) - mn * mn;
    float inv = 1.0f / sqrtf(var + 1e-5f);
    float sc  = inv * g[c];
    scsh[c] = make_float2(sc, be[c] - mn * sc);
  }
  __syncthreads();

  for (int r = 0; r < 16; ++r) {
    for (int c = tid; c < K; c += 256) {
      float v;
      if constexpr (CONC) {
        if (c < 512) { float2 ss = scsh[c];
          v = __builtin_fmaf(Af[(M0 + r) * 512 + c], ss.x, ss.y); }
        else v = Sf[(M0 + r) * 64 + (c - 512)];
      } else {
        float2 ss = scsh[c];
        v = __builtin_fmaf(Af[(M0 + r) * K + c], ss.x, ss.y);
      }
      ushort_t hi, lo;
      bfsplit(v, hi, lo);
      Ahi[r][c] = hi; Alo[r][c] = lo;
    }
  }
  __syncthreads();

  const ushort_t* bhrow = Whi + (N0 + lm) * K;
  const ushort_t* blrow = Wlo + (N0 + lm) * K;
  f32x4 acc = {0.0f, 0.0f, 0.0f, 0.0f};
  #pragma unroll
  for (int ks = 0; ks < K / 32; ++ks) {
    const int kb = ks * 32 + lk * 8;
    short8v ah = *reinterpret_cast<const short8v*>(&Ahi[lm][kb]);
    short8v al = *reinterpret_cast<const short8v*>(&Alo[lm][kb]);
    short8v wh = *reinterpret_cast<const short8v*>(bhrow + kb);
    short8v wl = *reinterpret_cast<const short8v*>(blrow + kb);
    acc = __builtin_amdgcn_mfma_f32_16x16x32_bf16(ah, wh, acc, 0, 0, 0);
    acc = __builtin_amdgcn_mfma_f32_16x16x32_bf16(ah, wl, acc, 0, 0, 0);
    acc = __builtin_amdgcn_mfma_f32_16x16x32_bf16(al, wh, acc, 0, 0, 0);
  }

  const int n = N0 + lm;
  if constexpr (EPI == 0) {
    float bias = b0[n];
    float s = 0.0f, q = 0.0f;
    #pragma unroll
    for (int j = 0; j < 4; ++j) {
      float xv = fmaxf(acc[j] + bias, 0.0f);
      s += xv; q += xv * xv;
      Of32[(M0 + lk * 4 + j) * 512 + n] = xv;
    }
    s += __shfl_xor(s, 16); s += __shfl_xor(s, 32);
    q += __shfl_xor(q, 16); q += __shfl_xor(q, 32);
    if (l < 16) ((float2*)partOut)[n * 32 + mt] = make_float2(s, q);
  } else {
    if (N0 < 256) {
      float bias = b0[n];
      #pragma unroll
      for (int j = 0; j < 4; ++j) {
        float xv = acc[j] + bias;
        int m = M0 + lk * 4 + j;
        outp[MUO_OFF + (m * NT + t) * NH + n] = xv;
      }
    } else {
      float bias = b1[n - 256];
      float s = 0.0f, q = 0.0f;
      #pragma unroll
      for (int j = 0; j < 4; ++j) {
        float xv = acc[j] + bias;
        xv = (xv > 0.0f ? xv : expm1f(xv)) + 1.0f + 1e-12f;
        s += xv; q += xv * xv;
        ps[(M0 + lk * 4 + j) * NH + (n - 256)] = xv;
      }
      s += __shfl_xor(s, 16); s += __shfl_xor(s, 32);
      q += __shfl_xor(q, 16); q += __shfl_xor(q, 32);
      if (l < 16) ((float2*)partOut)[(n - 256) * 32 + mt] = make_float2(s, q);
    }
  }
}

// ---- G5 phase (emission heads + sample from z-table; 128 tasks) ----
__device__ __forceinline__ void ph_g5(
    const float* __restrict__ Ef, const ushort_t* __restrict__ Whi,
    const ushort_t* __restrict__ Wlo,
    const float* __restrict__ partIn, const float* __restrict__ g,
    const float* __restrict__ be,
    const float* __restrict__ bm, const float* __restrict__ bs,
    const float* __restrict__ ze, float* __restrict__ outp, int t,
    int task, char* smem)
{
  constexpr int K = 512, KP = 520;
  const int tid = threadIdx.x;
  const int w = tid >> 6, l = tid & 63;
  const int mt = task >> 2, jg = task & 3;
  const int M0 = mt * 16;
  const int lm = l & 15, lk = l >> 4;
  const bool isStd = (w >= 2);
  const int jl0 = (w & 1) * 16;
  const int N0 = (isStd ? 128 : 0) + jg * 32 + jl0;

  ushort_t (*Ahi)[KP] = (ushort_t(*)[KP])smem;
  ushort_t (*Alo)[KP] = (ushort_t(*)[KP])(smem + SM_ALO);
  float2* scsh = (float2*)(smem + SM_SCSH);
  float (*mean_s)[32] = (float(*)[32])(smem + SM_EXTRA);
  float (*std_s)[32]  = (float(*)[32])(smem + SM_EXTRA + 2048);

  for (int c = tid; c < 512; c += 256) {
    const float2* pp = (const float2*)partIn + c * 32;
    float s = 0.0f, q = 0.0f;
    #pragma unroll
    for (int m = 0; m < 32; ++m) { float2 v = pp[m]; s += v.x; q += v.y; }
    float mn  = s * (1.0f / 512.0f);
    float var = q * (1.0f / 512.0f) - mn * mn;
    float inv = 1.0f / sqrtf(var + 1e-5f);
    float sc  = inv * g[c];
    scsh[c] = make_float2(sc, be[c] - mn * sc);
  }
  __syncthreads();

  for (int r = 0; r < 16; ++r) {
    for (int c = tid; c < K; c += 256) {
      float2 ss = scsh[c];
      float v = __builtin_fmaf(Ef[(M0 + r) * 512 + c], ss.x, ss.y);
      ushort_t hi, lo;
      bfsplit(v, hi, lo);
      Ahi[r][c] = hi; Alo[r][c] = lo;
    }
  }
  __syncthreads();

  const ushort_t* bhrow = Whi + (N0 + lm) * K;
  const ushort_t* blrow = Wlo + (N0 + lm) * K;
  f32x4 acc = {0.0f, 0.0f, 0.0f, 0.0f};
  #pragma unroll
  for (int ks = 0; ks < 16; ++ks) {
    const int kb = ks * 32 + lk * 8;
    short8v ah = *reinterpret_cast<const short8v*>(&Ahi[lm][kb]);
    short8v al = *reinterpret_cast<const short8v*>(&Alo[lm][kb]);
    short8v wh = *reinterpret_cast<const short8v*>(bhrow + kb);
    short8v wl = *reinterpret_cast<const short8v*>(blrow + kb);
    acc = __builtin_amdgcn_mfma_f32_16x16x32_bf16(ah, wh, acc, 0, 0, 0);
    acc = __builtin_amdgcn_mfma_f32_16x16x32_bf16(ah, wl, acc, 0, 0, 0);
    acc = __builtin_amdgcn_mfma_f32_16x16x32_bf16(al, wh, acc, 0, 0, 0);
  }

  const int n = N0 + lm;
  float bias = isStd ? bs[n - 128] : bm[n];
  #pragma unroll
  for (int j = 0; j < 4; ++j) {
    float xv = acc[j] + bias;
    if (isStd) xv = (xv > 0.0f ? xv : expm1f(xv)) + 1.0f + 1e-12f;
    int r = lk * 4 + j, jl = jl0 + lm;
    if (isStd) std_s[r][jl] = xv; else mean_s[r][jl] = xv;
  }
  __syncthreads();

  for (int e = tid; e < 512; e += 256) {
    int r = e >> 5, jl = e & 31;
    int bb = M0 + r, j = jg * 32 + jl;
    float z = ze[(t - 1) * (NB * NO) + bb * NO + j];
    outp[(bb * NT + t) * NO + j] = __fadd_rn(mean_s[r][jl], __fmul_rn(std_s[r][jl], z));
  }
}

// ---------------- kernels ----------------

// fused init: x copy (float4), tables, weight split, z-tables (4-way ILP),
// coalesced pis
#define EWB 2048
#define NZH (19*NB*NH)
#define NZE (19*NB*NO)
__global__ __launch_bounds__(256) void k_init(Params p)
{
  __shared__ float hgs[20][257];
  const int tid = threadIdx.x;
  if (blockIdx.x < EWB) {
    const int gtid = blockIdx.x * 256 + tid;
    const int gsz = EWB * 256;
    // x passthrough, vectorized
    {
      const float4* xs4 = (const float4*)p.x;
      float4* dst4 = (float4*)(p.out + NB * NT * NO);
      for (int i = gtid; i < NB * NT * NO / 4; i += gsz) dst4[i] = xs4[i];
    }
    for (int i = gtid; i < NB * NO / 4; i += gsz) {
      int b = i / 32, j = i % 32;                  // 32 float4 per row
      ((float4*)(p.out + b * NT * NO))[j] = ((const float4*)(p.x + b * NT * NO))[j];
    }
    for (int i = gtid; i < NB * NH; i += gsz) {
      int b = i >> 8, h = i & 255;
      p.out[MUO_OFF  + (b * NT) * NH + h] = p.mu0[h];
      p.out[VARO_OFF + (b * NT) * NH + h] = p.var0[h];
    }
    for (int i = gtid; i < 950272; i += gsz) {
      float v; int ho, lo_;
      if (i < 131072) { v = p.tW1[i]; ho = U_WT1H + i; lo_ = U_WT1L + i; }
      else if (i < 425984) { int j = i - 131072; v = p.tW2[j]; ho = U_WT2H + j; lo_ = U_WT2L + j; }
      else if (i < 688128) { int j = i - 425984; int n = j >> 9, k = j & 511;
        v = (n < 256) ? p.tWm[n * 512 + k] : p.tWs[(n - 256) * 512 + k];
        ho = U_WMSH + j; lo_ = U_WMSL + j; }
      else if (i < 819200) { int j = i - 688128; v = p.eW1[j]; ho = U_WE1H + j; lo_ = U_WE1L + j; }
      else { int j = i - 819200; int n = j >> 9, k = j & 511;
        v = (n < 128) ? p.eWm[n * 512 + k] : p.eWs[(n - 128) * 512 + k];
        ho = U_WESH + j; lo_ = U_WESL + j; }
      ushort_t h, l;
      bfsplit(v, h, l);
      p.U[ho] = h; p.U[lo_] = l;
    }
    // z-tables: fused index space, 4-way unrolled for threefry-chain ILP
    const int NZ = NZH + NZE;
    for (int i = gtid; i < NZ; i += 4 * gsz) {
      #pragma unroll
      for (int u = 0; u < 4; ++u) {
        int idx = i + u * gsz;
        if (idx < NZ) {
          if (idx < NZH) {
            int tt = idx >> 17;
            p.zh[idx] = jax_normal(rbits(p.zk2[2 * tt], p.zk2[2 * tt + 1],
                                         (uint32_t)(idx & 131071)));
          } else {
            int e = idx - NZH;
            int tt = e >> 16;
            p.ze[e] = jax_normal(rbits(p.zk3[2 * tt], p.zk3[2 * tt + 1],
                                       (uint32_t)(e & 65535)));
          }
        }
      }
    }
  } else {
    // coalesced pis: one block per batch row b
    const int b = blockIdx.x - EWB;
    for (int i = tid; i < NT * NH; i += 256) {
      int r = i >> 8, c = i & 255;
      hgs[r][c] = p.h_gru[(b * NT + r) * NH + c];
    }
    __syncthreads();
    const int wid = tid >> 6, lane = tid & 63;
    for (int t = 1 + wid; t < NT; t += 4) {
      uint32_t kt0, kt1, k1a, k1b;
      tf2x32(0u, 42u, 0u, (uint32_t)t, kt0, kt1);
      tf2x32(kt0, kt1, 0u, 0u, k1a, k1b);
      float v = -__builtin_inff();
      int idx = 0x7FFFFFFF;
      if (lane < t) {
        float d = 0.0f;
        for (int h = 0; h < NH; ++h) d += hgs[t][h] * hgs[lane][h];
        float logit = d * 0.0625f;
        uint32_t bits = rbits(k1a, k1b, (uint32_t)(b * t + lane));
        float f = __fsub_rn(__uint_as_float((bits >> 9) | 0x3F800000u), 1.0f);
        const float tinyf = 1.1754943508222875e-38f;
        float u = fmaxf(tinyf, __fadd_rn(f, tinyf));
        float gmb = -logf(-logf(u));
        v = gmb + logit;
        idx = lane;
      }
      for (int off = 32; off; off >>= 1) {
        float ov = __shfl_xor(v, off);
        int oi = __shfl_xor(idx, off);
        if (ov > v || (ov == v && oi < idx)) { v = ov; idx = oi; }
      }
      if (lane == 0) p.pisA[t * NB + b] = idx;
    }
  }
}

// KA(t): G3(t)
__global__ __launch_bounds__(256) void k_A(Params p, int t)
{
  __shared__ __align__(16) char smem[SM_BYTES];
  ph_mfs<512, 0, 1>(p.a2f, nullptr, p.part2, p.tg2, p.tbe2,
                    p.U + U_WMSH, p.U + U_WMSL, p.tbm, p.tbs,
                    nullptr, p.partS, p.psf, p.out, t, blockIdx.x, smem);
}

// KB(t): fused — one block (mt,ng) builds the ht A-tile once; each wave runs
// the G1(t+1) tile and/or the G4(t) tile from the same LDS.
// t==0: A = broadcast split(h0), G1 only.
template<int DOG1, int DOG4>
__global__ __launch_bounds__(256) void k_B(Params p, int t)
{
  __shared__ __align__(16) char smem[24576];
  constexpr int KP = 264;
  ushort_t (*Ahi)[KP] = (ushort_t(*)[KP])smem;
  ushort_t (*Alo)[KP] = (ushort_t(*)[KP])(smem + 16 * KP * 2);
  float2* scsh = (float2*)(smem + 2 * 16 * KP * 2);      // 256 ch
  int* pis_s = (int*)(smem + 2 * 16 * KP * 2 + 2048);

  const int tid = threadIdx.x;
  const int mt = blockIdx.x >> 3, M0 = mt * 16, ng = blockIdx.x & 7;
  const int w = tid >> 6, l = tid & 63;
  const int lm = l & 15, lk = l >> 4;

  if (t == 0) {
    int c = tid;
    ushort_t hi, lo;
    bfsplit(p.h0[c], hi, lo);
    #pragma unroll
    for (int r = 0; r < 16; ++r) { Ahi[r][c] = hi; Alo[r][c] = lo; }
  } else {
    {
      int c = tid;
      const float2* pp = (const float2*)p.partS + c * 32;
      float s = 0.0f, q = 0.0f;
      #pragma unroll
      for (int m = 0; m < 32; ++m) { float2 v = pp[m]; s += v.x; q += v.y; }
      float mn  = s * (1.0f / 512.0f);
      float var = q * (1.0f / 512.0f) - mn * mn;
      float inv = 1.0f / sqrtf(var + 1e-5f);
      float sc  = inv * p.tgs[c];
      scsh[c] = make_float2(sc, p.tbes[c] - mn * sc);
    }
    if (tid < 16) pis_s[tid] = p.pisA[t * NB + M0 + tid];
    __syncthreads();
    const bool wv = (ng == 0);
    for (int e = tid; e < 4096; e += 256) {
      int r = e >> 8, c = e & 255;
      int b = M0 + r;
      float2 ss = scsh[c];
      float vt = p.psf[b * NH + c] * ss.x + ss.y;
      if (wv) p.out[VARO_OFF + (b * NT + t) * NH + c] = vt;
      int pp = pis_s[r];
      float mu = p.out[MUO_OFF + (b * NT + pp + 1) * NH + c];
      float sd = (pp == t - 1) ? vt : p.out[VARO_OFF + (b * NT + pp + 1) * NH + c];
      float z = p.zh[(t - 1) * (NB * NH) + b * NH + c];
      float ht = __fadd_rn(mu, __fmul_rn(sd, z));
      ushort_t hi, lo;
      bfsplit(ht, hi, lo);
      Ahi[r][c] = hi; Alo[r][c] = lo;
    }
  }
  __syncthreads();

  const int N0 = ng * 64 + w * 16;
  const int n = N0 + lm;

  if constexpr (DOG1) {
    const ushort_t* bhrow = p.U + U_WT1H + (N0 + lm) * 256;
    const ushort_t* blrow = p.U + U_WT1L + (N0 + lm) * 256;
    f32x4 acc = {0.0f, 0.0f, 0.0f, 0.0f};
    #pragma unroll
    for (int ks = 0; ks < 8; ++ks) {
      const int kb = ks * 32 + lk * 8;
      short8v ah = *reinterpret_cast<const short8v*>(&Ahi[lm][kb]);
      short8v al = *reinterpret_cast<const short8v*>(&Alo[lm][kb]);
      short8v wh = *reinterpret_cast<const short8v*>(bhrow + kb);
      short8v wl = *reinterpret_cast<const short8v*>(blrow + kb);
      acc = __builtin_amdgcn_mfma_f32_16x16x32_bf16(ah, wh, acc, 0, 0, 0);
      acc = __builtin_amdgcn_mfma_f32_16x16x32_bf16(ah, wl, acc, 0, 0, 0);
      acc = __builtin_amdgcn_mfma_f32_16x16x32_bf16(al, wh, acc, 0, 0, 0);
    }
    float bias = p.tb1[n];
    float s = 0.0f, q = 0.0f;
    #pragma unroll
    for (int j = 0; j < 4; ++j) {
      float xv = fmaxf(acc[j] + bias, 0.0f);
      s += xv; q += xv * xv;
      p.a1f[(M0 + lk * 4 + j) * 512 + n] = xv;
    }
    s += __shfl_xor(s, 16); s += __shfl_xor(s, 32);
    q += __shfl_xor(q, 16); q += __shfl_xor(q, 32);
    if (l < 16) ((float2*)p.part1)[n * 32 + mt] = make_float2(s, q);
  }

  if constexpr (DOG4) {
    const ushort_t* bhrow = p.U + U_WE1H + (N0 + lm) * 256;
    const ushort_t* blrow = p.U + U_WE1L + (N0 + lm) * 256;
    f32x4 acc = {0.0f, 0.0f, 0.0f, 0.0f};
    #pragma unroll
    for (int ks = 0; ks < 8; ++ks) {
      const int kb = ks * 32 + lk * 8;
      short8v ah = *reinterpret_cast<const short8v*>(&Ahi[lm][kb]);
      short8v al = *reinterpret_cast<const short8v*>(&Alo[lm][kb]);
      short8v wh = *reinterpret_cast<const short8v*>(bhrow + kb);
      short8v wl = *reinterpret_cast<const short8v*>(blrow + kb);
      acc = __builtin_amdgcn_mfma_f32_16x16x32_bf16(ah, wh, acc, 0, 0, 0);
      acc = __builtin_amdgcn_mfma_f32_16x16x32_bf16(ah, wl, acc, 0, 0, 0);
      acc = __builtin_amdgcn_mfma_f32_16x16x32_bf16(al, wh, acc, 0, 0, 0);
    }
    float bias = p.eb1[n];
    float s = 0.0f, q = 0.0f;
    #pragma unroll
    for (int j = 0; j < 4; ++j) {
      float xv = fmaxf(acc[j] + bias, 0.0f);
      s += xv; q += xv * xv;
      p.e1f[(M0 + lk * 4 + j) * 512 + n] = xv;
    }
    s += __shfl_xor(s, 16); s += __shfl_xor(s, 32);
    q += __shfl_xor(q, 16); q += __shfl_xor(q, 32);
    if (l < 16) ((float2*)p.partE)[n * 32 + mt] = make_float2(s, q);
  }
}

// KC(t): [G2(t+1)] and/or [G5(t)]
template<int HASG2, int HASG5>
__global__ __launch_bounds__(256) void k_C(Params p, int t)
{
  __shared__ __align__(16) char smem[SM_BYTES];
  const bool isG2 = HASG2 && ((int)blockIdx.x < 256);
  if (isG2) {
    ph_mfs<576, 1, 0>(p.a1f, p.s, p.part1, p.tg1, p.tbe1,
                      p.U + U_WT2H, p.U + U_WT2L, p.tb2, nullptr,
                      p.a2f, p.part2, nullptr, nullptr, 0, blockIdx.x, smem);
  } else {
    int task = blockIdx.x - (HASG2 ? 256 : 0);
    ph_g5(p.e1f, p.U + U_WESH, p.U + U_WESL, p.partE, p.eg1, p.ebe1,
          p.ebm, p.ebs, p.ze, p.out, t, task, smem);
  }
}

// ---------------- host ----------------

extern "C" void kernel_launch(void* const* d_in, const int* in_sizes, int n_in,
                              void* d_out, int out_size, void* d_ws, size_t ws_size,
                              hipStream_t stream)
{
  Params P;
  P.x    = (const float*)d_in[0];
  P.s    = (const float*)d_in[1];
  P.h_gru= (const float*)d_in[2];
  P.mu0  = (const float*)d_in[3];
  P.var0 = (const float*)d_in[4];
  P.h0   = (const float*)d_in[5];
  P.tW1  = (const float*)d_in[6];
  P.tb1  = (const float*)d_in[7];
  P.tg1  = (const float*)d_in[8];
  P.tbe1 = (const float*)d_in[9];
  P.tW2  = (const float*)d_in[10];
  P.tb2  = (const float*)d_in[11];
  P.tg2  = (const float*)d_in[12];
  P.tbe2 = (const float*)d_in[13];
  P.tWm  = (const float*)d_in[14];
  P.tbm  = (const float*)d_in[15];
  P.tWs  = (const float*)d_in[16];
  P.tbs  = (const float*)d_in[17];
  P.tgs  = (const float*)d_in[18];
  P.tbes = (const float*)d_in[19];
  P.eW1  = (const float*)d_in[20];
  P.eb1  = (const float*)d_in[21];
  P.eg1  = (const float*)d_in[22];
  P.ebe1 = (const float*)d_in[23];
  P.eWm  = (const float*)d_in[24];
  P.ebm  = (const float*)d_in[25];
  P.eWs  = (const float*)d_in[26];
  P.ebs  = (const float*)d_in[27];

  float* ws = (float*)d_ws;
  P.out   = (float*)d_out;
  P.psf   = ws + O_PS;
  P.a1f   = ws + O_A1;
  P.a2f   = ws + O_A2;
  P.e1f   = ws + O_E1;
  P.part1 = ws + O_P1;
  P.part2 = ws + O_P2;
  P.partS = ws + O_PSD;
  P.partE = ws + O_PE;
  P.pisA  = (int*)(ws + O_PIS);
  P.zh    = ws + O_ZH;
  P.ze    = ws + O_ZE;
  P.U     = (ushort_t*)(ws + O_USH);

  for (int t = 1; t < NT; ++t) {
    uint32_t kt0, kt1, a, b;
    tf2x32_h(0u, 42u, 0u, (uint32_t)t, kt0, kt1);
    tf2x32_h(kt0, kt1, 0u, 1u, a, b);
    P.zk2[2 * (t - 1)] = a; P.zk2[2 * (t - 1) + 1] = b;
    tf2x32_h(kt0, kt1, 0u, 2u, a, b);
    P.zk3[2 * (t - 1)] = a; P.zk3[2 * (t - 1) + 1] = b;
  }

  k_init<<<EWB + NB, 256, 0, stream>>>(P);

  // t = 0: G1(1) from h0, then G2(1)
  k_B<1, 0><<<256, 256, 0, stream>>>(P, 0);
  k_C<1, 0><<<256, 256, 0, stream>>>(P, 0);

  for (int t = 1; t < NT; ++t) {
    k_A<<<256, 256, 0, stream>>>(P, t);
    if (t < NT - 1) {
      k_B<1, 1><<<256, 256, 0, stream>>>(P, t);
      k_C<1, 1><<<384, 256, 0, stream>>>(P, t);
    } else {
      k_B<0, 1><<<256, 256, 0, stream>>>(P, t);
      k_C<0, 1><<<128, 256, 0, stream>>>(P, t);
    }
  }
}

// Round 18
// 1226.946 us; speedup vs baseline: 3.4595x; 1.1129x over previous
//
#include <hip/hip_runtime.h>
#include <stdint.h>

#define NB 512
#define NT 20
#define NH 256
#define NO 128
#define MUO_OFF (2*NB*NT*NO)
#define VARO_OFF (MUO_OFF + NB*NT*NH)

// ===== LEDGER =====
//  R6 6587 f32-serial; R7 1557 f32-tiled; R9 1627 split-bf16 MFMA; R10 coop 4245;
//  R12 1475; R14 1392; R17 PASS 1365 absmax 0.0625 (z-ILP+KB-fusion; k_init 68us;
//  steady state 22us/launch >> ~3us compute).
//  Theory: consumer BN prologues re-read the whole 128KB partial array per block
//  (32MB broadcast/launch, cross-XCD -> HBM) = the ~10us/launch mystery.
//  R18 (this): producer-side atomicAdd accumulation into per-step 4KB coeff
//  slots; consumers read 4KB, no reduction. FP-order jitter ~ulp (threshold .36).
//  Predict: PASS, absmax ~0.0625, 1000-1150us (or unchanged => launch floor).
// ==================

typedef __attribute__((ext_vector_type(8))) short short8v;
typedef __attribute__((ext_vector_type(4))) float f32x4;
typedef unsigned short ushort_t;

// ws float offsets
#define O_PS   0
#define O_A1   (O_PS + NB*NH)
#define O_A2   (O_A1 + 512*512)
#define O_E1   (O_A2 + 512*512)
#define O_PA1  (O_E1 + 512*512)        // 20 slots x 512ch x {s,q}
#define O_PA2  (O_PA1 + 20*1024)
#define O_PAS  (O_PA2 + 20*1024)       // 20 x 256 x 2
#define O_PAE  (O_PAS + 20*512)
#define O_PIS  (O_PAE + 20*1024)
#define O_ZH   (O_PIS + NT*NB)
#define O_ZE   (O_ZH + 19*NB*NH)
#define O_USH  (O_ZE + 19*NB*NO)
#define NPACC  (20*1024*3 + 20*512)    // pa1+pa2+paE + paS = 71680 floats
// ushort offsets within U (weight hi/lo splits)
#define U_WT1H 0
#define U_WT1L 131072
#define U_WT2H 262144
#define U_WT2L 557056
#define U_WMSH 851968
#define U_WMSL 1114112
#define U_WE1H 1376256
#define U_WE1L 1507328
#define U_WESH 1638400
#define U_WESL 1769472

// shared scratch layout (bytes) for K<=576 phases
#define SM_ALO   18688
#define SM_SCSH  37376
#define SM_EXTRA 41472
#define SM_BYTES 45568

struct Params {
  const float *x, *s, *h_gru, *mu0, *var0, *h0;
  const float *tb1, *tg1, *tbe1, *tb2, *tg2, *tbe2;
  const float *tbm, *tbs, *tgs, *tbes;
  const float *eb1, *eg1, *ebe1, *ebm, *ebs;
  const float *tW1, *tW2, *tWm, *tWs, *eW1, *eWm, *eWs;
  float* out;
  float *psf, *a1f, *a2f, *e1f;
  float *pa1, *pa2, *paS, *paE;
  float *zh, *ze;
  int* pisA;
  ushort_t* U;
  uint32_t zk2[38];
  uint32_t zk3[38];
};

__device__ __forceinline__ void tf2x32(uint32_t k0, uint32_t k1,
                                       uint32_t x0, uint32_t x1,
                                       uint32_t& o0, uint32_t& o1)
{
  uint32_t k2 = k0 ^ k1 ^ 0x1BD11BDAu;
  x0 += k0; x1 += k1;
#define TF_R(r) x0 += x1; x1 = (x1 << (r)) | (x1 >> (32 - (r))); x1 ^= x0;
  TF_R(13) TF_R(15) TF_R(26) TF_R(6)
  x0 += k1; x1 += k2 + 1u;
  TF_R(17) TF_R(29) TF_R(16) TF_R(24)
  x0 += k2; x1 += k0 + 2u;
  TF_R(13) TF_R(15) TF_R(26) TF_R(6)
  x0 += k0; x1 += k1 + 3u;
  TF_R(17) TF_R(29) TF_R(16) TF_R(24)
  x0 += k1; x1 += k2 + 4u;
  TF_R(13) TF_R(15) TF_R(26) TF_R(6)
  x0 += k2; x1 += k0 + 5u;
#undef TF_R
  o0 = x0; o1 = x1;
}

__host__ __forceinline__ static void tf2x32_h(uint32_t k0, uint32_t k1,
                                              uint32_t x0, uint32_t x1,
                                              uint32_t& o0, uint32_t& o1)
{
  uint32_t k2 = k0 ^ k1 ^ 0x1BD11BDAu;
  x0 += k0; x1 += k1;
#define TF_R(r) x0 += x1; x1 = (x1 << (r)) | (x1 >> (32 - (r))); x1 ^= x0;
  TF_R(13) TF_R(15) TF_R(26) TF_R(6)
  x0 += k1; x1 += k2 + 1u;
  TF_R(17) TF_R(29) TF_R(16) TF_R(24)
  x0 += k2; x1 += k0 + 2u;
  TF_R(13) TF_R(15) TF_R(26) TF_R(6)
  x0 += k0; x1 += k1 + 3u;
  TF_R(17) TF_R(29) TF_R(16) TF_R(24)
  x0 += k1; x1 += k2 + 4u;
  TF_R(13) TF_R(15) TF_R(26) TF_R(6)
  x0 += k2; x1 += k0 + 5u;
#undef TF_R
  o0 = x0; o1 = x1;
}

__device__ __forceinline__ uint32_t rbits(uint32_t ka, uint32_t kb, uint32_t i)
{
  uint32_t o0, o1;
  tf2x32(ka, kb, 0u, i, o0, o1);
  return o0 ^ o1;
}

__device__ __forceinline__ float erfinv_xla(float x)
{
  float w = -log1pf(-__fmul_rn(x, x));
  float p;
  if (w < 5.0f) {
    w = __fsub_rn(w, 2.5f);
    p = 2.81022636e-08f;
    p = __fadd_rn( 3.43273939e-07f, __fmul_rn(p, w));
    p = __fadd_rn(-3.5233877e-06f,  __fmul_rn(p, w));
    p = __fadd_rn(-4.39150654e-06f, __fmul_rn(p, w));
    p = __fadd_rn( 0.00021858087f,  __fmul_rn(p, w));
    p = __fadd_rn(-0.00125372503f,  __fmul_rn(p, w));
    p = __fadd_rn(-0.00417768164f,  __fmul_rn(p, w));
    p = __fadd_rn( 0.246640727f,    __fmul_rn(p, w));
    p = __fadd_rn( 1.50140941f,     __fmul_rn(p, w));
  } else {
    w = __fsub_rn(sqrtf(w), 3.0f);
    p = -0.000200214257f;
    p = __fadd_rn( 0.000100950558f, __fmul_rn(p, w));
    p = __fadd_rn( 0.00134934322f,  __fmul_rn(p, w));
    p = __fadd_rn(-0.00367342844f,  __fmul_rn(p, w));
    p = __fadd_rn( 0.00573950773f,  __fmul_rn(p, w));
    p = __fadd_rn(-0.0076224613f,   __fmul_rn(p, w));
    p = __fadd_rn( 0.00943887047f,  __fmul_rn(p, w));
    p = __fadd_rn( 1.00167406f,     __fmul_rn(p, w));
    p = __fadd_rn( 2.83297682f,     __fmul_rn(p, w));
  }
  return __fmul_rn(p, x);
}

__device__ __forceinline__ float jax_normal(uint32_t bits)
{
  float f = __fsub_rn(__uint_as_float((bits >> 9) | 0x3F800000u), 1.0f);
  const float lo = -0.99999994f;
  float u = __fadd_rn(__fmul_rn(f, 2.0f), lo);
  u = fmaxf(lo, u);
  return __fmul_rn(1.41421356f, erfinv_xla(u));
}

__device__ __forceinline__ ushort_t f2bf(float x)
{
  uint32_t u = __float_as_uint(x);
  return (ushort_t)((u + 0x7FFFu + ((u >> 16) & 1u)) >> 16);
}

__device__ __forceinline__ void bfsplit(float x, ushort_t& hi, ushort_t& lo)
{
  uint32_t u = __float_as_uint(x);
  hi = (ushort_t)(u >> 16);
  float r = x - __uint_as_float(u & 0xFFFF0000u);
  lo = f2bf(r);
}

// BN coefficients from accumulated (s,q): identical math to prior reduction tail
__device__ __forceinline__ float2 bn_coeff(float s, float q, float gv, float bev)
{
  float mn  = s * (1.0f / 512.0f);
  float var = q * (1.0f / 512.0f) - mn * mn;
  float inv = 1.0f / sqrtf(var + 1e-5f);
  float sc  = inv * gv;
  return make_float2(sc, bev - mn * sc);
}

// ---- G2/G3 phase ----
template<int K, int CONC, int EPI>
__device__ __forceinline__ void ph_mfs(
    const float* __restrict__ Af, const float* __restrict__ Sf,
    const float* __restrict__ cIn, const float* __restrict__ g,
    const float* __restrict__ be,
    const ushort_t* __restrict__ Whi, const ushort_t* __restrict__ Wlo,
    const float* __restrict__ b0, const float* __restrict__ b1,
    float* __restrict__ Of32, float* __restrict__ paOut,
    float* __restrict__ ps, float* __restrict__ outp, int t,
    int task, char* smem)
{
  constexpr int KP = K + 8;
  const int tid = threadIdx.x;
  const int w = tid >> 6, l = tid & 63;
  const int mt = task >> 3, M0 = mt * 16;
  const int N0 = (task & 7) * 64 + w * 16;
  const int lm = l & 15, lk = l >> 4;

  ushort_t (*Ahi)[KP] = (ushort_t(*)[KP])smem;
  ushort_t (*Alo)[KP] = (ushort_t(*)[KP])(smem + SM_ALO);
  float2* scsh = (float2*)(smem + SM_SCSH);

  for (int c = tid; c < 512; c += 256)
    scsh[c] = bn_coeff(cIn[2 * c], cIn[2 * c + 1], g[c], be[c]);
  __syncthreads();

  for (int r = 0; r < 16; ++r) {
    for (int c = tid; c < K; c += 256) {
      float v;
      if constexpr (CONC) {
        if (c < 512) { float2 ss = scsh[c];
          v = __builtin_fmaf(Af[(M0 + r) * 512 + c], ss.x, ss.y); }
        else v = Sf[(M0 + r) * 64 + (c - 512)];
      } else {
        float2 ss = scsh[c];
        v = __builtin_fmaf(Af[(M0 + r) * K + c], ss.x, ss.y);
      }
      ushort_t hi, lo;
      bfsplit(v, hi, lo);
      Ahi[r][c] = hi; Alo[r][c] = lo;
    }
  }
  __syncthreads();

  const ushort_t* bhrow = Whi + (N0 + lm) * K;
  const ushort_t* blrow = Wlo + (N0 + lm) * K;
  f32x4 acc = {0.0f, 0.0f, 0.0f, 0.0f};
  #pragma unroll
  for (int ks = 0; ks < K / 32; ++ks) {
    const int kb = ks * 32 + lk * 8;
    short8v ah = *reinterpret_cast<const short8v*>(&Ahi[lm][kb]);
    short8v al = *reinterpret_cast<const short8v*>(&Alo[lm][kb]);
    short8v wh = *reinterpret_cast<const short8v*>(bhrow + kb);
    short8v wl = *reinterpret_cast<const short8v*>(blrow + kb);
    acc = __builtin_amdgcn_mfma_f32_16x16x32_bf16(ah, wh, acc, 0, 0, 0);
    acc = __builtin_amdgcn_mfma_f32_16x16x32_bf16(ah, wl, acc, 0, 0, 0);
    acc = __builtin_amdgcn_mfma_f32_16x16x32_bf16(al, wh, acc, 0, 0, 0);
  }

  const int n = N0 + lm;
  if constexpr (EPI == 0) {
    float bias = b0[n];
    float s = 0.0f, q = 0.0f;
    #pragma unroll
    for (int j = 0; j < 4; ++j) {
      float xv = fmaxf(acc[j] + bias, 0.0f);
      s += xv; q += xv * xv;
      Of32[(M0 + lk * 4 + j) * 512 + n] = xv;
    }
    s += __shfl_xor(s, 16); s += __shfl_xor(s, 32);
    q += __shfl_xor(q, 16); q += __shfl_xor(q, 32);
    if (l < 16) { atomicAdd(&paOut[2 * n], s); atomicAdd(&paOut[2 * n + 1], q); }
  } else {
    if (N0 < 256) {
      float bias = b0[n];
      #pragma unroll
      for (int j = 0; j < 4; ++j) {
        float xv = acc[j] + bias;
        int m = M0 + lk * 4 + j;
        outp[MUO_OFF + (m * NT + t) * NH + n] = xv;
      }
    } else {
      float bias = b1[n - 256];
      float s = 0.0f, q = 0.0f;
      #pragma unroll
      for (int j = 0; j < 4; ++j) {
        float xv = acc[j] + bias;
        xv = (xv > 0.0f ? xv : expm1f(xv)) + 1.0f + 1e-12f;
        s += xv; q += xv * xv;
        ps[(M0 + lk * 4 + j) * NH + (n - 256)] = xv;
      }
      s += __shfl_xor(s, 16); s += __shfl_xor(s, 32);
      q += __shfl_xor(q, 16); q += __shfl_xor(q, 32);
      if (l < 16) { atomicAdd(&paOut[2 * (n - 256)], s);
                    atomicAdd(&paOut[2 * (n - 256) + 1], q); }
    }
  }
}

// ---- G5 phase ----
__device__ __forceinline__ void ph_g5(
    const float* __restrict__ Ef, const ushort_t* __restrict__ Whi,
    const ushort_t* __restrict__ Wlo,
    const float* __restrict__ cIn, const float* __restrict__ g,
    const float* __restrict__ be,
    const float* __restrict__ bm, const float* __restrict__ bs,
    const float* __restrict__ ze, float* __restrict__ outp, int t,
    int task, char* smem)
{
  constexpr int K = 512, KP = 520;
  const int tid = threadIdx.x;
  const int w = tid >> 6, l = tid & 63;
  const int mt = task >> 2, jg = task & 3;
  const int M0 = mt * 16;
  const int lm = l & 15, lk = l >> 4;
  const bool isStd = (w >= 2);
  const int jl0 = (w & 1) * 16;
  const int N0 = (isStd ? 128 : 0) + jg * 32 + jl0;

  ushort_t (*Ahi)[KP] = (ushort_t(*)[KP])smem;
  ushort_t (*Alo)[KP] = (ushort_t(*)[KP])(smem + SM_ALO);
  float2* scsh = (float2*)(smem + SM_SCSH);
  float (*mean_s)[32] = (float(*)[32])(smem + SM_EXTRA);
  float (*std_s)[32]  = (float(*)[32])(smem + SM_EXTRA + 2048);

  for (int c = tid; c < 512; c += 256)
    scsh[c] = bn_coeff(cIn[2 * c], cIn[2 * c + 1], g[c], be[c]);
  __syncthreads();

  for (int r = 0; r < 16; ++r) {
    for (int c = tid; c < K; c += 256) {
      float2 ss = scsh[c];
      float v = __builtin_fmaf(Ef[(M0 + r) * 512 + c], ss.x, ss.y);
      ushort_t hi, lo;
      bfsplit(v, hi, lo);
      Ahi[r][c] = hi; Alo[r][c] = lo;
    }
  }
  __syncthreads();

  const ushort_t* bhrow = Whi + (N0 + lm) * K;
  const ushort_t* blrow = Wlo + (N0 + lm) * K;
  f32x4 acc = {0.0f, 0.0f, 0.0f, 0.0f};
  #pragma unroll
  for (int ks = 0; ks < 16; ++ks) {
    const int kb = ks * 32 + lk * 8;
    short8v ah = *reinterpret_cast<const short8v*>(&Ahi[lm][kb]);
    short8v al = *reinterpret_cast<const short8v*>(&Alo[lm][kb]);
    short8v wh = *reinterpret_cast<const short8v*>(bhrow + kb);
    short8v wl = *reinterpret_cast<const short8v*>(blrow + kb);
    acc = __builtin_amdgcn_mfma_f32_16x16x32_bf16(ah, wh, acc, 0, 0, 0);
    acc = __builtin_amdgcn_mfma_f32_16x16x32_bf16(ah, wl, acc, 0, 0, 0);
    acc = __builtin_amdgcn_mfma_f32_16x16x32_bf16(al, wh, acc, 0, 0, 0);
  }

  const int n = N0 + lm;
  float bias = isStd ? bs[n - 128] : bm[n];
  #pragma unroll
  for (int j = 0; j < 4; ++j) {
    float xv = acc[j] + bias;
    if (isStd) xv = (xv > 0.0f ? xv : expm1f(xv)) + 1.0f + 1e-12f;
    int r = lk * 4 + j, jl = jl0 + lm;
    if (isStd) std_s[r][jl] = xv; else mean_s[r][jl] = xv;
  }
  __syncthreads();

  for (int e = tid; e < 512; e += 256) {
    int r = e >> 5, jl = e & 31;
    int bb = M0 + r, j = jg * 32 + jl;
    float z = ze[(t - 1) * (NB * NO) + bb * NO + j];
    outp[(bb * NT + t) * NO + j] = __fadd_rn(mean_s[r][jl], __fmul_rn(std_s[r][jl], z));
  }
}

// ---------------- kernels ----------------

#define EWB 2048
#define NZH (19*NB*NH)
#define NZE (19*NB*NO)
__global__ __launch_bounds__(256) void k_init(Params p)
{
  __shared__ float hgs[20][257];
  const int tid = threadIdx.x;
  if (blockIdx.x < EWB) {
    const int gtid = blockIdx.x * 256 + tid;
    const int gsz = EWB * 256;
    // zero the BN accumulators (pa1|pa2|paS|paE contiguous)
    for (int i = gtid; i < NPACC; i += gsz) p.pa1[i] = 0.0f;
    // x passthrough
    {
      const float4* xs4 = (const float4*)p.x;
      float4* dst4 = (float4*)(p.out + NB * NT * NO);
      for (int i = gtid; i < NB * NT * NO / 4; i += gsz) dst4[i] = xs4[i];
    }
    for (int i = gtid; i < NB * NO / 4; i += gsz) {
      int b = i / 32, j = i % 32;
      ((float4*)(p.out + b * NT * NO))[j] = ((const float4*)(p.x + b * NT * NO))[j];
    }
    for (int i = gtid; i < NB * NH; i += gsz) {
      int b = i >> 8, h = i & 255;
      p.out[MUO_OFF  + (b * NT) * NH + h] = p.mu0[h];
      p.out[VARO_OFF + (b * NT) * NH + h] = p.var0[h];
    }
    for (int i = gtid; i < 950272; i += gsz) {
      float v; int ho, lo_;
      if (i < 131072) { v = p.tW1[i]; ho = U_WT1H + i; lo_ = U_WT1L + i; }
      else if (i < 425984) { int j = i - 131072; v = p.tW2[j]; ho = U_WT2H + j; lo_ = U_WT2L + j; }
      else if (i < 688128) { int j = i - 425984; int n = j >> 9, k = j & 511;
        v = (n < 256) ? p.tWm[n * 512 + k] : p.tWs[(n - 256) * 512 + k];
        ho = U_WMSH + j; lo_ = U_WMSL + j; }
      else if (i < 819200) { int j = i - 688128; v = p.eW1[j]; ho = U_WE1H + j; lo_ = U_WE1L + j; }
      else { int j = i - 819200; int n = j >> 9, k = j & 511;
        v = (n < 128) ? p.eWm[n * 512 + k] : p.eWs[(n - 128) * 512 + k];
        ho = U_WESH + j; lo_ = U_WESL + j; }
      ushort_t h, l;
      bfsplit(v, h, l);
      p.U[ho] = h; p.U[lo_] = l;
    }
    // z-tables: fused index space, 4-way unrolled
    const int NZ = NZH + NZE;
    for (int i = gtid; i < NZ; i += 4 * gsz) {
      #pragma unroll
      for (int u = 0; u < 4; ++u) {
        int idx = i + u * gsz;
        if (idx < NZ) {
          if (idx < NZH) {
            int tt = idx >> 17;
            p.zh[idx] = jax_normal(rbits(p.zk2[2 * tt], p.zk2[2 * tt + 1],
                                         (uint32_t)(idx & 131071)));
          } else {
            int e = idx - NZH;
            int tt = e >> 16;
            p.ze[e] = jax_normal(rbits(p.zk3[2 * tt], p.zk3[2 * tt + 1],
                                       (uint32_t)(e & 65535)));
          }
        }
      }
    }
  } else {
    const int b = blockIdx.x - EWB;
    for (int i = tid; i < NT * NH; i += 256) {
      int r = i >> 8, c = i & 255;
      hgs[r][c] = p.h_gru[(b * NT + r) * NH + c];
    }
    __syncthreads();
    const int wid = tid >> 6, lane = tid & 63;
    for (int t = 1 + wid; t < NT; t += 4) {
      uint32_t kt0, kt1, k1a, k1b;
      tf2x32(0u, 42u, 0u, (uint32_t)t, kt0, kt1);
      tf2x32(kt0, kt1, 0u, 0u, k1a, k1b);
      float v = -__builtin_inff();
      int idx = 0x7FFFFFFF;
      if (lane < t) {
        float d = 0.0f;
        for (int h = 0; h < NH; ++h) d += hgs[t][h] * hgs[lane][h];
        float logit = d * 0.0625f;
        uint32_t bits = rbits(k1a, k1b, (uint32_t)(b * t + lane));
        float f = __fsub_rn(__uint_as_float((bits >> 9) | 0x3F800000u), 1.0f);
        const float tinyf = 1.1754943508222875e-38f;
        float u = fmaxf(tinyf, __fadd_rn(f, tinyf));
        float gmb = -logf(-logf(u));
        v = gmb + logit;
        idx = lane;
      }
      for (int off = 32; off; off >>= 1) {
        float ov = __shfl_xor(v, off);
        int oi = __shfl_xor(idx, off);
        if (ov > v || (ov == v && oi < idx)) { v = ov; idx = oi; }
      }
      if (lane == 0) p.pisA[t * NB + b] = idx;
    }
  }
}

// KA(t): G3(t); consumes pa2 slot t-1; produces paS slot t
__global__ __launch_bounds__(256) void k_A(Params p, int t)
{
  __shared__ __align__(16) char smem[SM_BYTES];
  ph_mfs<512, 0, 1>(p.a2f, nullptr, p.pa2 + (t - 1) * 1024, p.tg2, p.tbe2,
                    p.U + U_WMSH, p.U + U_WMSL, p.tbm, p.tbs,
                    nullptr, p.paS + t * 512, p.psf, p.out, t, blockIdx.x, smem);
}

// KB(t): ht(t)-prologue (consumes paS slot t) + G1(t+1)->pa1[t] / G4(t)->paE[t]
template<int DOG1, int DOG4>
__global__ __launch_bounds__(256) void k_B(Params p, int t)
{
  __shared__ __align__(16) char smem[24576];
  constexpr int KP = 264;
  ushort_t (*Ahi)[KP] = (ushort_t(*)[KP])smem;
  ushort_t (*Alo)[KP] = (ushort_t(*)[KP])(smem + 16 * KP * 2);
  float2* scsh = (float2*)(smem + 2 * 16 * KP * 2);
  int* pis_s = (int*)(smem + 2 * 16 * KP * 2 + 2048);

  const int tid = threadIdx.x;
  const int mt = blockIdx.x >> 3, M0 = mt * 16, ng = blockIdx.x & 7;
  const int w = tid >> 6, l = tid & 63;
  const int lm = l & 15, lk = l >> 4;

  if (t == 0) {
    int c = tid;
    ushort_t hi, lo;
    bfsplit(p.h0[c], hi, lo);
    #pragma unroll
    for (int r = 0; r < 16; ++r) { Ahi[r][c] = hi; Alo[r][c] = lo; }
  } else {
    {
      int c = tid;
      const float* cS = p.paS + t * 512;
      scsh[c] = bn_coeff(cS[2 * c], cS[2 * c + 1], p.tgs[c], p.tbes[c]);
    }
    if (tid < 16) pis_s[tid] = p.pisA[t * NB + M0 + tid];
    __syncthreads();
    const bool wv = (ng == 0);
    for (int e = tid; e < 4096; e += 256) {
      int r = e >> 8, c = e & 255;
      int b = M0 + r;
      float2 ss = scsh[c];
      float vt = p.psf[b * NH + c] * ss.x + ss.y;
      if (wv) p.out[VARO_OFF + (b * NT + t) * NH + c] = vt;
      int pp = pis_s[r];
      float mu = p.out[MUO_OFF + (b * NT + pp + 1) * NH + c];
      float sd = (pp == t - 1) ? vt : p.out[VARO_OFF + (b * NT + pp + 1) * NH + c];
      float z = p.zh[(t - 1) * (NB * NH) + b * NH + c];
      float ht = __fadd_rn(mu, __fmul_rn(sd, z));
      ushort_t hi, lo;
      bfsplit(ht, hi, lo);
      Ahi[r][c] = hi; Alo[r][c] = lo;
    }
  }
  __syncthreads();

  const int N0 = ng * 64 + w * 16;
  const int n = N0 + lm;

  if constexpr (DOG1) {
    const ushort_t* bhrow = p.U + U_WT1H + (N0 + lm) * 256;
    const ushort_t* blrow = p.U + U_WT1L + (N0 + lm) * 256;
    f32x4 acc = {0.0f, 0.0f, 0.0f, 0.0f};
    #pragma unroll
    for (int ks = 0; ks < 8; ++ks) {
      const int kb = ks * 32 + lk * 8;
      short8v ah = *reinterpret_cast<const short8v*>(&Ahi[lm][kb]);
      short8v al = *reinterpret_cast<const short8v*>(&Alo[lm][kb]);
      short8v wh = *reinterpret_cast<const short8v*>(bhrow + kb);
      short8v wl = *reinterpret_cast<const short8v*>(blrow + kb);
      acc = __builtin_amdgcn_mfma_f32_16x16x32_bf16(ah, wh, acc, 0, 0, 0);
      acc = __builtin_amdgcn_mfma_f32_16x16x32_bf16(ah, wl, acc, 0, 0, 0);
      acc = __builtin_amdgcn_mfma_f32_16x16x32_bf16(al, wh, acc, 0, 0, 0);
    }
    float bias = p.tb1[n];
    float s = 0.0f, q = 0.0f;
    #pragma unroll
    for (int j = 0; j < 4; ++j) {
      float xv = fmaxf(acc[j] + bias, 0.0f);
      s += xv; q += xv * xv;
      p.a1f[(M0 + lk * 4 + j) * 512 + n] = xv;
    }
    s += __shfl_xor(s, 16); s += __shfl_xor(s, 32);
    q += __shfl_xor(q, 16); q += __shfl_xor(q, 32);
    if (l < 16) { float* pa = p.pa1 + t * 1024;
      atomicAdd(&pa[2 * n], s); atomicAdd(&pa[2 * n + 1], q); }
  }

  if constexpr (DOG4) {
    const ushort_t* bhrow = p.U + U_WE1H + (N0 + lm) * 256;
    const ushort_t* blrow = p.U + U_WE1L + (N0 + lm) * 256;
    f32x4 acc = {0.0f, 0.0f, 0.0f, 0.0f};
    #pragma unroll
    for (int ks = 0; ks < 8; ++ks) {
      const int kb = ks * 32 + lk * 8;
      short8v ah = *reinterpret_cast<const short8v*>(&Ahi[lm][kb]);
      short8v al = *reinterpret_cast<const short8v*>(&Alo[lm][kb]);
      short8v wh = *reinterpret_cast<const short8v*>(bhrow + kb);
      short8v wl = *reinterpret_cast<const short8v*>(blrow + kb);
      acc = __builtin_amdgcn_mfma_f32_16x16x32_bf16(ah, wh, acc, 0, 0, 0);
      acc = __builtin_amdgcn_mfma_f32_16x16x32_bf16(ah, wl, acc, 0, 0, 0);
      acc = __builtin_amdgcn_mfma_f32_16x16x32_bf16(al, wh, acc, 0, 0, 0);
    }
    float bias = p.eb1[n];
    float s = 0.0f, q = 0.0f;
    #pragma unroll
    for (int j = 0; j < 4; ++j) {
      float xv = fmaxf(acc[j] + bias, 0.0f);
      s += xv; q += xv * xv;
      p.e1f[(M0 + lk * 4 + j) * 512 + n] = xv;
    }
    s += __shfl_xor(s, 16); s += __shfl_xor(s, 32);
    q += __shfl_xor(q, 16); q += __shfl_xor(q, 32);
    if (l < 16) { float* pa = p.paE + t * 1024;
      atomicAdd(&pa[2 * n], s); atomicAdd(&pa[2 * n + 1], q); }
  }
}

// KC(t): [G2(t+1): consumes pa1[t], produces pa2[t]] and/or [G5(t): consumes paE[t]]
template<int HASG2, int HASG5>
__global__ __launch_bounds__(256) void k_C(Params p, int t)
{
  __shared__ __align__(16) char smem[SM_BYTES];
  const bool isG2 = HASG2 && ((int)blockIdx.x < 256);
  if (isG2) {
    ph_mfs<576, 1, 0>(p.a1f, p.s, p.pa1 + t * 1024, p.tg1, p.tbe1,
                      p.U + U_WT2H, p.U + U_WT2L, p.tb2, nullptr,
                      p.a2f, p.pa2 + t * 1024, nullptr, nullptr, 0, blockIdx.x, smem);
  } else {
    int task = blockIdx.x - (HASG2 ? 256 : 0);
    ph_g5(p.e1f, p.U + U_WESH, p.U + U_WESL, p.paE + t * 1024, p.eg1, p.ebe1,
          p.ebm, p.ebs, p.ze, p.out, t, task, smem);
  }
}

// ---------------- host ----------------

extern "C" void kernel_launch(void* const* d_in, const int* in_sizes, int n_in,
                              void* d_out, int out_size, void* d_ws, size_t ws_size,
                              hipStream_t stream)
{
  Params P;
  P.x    = (const float*)d_in[0];
  P.s    = (const float*)d_in[1];
  P.h_gru= (const float*)d_in[2];
  P.mu0  = (const float*)d_in[3];
  P.var0 = (const float*)d_in[4];
  P.h0   = (const float*)d_in[5];
  P.tW1  = (const float*)d_in[6];
  P.tb1  = (const float*)d_in[7];
  P.tg1  = (const float*)d_in[8];
  P.tbe1 = (const float*)d_in[9];
  P.tW2  = (const float*)d_in[10];
  P.tb2  = (const float*)d_in[11];
  P.tg2  = (const float*)d_in[12];
  P.tbe2 = (const float*)d_in[13];
  P.tWm  = (const float*)d_in[14];
  P.tbm  = (const float*)d_in[15];
  P.tWs  = (const float*)d_in[16];
  P.tbs  = (const float*)d_in[17];
  P.tgs  = (const float*)d_in[18];
  P.tbes = (const float*)d_in[19];
  P.eW1  = (const float*)d_in[20];
  P.eb1  = (const float*)d_in[21];
  P.eg1  = (const float*)d_in[22];
  P.ebe1 = (const float*)d_in[23];
  P.eWm  = (const float*)d_in[24];
  P.ebm  = (const float*)d_in[25];
  P.eWs  = (const float*)d_in[26];
  P.ebs  = (const float*)d_in[27];

  float* ws = (float*)d_ws;
  P.out   = (float*)d_out;
  P.psf   = ws + O_PS;
  P.a1f   = ws + O_A1;
  P.a2f   = ws + O_A2;
  P.e1f   = ws + O_E1;
  P.pa1   = ws + O_PA1;
  P.pa2   = ws + O_PA2;
  P.paS   = ws + O_PAS;
  P.paE   = ws + O_PAE;
  P.pisA  = (int*)(ws + O_PIS);
  P.zh    = ws + O_ZH;
  P.ze    = ws + O_ZE;
  P.U     = (ushort_t*)(ws + O_USH);

  for (int t = 1; t < NT; ++t) {
    uint32_t kt0, kt1, a, b;
    tf2x32_h(0u, 42u, 0u, (uint32_t)t, kt0, kt1);
    tf2x32_h(kt0, kt1, 0u, 1u, a, b);
    P.zk2[2 * (t - 1)] = a; P.zk2[2 * (t - 1) + 1] = b;
    tf2x32_h(kt0, kt1, 0u, 2u, a, b);
    P.zk3[2 * (t - 1)] = a; P.zk3[2 * (t - 1) + 1] = b;
  }

  k_init<<<EWB + NB, 256, 0, stream>>>(P);

  // t = 0: G1(1) from h0, then G2(1)
  k_B<1, 0><<<256, 256, 0, stream>>>(P, 0);
  k_C<1, 0><<<256, 256, 0, stream>>>(P, 0);

  for (int t = 1; t < NT; ++t) {
    k_A<<<256, 256, 0, stream>>>(P, t);
    if (t < NT - 1) {
      k_B<1, 1><<<256, 256, 0, stream>>>(P, t);
      k_C<1, 1><<<384, 256, 0, stream>>>(P, t);
    } else {
      k_B<0, 1><<<256, 256, 0, stream>>>(P, t);
      k_C<0, 1><<<128, 256, 0, stream>>>(P, t);
    }
  }
}

// Round 19
// 809.177 us; speedup vs baseline: 5.2456x; 1.5163x over previous
//
#include <hip/hip_runtime.h>
#include <stdint.h>

#define NB 512
#define NT 20
#define NH 256
#define NO 128
#define MUO_OFF (2*NB*NT*NO)
#define VARO_OFF (MUO_OFF + NB*NT*NH)

// ===== LEDGER =====
//  R6 6587; R7 1557; R9 1627; R10 coop 4245; R12 1475; R14 1392; R17 1365;
//  R18 PASS 1227 absmax 0.0625 (atomic BN-stat slots, -2.4us/launch).
//  Remaining: 20us/launch vs ~3us compute; 1 block/CU = 1 wave/SIMD = no TLP;
//  k_init 67us (z-gen guards blocked ILP).
//  R19 (this): z-gen moved into k_A as 192 appended blocks (slot t-1, 4 elems/
//  thread unconditional); float4 staging everywhere; dual-acc MFMA (ph_mfs/ph_g5,
//  reassociation ~ulp); k_B G1+G4 merged loops sharing A-frags.
//  Predict: PASS, absmax ~0.0625 (<=0.12), 950-1100us, k_init ~20us.
// ==================

typedef __attribute__((ext_vector_type(8))) short short8v;
typedef __attribute__((ext_vector_type(4))) float f32x4;
typedef __attribute__((ext_vector_type(4))) unsigned short us4v;
typedef unsigned short ushort_t;

// ws float offsets
#define O_PS   0
#define O_A1   (O_PS + NB*NH)
#define O_A2   (O_A1 + 512*512)
#define O_E1   (O_A2 + 512*512)
#define O_PA1  (O_E1 + 512*512)
#define O_PA2  (O_PA1 + 20*1024)
#define O_PAS  (O_PA2 + 20*1024)
#define O_PAE  (O_PAS + 20*512)
#define O_PIS  (O_PAE + 20*1024)
#define O_ZH   (O_PIS + NT*NB)
#define O_ZE   (O_ZH + 19*NB*NH)
#define O_USH  (O_ZE + 19*NB*NO)
#define NPACC  (20*1024*3 + 20*512)
// ushort offsets within U
#define U_WT1H 0
#define U_WT1L 131072
#define U_WT2H 262144
#define U_WT2L 557056
#define U_WMSH 851968
#define U_WMSL 1114112
#define U_WE1H 1376256
#define U_WE1L 1507328
#define U_WESH 1638400
#define U_WESL 1769472

#define SM_ALO   18688
#define SM_SCSH  37376
#define SM_EXTRA 41472
#define SM_BYTES 45568

struct Params {
  const float *x, *s, *h_gru, *mu0, *var0, *h0;
  const float *tb1, *tg1, *tbe1, *tb2, *tg2, *tbe2;
  const float *tbm, *tbs, *tgs, *tbes;
  const float *eb1, *eg1, *ebe1, *ebm, *ebs;
  const float *tW1, *tW2, *tWm, *tWs, *eW1, *eWm, *eWs;
  float* out;
  float *psf, *a1f, *a2f, *e1f;
  float *pa1, *pa2, *paS, *paE;
  float *zh, *ze;
  int* pisA;
  ushort_t* U;
  uint32_t zk2[38];
  uint32_t zk3[38];
};

__device__ __forceinline__ void tf2x32(uint32_t k0, uint32_t k1,
                                       uint32_t x0, uint32_t x1,
                                       uint32_t& o0, uint32_t& o1)
{
  uint32_t k2 = k0 ^ k1 ^ 0x1BD11BDAu;
  x0 += k0; x1 += k1;
#define TF_R(r) x0 += x1; x1 = (x1 << (r)) | (x1 >> (32 - (r))); x1 ^= x0;
  TF_R(13) TF_R(15) TF_R(26) TF_R(6)
  x0 += k1; x1 += k2 + 1u;
  TF_R(17) TF_R(29) TF_R(16) TF_R(24)
  x0 += k2; x1 += k0 + 2u;
  TF_R(13) TF_R(15) TF_R(26) TF_R(6)
  x0 += k0; x1 += k1 + 3u;
  TF_R(17) TF_R(29) TF_R(16) TF_R(24)
  x0 += k1; x1 += k2 + 4u;
  TF_R(13) TF_R(15) TF_R(26) TF_R(6)
  x0 += k2; x1 += k0 + 5u;
#undef TF_R
  o0 = x0; o1 = x1;
}

__host__ __forceinline__ static void tf2x32_h(uint32_t k0, uint32_t k1,
                                              uint32_t x0, uint32_t x1,
                                              uint32_t& o0, uint32_t& o1)
{
  uint32_t k2 = k0 ^ k1 ^ 0x1BD11BDAu;
  x0 += k0; x1 += k1;
#define TF_R(r) x0 += x1; x1 = (x1 << (r)) | (x1 >> (32 - (r))); x1 ^= x0;
  TF_R(13) TF_R(15) TF_R(26) TF_R(6)
  x0 += k1; x1 += k2 + 1u;
  TF_R(17) TF_R(29) TF_R(16) TF_R(24)
  x0 += k2; x1 += k0 + 2u;
  TF_R(13) TF_R(15) TF_R(26) TF_R(6)
  x0 += k0; x1 += k1 + 3u;
  TF_R(17) TF_R(29) TF_R(16) TF_R(24)
  x0 += k1; x1 += k2 + 4u;
  TF_R(13) TF_R(15) TF_R(26) TF_R(6)
  x0 += k2; x1 += k0 + 5u;
#undef TF_R
  o0 = x0; o1 = x1;
}

__device__ __forceinline__ uint32_t rbits(uint32_t ka, uint32_t kb, uint32_t i)
{
  uint32_t o0, o1;
  tf2x32(ka, kb, 0u, i, o0, o1);
  return o0 ^ o1;
}

__device__ __forceinline__ float erfinv_xla(float x)
{
  float w = -log1pf(-__fmul_rn(x, x));
  float p;
  if (w < 5.0f) {
    w = __fsub_rn(w, 2.5f);
    p = 2.81022636e-08f;
    p = __fadd_rn( 3.43273939e-07f, __fmul_rn(p, w));
    p = __fadd_rn(-3.5233877e-06f,  __fmul_rn(p, w));
    p = __fadd_rn(-4.39150654e-06f, __fmul_rn(p, w));
    p = __fadd_rn( 0.00021858087f,  __fmul_rn(p, w));
    p = __fadd_rn(-0.00125372503f,  __fmul_rn(p, w));
    p = __fadd_rn(-0.00417768164f,  __fmul_rn(p, w));
    p = __fadd_rn( 0.246640727f,    __fmul_rn(p, w));
    p = __fadd_rn( 1.50140941f,     __fmul_rn(p, w));
  } else {
    w = __fsub_rn(sqrtf(w), 3.0f);
    p = -0.000200214257f;
    p = __fadd_rn( 0.000100950558f, __fmul_rn(p, w));
    p = __fadd_rn( 0.00134934322f,  __fmul_rn(p, w));
    p = __fadd_rn(-0.00367342844f,  __fmul_rn(p, w));
    p = __fadd_rn( 0.00573950773f,  __fmul_rn(p, w));
    p = __fadd_rn(-0.0076224613f,   __fmul_rn(p, w));
    p = __fadd_rn( 0.00943887047f,  __fmul_rn(p, w));
    p = __fadd_rn( 1.00167406f,     __fmul_rn(p, w));
    p = __fadd_rn( 2.83297682f,     __fmul_rn(p, w));
  }
  return __fmul_rn(p, x);
}

__device__ __forceinline__ float jax_normal(uint32_t bits)
{
  float f = __fsub_rn(__uint_as_float((bits >> 9) | 0x3F800000u), 1.0f);
  const float lo = -0.99999994f;
  float u = __fadd_rn(__fmul_rn(f, 2.0f), lo);
  u = fmaxf(lo, u);
  return __fmul_rn(1.41421356f, erfinv_xla(u));
}

__device__ __forceinline__ ushort_t f2bf(float x)
{
  uint32_t u = __float_as_uint(x);
  return (ushort_t)((u + 0x7FFFu + ((u >> 16) & 1u)) >> 16);
}

__device__ __forceinline__ void bfsplit(float x, ushort_t& hi, ushort_t& lo)
{
  uint32_t u = __float_as_uint(x);
  hi = (ushort_t)(u >> 16);
  float r = x - __uint_as_float(u & 0xFFFF0000u);
  lo = f2bf(r);
}

__device__ __forceinline__ float2 bn_coeff(float s, float q, float gv, float bev)
{
  float mn  = s * (1.0f / 512.0f);
  float var = q * (1.0f / 512.0f) - mn * mn;
  float inv = 1.0f / sqrtf(var + 1e-5f);
  float sc  = inv * gv;
  return make_float2(sc, bev - mn * sc);
}

// ---- G2/G3 phase (float4 staging; dual-acc MFMA) ----
template<int K, int CONC, int EPI>
__device__ __forceinline__ void ph_mfs(
    const float* __restrict__ Af, const float* __restrict__ Sf,
    const float* __restrict__ cIn, const float* __restrict__ g,
    const float* __restrict__ be,
    const ushort_t* __restrict__ Whi, const ushort_t* __restrict__ Wlo,
    const float* __restrict__ b0, const float* __restrict__ b1,
    float* __restrict__ Of32, float* __restrict__ paOut,
    float* __restrict__ ps, float* __restrict__ outp, int t,
    int task, char* smem)
{
  constexpr int KP = K + 8;
  const int tid = threadIdx.x;
  const int w = tid >> 6, l = tid & 63;
  const int mt = task >> 3, M0 = mt * 16;
  const int N0 = (task & 7) * 64 + w * 16;
  const int lm = l & 15, lk = l >> 4;

  ushort_t (*Ahi)[KP] = (ushort_t(*)[KP])smem;
  ushort_t (*Alo)[KP] = (ushort_t(*)[KP])(smem + SM_ALO);
  float2* scsh = (float2*)(smem + SM_SCSH);

  for (int c = tid; c < 512; c += 256)
    scsh[c] = bn_coeff(cIn[2 * c], cIn[2 * c + 1], g[c], be[c]);
  __syncthreads();

  constexpr int F4R = K / 4;           // float4 per row
  constexpr int NF4 = 16 * F4R;
  for (int e = tid; e < NF4; e += 256) {
    int r = e / F4R;
    int c4 = (e - r * F4R) * 4;
    float4 v4;
    if constexpr (CONC) {
      if (c4 < 512) {
        v4 = *reinterpret_cast<const float4*>(&Af[(M0 + r) * 512 + c4]);
        float2 s0 = scsh[c4], s1 = scsh[c4 + 1], s2 = scsh[c4 + 2], s3 = scsh[c4 + 3];
        v4.x = __builtin_fmaf(v4.x, s0.x, s0.y);
        v4.y = __builtin_fmaf(v4.y, s1.x, s1.y);
        v4.z = __builtin_fmaf(v4.z, s2.x, s2.y);
        v4.w = __builtin_fmaf(v4.w, s3.x, s3.y);
      } else {
        v4 = *reinterpret_cast<const float4*>(&Sf[(M0 + r) * 64 + (c4 - 512)]);
      }
    } else {
      v4 = *reinterpret_cast<const float4*>(&Af[(M0 + r) * K + c4]);
      float2 s0 = scsh[c4], s1 = scsh[c4 + 1], s2 = scsh[c4 + 2], s3 = scsh[c4 + 3];
      v4.x = __builtin_fmaf(v4.x, s0.x, s0.y);
      v4.y = __builtin_fmaf(v4.y, s1.x, s1.y);
      v4.z = __builtin_fmaf(v4.z, s2.x, s2.y);
      v4.w = __builtin_fmaf(v4.w, s3.x, s3.y);
    }
    us4v h4, l4;
    ushort_t hh, ll;
    bfsplit(v4.x, hh, ll); h4[0] = hh; l4[0] = ll;
    bfsplit(v4.y, hh, ll); h4[1] = hh; l4[1] = ll;
    bfsplit(v4.z, hh, ll); h4[2] = hh; l4[2] = ll;
    bfsplit(v4.w, hh, ll); h4[3] = hh; l4[3] = ll;
    *reinterpret_cast<us4v*>(&Ahi[r][c4]) = h4;
    *reinterpret_cast<us4v*>(&Alo[r][c4]) = l4;
  }
  __syncthreads();

  const ushort_t* bhrow = Whi + (N0 + lm) * K;
  const ushort_t* blrow = Wlo + (N0 + lm) * K;
  f32x4 acc0 = {0.0f, 0.0f, 0.0f, 0.0f};
  f32x4 acc1 = {0.0f, 0.0f, 0.0f, 0.0f};
  #pragma unroll
  for (int ks = 0; ks < K / 32; ks += 2) {
    {
      const int kb = ks * 32 + lk * 8;
      short8v ah = *reinterpret_cast<const short8v*>(&Ahi[lm][kb]);
      short8v al = *reinterpret_cast<const short8v*>(&Alo[lm][kb]);
      short8v wh = *reinterpret_cast<const short8v*>(bhrow + kb);
      short8v wl = *reinterpret_cast<const short8v*>(blrow + kb);
      acc0 = __builtin_amdgcn_mfma_f32_16x16x32_bf16(ah, wh, acc0, 0, 0, 0);
      acc0 = __builtin_amdgcn_mfma_f32_16x16x32_bf16(ah, wl, acc0, 0, 0, 0);
      acc0 = __builtin_amdgcn_mfma_f32_16x16x32_bf16(al, wh, acc0, 0, 0, 0);
    }
    if (ks + 1 < K / 32) {
      const int kb = (ks + 1) * 32 + lk * 8;
      short8v ah = *reinterpret_cast<const short8v*>(&Ahi[lm][kb]);
      short8v al = *reinterpret_cast<const short8v*>(&Alo[lm][kb]);
      short8v wh = *reinterpret_cast<const short8v*>(bhrow + kb);
      short8v wl = *reinterpret_cast<const short8v*>(blrow + kb);
      acc1 = __builtin_amdgcn_mfma_f32_16x16x32_bf16(ah, wh, acc1, 0, 0, 0);
      acc1 = __builtin_amdgcn_mfma_f32_16x16x32_bf16(ah, wl, acc1, 0, 0, 0);
      acc1 = __builtin_amdgcn_mfma_f32_16x16x32_bf16(al, wh, acc1, 0, 0, 0);
    }
  }
  f32x4 acc;
  acc[0] = acc0[0] + acc1[0];
  acc[1] = acc0[1] + acc1[1];
  acc[2] = acc0[2] + acc1[2];
  acc[3] = acc0[3] + acc1[3];

  const int n = N0 + lm;
  if constexpr (EPI == 0) {
    float bias = b0[n];
    float s = 0.0f, q = 0.0f;
    #pragma unroll
    for (int j = 0; j < 4; ++j) {
      float xv = fmaxf(acc[j] + bias, 0.0f);
      s += xv; q += xv * xv;
      Of32[(M0 + lk * 4 + j) * 512 + n] = xv;
    }
    s += __shfl_xor(s, 16); s += __shfl_xor(s, 32);
    q += __shfl_xor(q, 16); q += __shfl_xor(q, 32);
    if (l < 16) { atomicAdd(&paOut[2 * n], s); atomicAdd(&paOut[2 * n + 1], q); }
  } else {
    if (N0 < 256) {
      float bias = b0[n];
      #pragma unroll
      for (int j = 0; j < 4; ++j) {
        float xv = acc[j] + bias;
        int m = M0 + lk * 4 + j;
        outp[MUO_OFF + (m * NT + t) * NH + n] = xv;
      }
    } else {
      float bias = b1[n - 256];
      float s = 0.0f, q = 0.0f;
      #pragma unroll
      for (int j = 0; j < 4; ++j) {
        float xv = acc[j] + bias;
        xv = (xv > 0.0f ? xv : expm1f(xv)) + 1.0f + 1e-12f;
        s += xv; q += xv * xv;
        ps[(M0 + lk * 4 + j) * NH + (n - 256)] = xv;
      }
      s += __shfl_xor(s, 16); s += __shfl_xor(s, 32);
      q += __shfl_xor(q, 16); q += __shfl_xor(q, 32);
      if (l < 16) { atomicAdd(&paOut[2 * (n - 256)], s);
                    atomicAdd(&paOut[2 * (n - 256) + 1], q); }
    }
  }
}

// ---- G5 phase (float4 staging; dual-acc) ----
__device__ __forceinline__ void ph_g5(
    const float* __restrict__ Ef, const ushort_t* __restrict__ Whi,
    const ushort_t* __restrict__ Wlo,
    const float* __restrict__ cIn, const float* __restrict__ g,
    const float* __restrict__ be,
    const float* __restrict__ bm, const float* __restrict__ bs,
    const float* __restrict__ ze, float* __restrict__ outp, int t,
    int task, char* smem)
{
  constexpr int K = 512, KP = 520;
  const int tid = threadIdx.x;
  const int w = tid >> 6, l = tid & 63;
  const int mt = task >> 2, jg = task & 3;
  const int M0 = mt * 16;
  const int lm = l & 15, lk = l >> 4;
  const bool isStd = (w >= 2);
  const int jl0 = (w & 1) * 16;
  const int N0 = (isStd ? 128 : 0) + jg * 32 + jl0;

  ushort_t (*Ahi)[KP] = (ushort_t(*)[KP])smem;
  ushort_t (*Alo)[KP] = (ushort_t(*)[KP])(smem + SM_ALO);
  float2* scsh = (float2*)(smem + SM_SCSH);
  float (*mean_s)[32] = (float(*)[32])(smem + SM_EXTRA);
  float (*std_s)[32]  = (float(*)[32])(smem + SM_EXTRA + 2048);

  for (int c = tid; c < 512; c += 256)
    scsh[c] = bn_coeff(cIn[2 * c], cIn[2 * c + 1], g[c], be[c]);
  __syncthreads();

  for (int e = tid; e < 2048; e += 256) {
    int r = e >> 7, c4 = (e & 127) << 2;
    float4 v4 = *reinterpret_cast<const float4*>(&Ef[(M0 + r) * 512 + c4]);
    float2 s0 = scsh[c4], s1 = scsh[c4 + 1], s2 = scsh[c4 + 2], s3 = scsh[c4 + 3];
    v4.x = __builtin_fmaf(v4.x, s0.x, s0.y);
    v4.y = __builtin_fmaf(v4.y, s1.x, s1.y);
    v4.z = __builtin_fmaf(v4.z, s2.x, s2.y);
    v4.w = __builtin_fmaf(v4.w, s3.x, s3.y);
    us4v h4, l4;
    ushort_t hh, ll;
    bfsplit(v4.x, hh, ll); h4[0] = hh; l4[0] = ll;
    bfsplit(v4.y, hh, ll); h4[1] = hh; l4[1] = ll;
    bfsplit(v4.z, hh, ll); h4[2] = hh; l4[2] = ll;
    bfsplit(v4.w, hh, ll); h4[3] = hh; l4[3] = ll;
    *reinterpret_cast<us4v*>(&Ahi[r][c4]) = h4;
    *reinterpret_cast<us4v*>(&Alo[r][c4]) = l4;
  }
  __syncthreads();

  const ushort_t* bhrow = Whi + (N0 + lm) * K;
  const ushort_t* blrow = Wlo + (N0 + lm) * K;
  f32x4 acc0 = {0.0f, 0.0f, 0.0f, 0.0f};
  f32x4 acc1 = {0.0f, 0.0f, 0.0f, 0.0f};
  #pragma unroll
  for (int ks = 0; ks < 16; ks += 2) {
    {
      const int kb = ks * 32 + lk * 8;
      short8v ah = *reinterpret_cast<const short8v*>(&Ahi[lm][kb]);
      short8v al = *reinterpret_cast<const short8v*>(&Alo[lm][kb]);
      short8v wh = *reinterpret_cast<const short8v*>(bhrow + kb);
      short8v wl = *reinterpret_cast<const short8v*>(blrow + kb);
      acc0 = __builtin_amdgcn_mfma_f32_16x16x32_bf16(ah, wh, acc0, 0, 0, 0);
      acc0 = __builtin_amdgcn_mfma_f32_16x16x32_bf16(ah, wl, acc0, 0, 0, 0);
      acc0 = __builtin_amdgcn_mfma_f32_16x16x32_bf16(al, wh, acc0, 0, 0, 0);
    }
    {
      const int kb = (ks + 1) * 32 + lk * 8;
      short8v ah = *reinterpret_cast<const short8v*>(&Ahi[lm][kb]);
      short8v al = *reinterpret_cast<const short8v*>(&Alo[lm][kb]);
      short8v wh = *reinterpret_cast<const short8v*>(bhrow + kb);
      short8v wl = *reinterpret_cast<const short8v*>(blrow + kb);
      acc1 = __builtin_amdgcn_mfma_f32_16x16x32_bf16(ah, wh, acc1, 0, 0, 0);
      acc1 = __builtin_amdgcn_mfma_f32_16x16x32_bf16(ah, wl, acc1, 0, 0, 0);
      acc1 = __builtin_amdgcn_mfma_f32_16x16x32_bf16(al, wh, acc1, 0, 0, 0);
    }
  }
  f32x4 acc;
  acc[0] = acc0[0] + acc1[0];
  acc[1] = acc0[1] + acc1[1];
  acc[2] = acc0[2] + acc1[2];
  acc[3] = acc0[3] + acc1[3];

  const int n = N0 + lm;
  float bias = isStd ? bs[n - 128] : bm[n];
  #pragma unroll
  for (int j = 0; j < 4; ++j) {
    float xv = acc[j] + bias;
    if (isStd) xv = (xv > 0.0f ? xv : expm1f(xv)) + 1.0f + 1e-12f;
    int r = lk * 4 + j, jl = jl0 + lm;
    if (isStd) std_s[r][jl] = xv; else mean_s[r][jl] = xv;
  }
  __syncthreads();

  for (int e = tid; e < 512; e += 256) {
    int r = e >> 5, jl = e & 31;
    int bb = M0 + r, j = jg * 32 + jl;
    float z = ze[(t - 1) * (NB * NO) + bb * NO + j];
    outp[(bb * NT + t) * NO + j] = __fadd_rn(mean_s[r][jl], __fmul_rn(std_s[r][jl], z));
  }
}

// ---------------- kernels ----------------

#define EWB 2048
#define NZH (19*NB*NH)
#define NZE (19*NB*NO)
__global__ __launch_bounds__(256) void k_init(Params p)
{
  __shared__ float hgs[20][257];
  const int tid = threadIdx.x;
  if (blockIdx.x < EWB) {
    const int gtid = blockIdx.x * 256 + tid;
    const int gsz = EWB * 256;
    for (int i = gtid; i < NPACC; i += gsz) p.pa1[i] = 0.0f;
    {
      const float4* xs4 = (const float4*)p.x;
      float4* dst4 = (float4*)(p.out + NB * NT * NO);
      for (int i = gtid; i < NB * NT * NO / 4; i += gsz) dst4[i] = xs4[i];
    }
    for (int i = gtid; i < NB * NO / 4; i += gsz) {
      int b = i / 32, j = i % 32;
      ((float4*)(p.out + b * NT * NO))[j] = ((const float4*)(p.x + b * NT * NO))[j];
    }
    for (int i = gtid; i < NB * NH; i += gsz) {
      int b = i >> 8, h = i & 255;
      p.out[MUO_OFF  + (b * NT) * NH + h] = p.mu0[h];
      p.out[VARO_OFF + (b * NT) * NH + h] = p.var0[h];
    }
    for (int i = gtid; i < 950272; i += gsz) {
      float v; int ho, lo_;
      if (i < 131072) { v = p.tW1[i]; ho = U_WT1H + i; lo_ = U_WT1L + i; }
      else if (i < 425984) { int j = i - 131072; v = p.tW2[j]; ho = U_WT2H + j; lo_ = U_WT2L + j; }
      else if (i < 688128) { int j = i - 425984; int n = j >> 9, k = j & 511;
        v = (n < 256) ? p.tWm[n * 512 + k] : p.tWs[(n - 256) * 512 + k];
        ho = U_WMSH + j; lo_ = U_WMSL + j; }
      else if (i < 819200) { int j = i - 688128; v = p.eW1[j]; ho = U_WE1H + j; lo_ = U_WE1L + j; }
      else { int j = i - 819200; int n = j >> 9, k = j & 511;
        v = (n < 128) ? p.eWm[n * 512 + k] : p.eWs[(n - 128) * 512 + k];
        ho = U_WESH + j; lo_ = U_WESL + j; }
      ushort_t h, l;
      bfsplit(v, h, l);
      p.U[ho] = h; p.U[lo_] = l;
    }
  } else {
    const int b = blockIdx.x - EWB;
    for (int i = tid; i < NT * NH; i += 256) {
      int r = i >> 8, c = i & 255;
      hgs[r][c] = p.h_gru[(b * NT + r) * NH + c];
    }
    __syncthreads();
    const int wid = tid >> 6, lane = tid & 63;
    for (int t = 1 + wid; t < NT; t += 4) {
      uint32_t kt0, kt1, k1a, k1b;
      tf2x32(0u, 42u, 0u, (uint32_t)t, kt0, kt1);
      tf2x32(kt0, kt1, 0u, 0u, k1a, k1b);
      float v = -__builtin_inff();
      int idx = 0x7FFFFFFF;
      if (lane < t) {
        float d = 0.0f;
        for (int h = 0; h < NH; ++h) d += hgs[t][h] * hgs[lane][h];
        float logit = d * 0.0625f;
        uint32_t bits = rbits(k1a, k1b, (uint32_t)(b * t + lane));
        float f = __fsub_rn(__uint_as_float((bits >> 9) | 0x3F800000u), 1.0f);
        const float tinyf = 1.1754943508222875e-38f;
        float u = fmaxf(tinyf, __fadd_rn(f, tinyf));
        float gmb = -logf(-logf(u));
        v = gmb + logit;
        idx = lane;
      }
      for (int off = 32; off; off >>= 1) {
        float ov = __shfl_xor(v, off);
        int oi = __shfl_xor(idx, off);
        if (ov > v || (ov == v && oi < idx)) { v = ov; idx = oi; }
      }
      if (lane == 0) p.pisA[t * NB + b] = idx;
    }
  }
}

// KA(t): blocks [0,256) = G3(t); blocks [256,448) = z-gen slot t-1 (4 elems/thr)
__global__ __launch_bounds__(256) void k_A(Params p, int t)
{
  if ((int)blockIdx.x >= 256) {
    const int tt = t - 1;
    const uint32_t ka2 = p.zk2[2 * tt], kb2 = p.zk2[2 * tt + 1];
    const uint32_t ka3 = p.zk3[2 * tt], kb3 = p.zk3[2 * tt + 1];
    float* zhS = p.zh + tt * (NB * NH);
    float* zeS = p.ze + tt * (NB * NO);
    const int base = ((int)blockIdx.x - 256) * 256 + (int)threadIdx.x;
    #pragma unroll
    for (int u = 0; u < 4; ++u) {
      int idx = base + u * 49152;          // 192 blocks * 256 thr
      if (idx < 131072) zhS[idx] = jax_normal(rbits(ka2, kb2, (uint32_t)idx));
      else zeS[idx - 131072] = jax_normal(rbits(ka3, kb3, (uint32_t)(idx - 131072)));
    }
    return;
  }
  __shared__ __align__(16) char smem[SM_BYTES];
  ph_mfs<512, 0, 1>(p.a2f, nullptr, p.pa2 + (t - 1) * 1024, p.tg2, p.tbe2,
                    p.U + U_WMSH, p.U + U_WMSL, p.tbm, p.tbs,
                    nullptr, p.paS + t * 512, p.psf, p.out, t, blockIdx.x, smem);
}

// KB(t): ht(t)-prologue (float4) + merged G1(t+1)/G4(t) MFMA sharing A-frags
template<int DOG1, int DOG4>
__global__ __launch_bounds__(256) void k_B(Params p, int t)
{
  __shared__ __align__(16) char smem[24576];
  constexpr int KP = 264;
  ushort_t (*Ahi)[KP] = (ushort_t(*)[KP])smem;
  ushort_t (*Alo)[KP] = (ushort_t(*)[KP])(smem + 16 * KP * 2);
  float2* scsh = (float2*)(smem + 2 * 16 * KP * 2);
  int* pis_s = (int*)(smem + 2 * 16 * KP * 2 + 2048);

  const int tid = threadIdx.x;
  const int mt = blockIdx.x >> 3, M0 = mt * 16, ng = blockIdx.x & 7;
  const int w = tid >> 6, l = tid & 63;
  const int lm = l & 15, lk = l >> 4;

  if (t == 0) {
    int c = tid;
    ushort_t hi, lo;
    bfsplit(p.h0[c], hi, lo);
    #pragma unroll
    for (int r = 0; r < 16; ++r) { Ahi[r][c] = hi; Alo[r][c] = lo; }
  } else {
    {
      int c = tid;
      const float* cS = p.paS + t * 512;
      scsh[c] = bn_coeff(cS[2 * c], cS[2 * c + 1], p.tgs[c], p.tbes[c]);
    }
    if (tid < 16) pis_s[tid] = p.pisA[t * NB + M0 + tid];
    __syncthreads();
    const bool wv = (ng == 0);
    for (int e = tid; e < 1024; e += 256) {
      int r = e >> 6, c4 = (e & 63) << 2;
      int b = M0 + r;
      float4 ps4 = *reinterpret_cast<const float4*>(&p.psf[b * NH + c4]);
      float2 s0 = scsh[c4], s1 = scsh[c4 + 1], s2 = scsh[c4 + 2], s3 = scsh[c4 + 3];
      float4 vt4;
      vt4.x = ps4.x * s0.x + s0.y;
      vt4.y = ps4.y * s1.x + s1.y;
      vt4.z = ps4.z * s2.x + s2.y;
      vt4.w = ps4.w * s3.x + s3.y;
      if (wv) *reinterpret_cast<float4*>(&p.out[VARO_OFF + (b * NT + t) * NH + c4]) = vt4;
      int pp = pis_s[r];
      float4 mu4 = *reinterpret_cast<const float4*>(&p.out[MUO_OFF + (b * NT + pp + 1) * NH + c4]);
      float4 sd4 = (pp == t - 1) ? vt4
        : *reinterpret_cast<const float4*>(&p.out[VARO_OFF + (b * NT + pp + 1) * NH + c4]);
      float4 z4 = *reinterpret_cast<const float4*>(&p.zh[(t - 1) * (NB * NH) + b * NH + c4]);
      us4v h4, l4;
      ushort_t hh, ll;
      bfsplit(__fadd_rn(mu4.x, __fmul_rn(sd4.x, z4.x)), hh, ll); h4[0] = hh; l4[0] = ll;
      bfsplit(__fadd_rn(mu4.y, __fmul_rn(sd4.y, z4.y)), hh, ll); h4[1] = hh; l4[1] = ll;
      bfsplit(__fadd_rn(mu4.z, __fmul_rn(sd4.z, z4.z)), hh, ll); h4[2] = hh; l4[2] = ll;
      bfsplit(__fadd_rn(mu4.w, __fmul_rn(sd4.w, z4.w)), hh, ll); h4[3] = hh; l4[3] = ll;
      *reinterpret_cast<us4v*>(&Ahi[r][c4]) = h4;
      *reinterpret_cast<us4v*>(&Alo[r][c4]) = l4;
    }
  }
  __syncthreads();

  const int N0 = ng * 64 + w * 16;
  const int n = N0 + lm;

  if constexpr (DOG1 && DOG4) {
    const ushort_t* bhT = p.U + U_WT1H + (N0 + lm) * 256;
    const ushort_t* blT = p.U + U_WT1L + (N0 + lm) * 256;
    const ushort_t* bhE = p.U + U_WE1H + (N0 + lm) * 256;
    const ushort_t* blE = p.U + U_WE1L + (N0 + lm) * 256;
    f32x4 accT = {0.0f, 0.0f, 0.0f, 0.0f};
    f32x4 accE = {0.0f, 0.0f, 0.0f, 0.0f};
    #pragma unroll
    for (int ks = 0; ks < 8; ++ks) {
      const int kb = ks * 32 + lk * 8;
      short8v ah = *reinterpret_cast<const short8v*>(&Ahi[lm][kb]);
      short8v al = *reinterpret_cast<const short8v*>(&Alo[lm][kb]);
      short8v whT = *reinterpret_cast<const short8v*>(bhT + kb);
      short8v wlT = *reinterpret_cast<const short8v*>(blT + kb);
      short8v whE = *reinterpret_cast<const short8v*>(bhE + kb);
      short8v wlE = *reinterpret_cast<const short8v*>(blE + kb);
      accT = __builtin_amdgcn_mfma_f32_16x16x32_bf16(ah, whT, accT, 0, 0, 0);
      accE = __builtin_amdgcn_mfma_f32_16x16x32_bf16(ah, whE, accE, 0, 0, 0);
      accT = __builtin_amdgcn_mfma_f32_16x16x32_bf16(ah, wlT, accT, 0, 0, 0);
      accE = __builtin_amdgcn_mfma_f32_16x16x32_bf16(ah, wlE, accE, 0, 0, 0);
      accT = __builtin_amdgcn_mfma_f32_16x16x32_bf16(al, whT, accT, 0, 0, 0);
      accE = __builtin_amdgcn_mfma_f32_16x16x32_bf16(al, whE, accE, 0, 0, 0);
    }
    {
      float bias = p.tb1[n];
      float s = 0.0f, q = 0.0f;
      #pragma unroll
      for (int j = 0; j < 4; ++j) {
        float xv = fmaxf(accT[j] + bias, 0.0f);
        s += xv; q += xv * xv;
        p.a1f[(M0 + lk * 4 + j) * 512 + n] = xv;
      }
      s += __shfl_xor(s, 16); s += __shfl_xor(s, 32);
      q += __shfl_xor(q, 16); q += __shfl_xor(q, 32);
      if (l < 16) { float* pa = p.pa1 + t * 1024;
        atomicAdd(&pa[2 * n], s); atomicAdd(&pa[2 * n + 1], q); }
    }
    {
      float bias = p.eb1[n];
      float s = 0.0f, q = 0.0f;
      #pragma unroll
      for (int j = 0; j < 4; ++j) {
        float xv = fmaxf(accE[j] + bias, 0.0f);
        s += xv; q += xv * xv;
        p.e1f[(M0 + lk * 4 + j) * 512 + n] = xv;
      }
      s += __shfl_xor(s, 16); s += __shfl_xor(s, 32);
      q += __shfl_xor(q, 16); q += __shfl_xor(q, 32);
      if (l < 16) { float* pa = p.paE + t * 1024;
        atomicAdd(&pa[2 * n], s); atomicAdd(&pa[2 * n + 1], q); }
    }
  } else if constexpr (DOG1) {
    const ushort_t* bhrow = p.U + U_WT1H + (N0 + lm) * 256;
    const ushort_t* blrow = p.U + U_WT1L + (N0 + lm) * 256;
    f32x4 acc = {0.0f, 0.0f, 0.0f, 0.0f};
    #pragma unroll
    for (int ks = 0; ks < 8; ++ks) {
      const int kb = ks * 32 + lk * 8;
      short8v ah = *reinterpret_cast<const short8v*>(&Ahi[lm][kb]);
      short8v al = *reinterpret_cast<const short8v*>(&Alo[lm][kb]);
      short8v wh = *reinterpret_cast<const short8v*>(bhrow + kb);
      short8v wl = *reinterpret_cast<const short8v*>(blrow + kb);
      acc = __builtin_amdgcn_mfma_f32_16x16x32_bf16(ah, wh, acc, 0, 0, 0);
      acc = __builtin_amdgcn_mfma_f32_16x16x32_bf16(ah, wl, acc, 0, 0, 0);
      acc = __builtin_amdgcn_mfma_f32_16x16x32_bf16(al, wh, acc, 0, 0, 0);
    }
    float bias = p.tb1[n];
    float s = 0.0f, q = 0.0f;
    #pragma unroll
    for (int j = 0; j < 4; ++j) {
      float xv = fmaxf(acc[j] + bias, 0.0f);
      s += xv; q += xv * xv;
      p.a1f[(M0 + lk * 4 + j) * 512 + n] = xv;
    }
    s += __shfl_xor(s, 16); s += __shfl_xor(s, 32);
    q += __shfl_xor(q, 16); q += __shfl_xor(q, 32);
    if (l < 16) { float* pa = p.pa1 + t * 1024;
      atomicAdd(&pa[2 * n], s); atomicAdd(&pa[2 * n + 1], q); }
  } else {
    const ushort_t* bhrow = p.U + U_WE1H + (N0 + lm) * 256;
    const ushort_t* blrow = p.U + U_WE1L + (N0 + lm) * 256;
    f32x4 acc = {0.0f, 0.0f, 0.0f, 0.0f};
    #pragma unroll
    for (int ks = 0; ks < 8; ++ks) {
      const int kb = ks * 32 + lk * 8;
      short8v ah = *reinterpret_cast<const short8v*>(&Ahi[lm][kb]);
      short8v al = *reinterpret_cast<const short8v*>(&Alo[lm][kb]);
      short8v wh = *reinterpret_cast<const short8v*>(bhrow + kb);
      short8v wl = *reinterpret_cast<const short8v*>(blrow + kb);
      acc = __builtin_amdgcn_mfma_f32_16x16x32_bf16(ah, wh, acc, 0, 0, 0);
      acc = __builtin_amdgcn_mfma_f32_16x16x32_bf16(ah, wl, acc, 0, 0, 0);
      acc = __builtin_amdgcn_mfma_f32_16x16x32_bf16(al, wh, acc, 0, 0, 0);
    }
    float bias = p.eb1[n];
    float s = 0.0f, q = 0.0f;
    #pragma unroll
    for (int j = 0; j < 4; ++j) {
      float xv = fmaxf(acc[j] + bias, 0.0f);
      s += xv; q += xv * xv;
      p.e1f[(M0 + lk * 4 + j) * 512 + n] = xv;
    }
    s += __shfl_xor(s, 16); s += __shfl_xor(s, 32);
    q += __shfl_xor(q, 16); q += __shfl_xor(q, 32);
    if (l < 16) { float* pa = p.paE + t * 1024;
      atomicAdd(&pa[2 * n], s); atomicAdd(&pa[2 * n + 1], q); }
  }
}

// KC(t): [G2(t+1)] and/or [G5(t)]
template<int HASG2, int HASG5>
__global__ __launch_bounds__(256) void k_C(Params p, int t)
{
  __shared__ __align__(16) char smem[SM_BYTES];
  const bool isG2 = HASG2 && ((int)blockIdx.x < 256);
  if (isG2) {
    ph_mfs<576, 1, 0>(p.a1f, p.s, p.pa1 + t * 1024, p.tg1, p.tbe1,
                      p.U + U_WT2H, p.U + U_WT2L, p.tb2, nullptr,
                      p.a2f, p.pa2 + t * 1024, nullptr, nullptr, 0, blockIdx.x, smem);
  } else {
    int task = blockIdx.x - (HASG2 ? 256 : 0);
    ph_g5(p.e1f, p.U + U_WESH, p.U + U_WESL, p.paE + t * 1024, p.eg1, p.ebe1,
          p.ebm, p.ebs, p.ze, p.out, t, task, smem);
  }
}

// ---------------- host ----------------

extern "C" void kernel_launch(void* const* d_in, const int* in_sizes, int n_in,
                              void* d_out, int out_size, void* d_ws, size_t ws_size,
                              hipStream_t stream)
{
  Params P;
  P.x    = (const float*)d_in[0];
  P.s    = (const float*)d_in[1];
  P.h_gru= (const float*)d_in[2];
  P.mu0  = (const float*)d_in[3];
  P.var0 = (const float*)d_in[4];
  P.h0   = (const float*)d_in[5];
  P.tW1  = (const float*)d_in[6];
  P.tb1  = (const float*)d_in[7];
  P.tg1  = (const float*)d_in[8];
  P.tbe1 = (const float*)d_in[9];
  P.tW2  = (const float*)d_in[10];
  P.tb2  = (const float*)d_in[11];
  P.tg2  = (const float*)d_in[12];
  P.tbe2 = (const float*)d_in[13];
  P.tWm  = (const float*)d_in[14];
  P.tbm  = (const float*)d_in[15];
  P.tWs  = (const float*)d_in[16];
  P.tbs  = (const float*)d_in[17];
  P.tgs  = (const float*)d_in[18];
  P.tbes = (const float*)d_in[19];
  P.eW1  = (const float*)d_in[20];
  P.eb1  = (const float*)d_in[21];
  P.eg1  = (const float*)d_in[22];
  P.ebe1 = (const float*)d_in[23];
  P.eWm  = (const float*)d_in[24];
  P.ebm  = (const float*)d_in[25];
  P.eWs  = (const float*)d_in[26];
  P.ebs  = (const float*)d_in[27];

  float* ws = (float*)d_ws;
  P.out   = (float*)d_out;
  P.psf   = ws + O_PS;
  P.a1f   = ws + O_A1;
  P.a2f   = ws + O_A2;
  P.e1f   = ws + O_E1;
  P.pa1   = ws + O_PA1;
  P.pa2   = ws + O_PA2;
  P.paS   = ws + O_PAS;
  P.paE   = ws + O_PAE;
  P.pisA  = (int*)(ws + O_PIS);
  P.zh    = ws + O_ZH;
  P.ze    = ws + O_ZE;
  P.U     = (ushort_t*)(ws + O_USH);

  for (int t = 1; t < NT; ++t) {
    uint32_t kt0, kt1, a, b;
    tf2x32_h(0u, 42u, 0u, (uint32_t)t, kt0, kt1);
    tf2x32_h(kt0, kt1, 0u, 1u, a, b);
    P.zk2[2 * (t - 1)] = a; P.zk2[2 * (t - 1) + 1] = b;
    tf2x32_h(kt0, kt1, 0u, 2u, a, b);
    P.zk3[2 * (t - 1)] = a; P.zk3[2 * (t - 1) + 1] = b;
  }

  k_init<<<EWB + NB, 256, 0, stream>>>(P);

  // t = 0: G1(1) from h0, then G2(1)
  k_B<1, 0><<<256, 256, 0, stream>>>(P, 0);
  k_C<1, 0><<<256, 256, 0, stream>>>(P, 0);

  for (int t = 1; t < NT; ++t) {
    k_A<<<448, 256, 0, stream>>>(P, t);      // 256 G3 + 192 z-gen(slot t-1)
    if (t < NT - 1) {
      k_B<1, 1><<<256, 256, 0, stream>>>(P, t);
      k_C<1, 1><<<384, 256, 0, stream>>>(P, t);
    } else {
      k_B<0, 1><<<256, 256, 0, stream>>>(P, t);
      k_C<0, 1><<<128, 256, 0, stream>>>(P, t);
    }
  }
}

// Round 20
// 790.131 us; speedup vs baseline: 5.3721x; 1.0241x over previous
//
#include <hip/hip_runtime.h>
#include <stdint.h>

#define NB 512
#define NT 20
#define NH 256
#define NO 128
#define MUO_OFF (2*NB*NT*NO)
#define VARO_OFF (MUO_OFF + NB*NT*NH)

// ===== LEDGER =====
//  R6 6587; R7 1557; R9 1627; R10 coop 4245; R12 1475; R14 1392; R17 1365;
//  R18 1227; R19 PASS 809 absmax 0.0625 (float4 staging + dual-acc MFMA +
//  z-gen co-scheduled into k_A). Steady state 12.9us/launch ~ launch floor.
//  k_init 75us: weight split = 950K scalar loads, 5-way branch/elem, 2B stores.
//  R20 (this): vectorized weight split (float4 loads, ushort4 stores, branch
//  per 4 elems). Bit-identical. Predict 740-780us, k_init ~35us.
//  57-launch chain is structurally minimal (G3->ht->{G1,G4}->{G2,G5} deps;
//  grid.sync costs 30-45us per R10). Floor ~ 57*12 + 30 ~= 720us.
// ==================

typedef __attribute__((ext_vector_type(8))) short short8v;
typedef __attribute__((ext_vector_type(4))) float f32x4;
typedef __attribute__((ext_vector_type(4))) unsigned short us4v;
typedef unsigned short ushort_t;

// ws float offsets
#define O_PS   0
#define O_A1   (O_PS + NB*NH)
#define O_A2   (O_A1 + 512*512)
#define O_E1   (O_A2 + 512*512)
#define O_PA1  (O_E1 + 512*512)
#define O_PA2  (O_PA1 + 20*1024)
#define O_PAS  (O_PA2 + 20*1024)
#define O_PAE  (O_PAS + 20*512)
#define O_PIS  (O_PAE + 20*1024)
#define O_ZH   (O_PIS + NT*NB)
#define O_ZE   (O_ZH + 19*NB*NH)
#define O_USH  (O_ZE + 19*NB*NO)
#define NPACC  (20*1024*3 + 20*512)
// ushort offsets within U
#define U_WT1H 0
#define U_WT1L 131072
#define U_WT2H 262144
#define U_WT2L 557056
#define U_WMSH 851968
#define U_WMSL 1114112
#define U_WE1H 1376256
#define U_WE1L 1507328
#define U_WESH 1638400
#define U_WESL 1769472

#define SM_ALO   18688
#define SM_SCSH  37376
#define SM_EXTRA 41472
#define SM_BYTES 45568

struct Params {
  const float *x, *s, *h_gru, *mu0, *var0, *h0;
  const float *tb1, *tg1, *tbe1, *tb2, *tg2, *tbe2;
  const float *tbm, *tbs, *tgs, *tbes;
  const float *eb1, *eg1, *ebe1, *ebm, *ebs;
  const float *tW1, *tW2, *tWm, *tWs, *eW1, *eWm, *eWs;
  float* out;
  float *psf, *a1f, *a2f, *e1f;
  float *pa1, *pa2, *paS, *paE;
  float *zh, *ze;
  int* pisA;
  ushort_t* U;
  uint32_t zk2[38];
  uint32_t zk3[38];
};

__device__ __forceinline__ void tf2x32(uint32_t k0, uint32_t k1,
                                       uint32_t x0, uint32_t x1,
                                       uint32_t& o0, uint32_t& o1)
{
  uint32_t k2 = k0 ^ k1 ^ 0x1BD11BDAu;
  x0 += k0; x1 += k1;
#define TF_R(r) x0 += x1; x1 = (x1 << (r)) | (x1 >> (32 - (r))); x1 ^= x0;
  TF_R(13) TF_R(15) TF_R(26) TF_R(6)
  x0 += k1; x1 += k2 + 1u;
  TF_R(17) TF_R(29) TF_R(16) TF_R(24)
  x0 += k2; x1 += k0 + 2u;
  TF_R(13) TF_R(15) TF_R(26) TF_R(6)
  x0 += k0; x1 += k1 + 3u;
  TF_R(17) TF_R(29) TF_R(16) TF_R(24)
  x0 += k1; x1 += k2 + 4u;
  TF_R(13) TF_R(15) TF_R(26) TF_R(6)
  x0 += k2; x1 += k0 + 5u;
#undef TF_R
  o0 = x0; o1 = x1;
}

__host__ __forceinline__ static void tf2x32_h(uint32_t k0, uint32_t k1,
                                              uint32_t x0, uint32_t x1,
                                              uint32_t& o0, uint32_t& o1)
{
  uint32_t k2 = k0 ^ k1 ^ 0x1BD11BDAu;
  x0 += k0; x1 += k1;
#define TF_R(r) x0 += x1; x1 = (x1 << (r)) | (x1 >> (32 - (r))); x1 ^= x0;
  TF_R(13) TF_R(15) TF_R(26) TF_R(6)
  x0 += k1; x1 += k2 + 1u;
  TF_R(17) TF_R(29) TF_R(16) TF_R(24)
  x0 += k2; x1 += k0 + 2u;
  TF_R(13) TF_R(15) TF_R(26) TF_R(6)
  x0 += k0; x1 += k1 + 3u;
  TF_R(17) TF_R(29) TF_R(16) TF_R(24)
  x0 += k1; x1 += k2 + 4u;
  TF_R(13) TF_R(15) TF_R(26) TF_R(6)
  x0 += k2; x1 += k0 + 5u;
#undef TF_R
  o0 = x0; o1 = x1;
}

__device__ __forceinline__ uint32_t rbits(uint32_t ka, uint32_t kb, uint32_t i)
{
  uint32_t o0, o1;
  tf2x32(ka, kb, 0u, i, o0, o1);
  return o0 ^ o1;
}

__device__ __forceinline__ float erfinv_xla(float x)
{
  float w = -log1pf(-__fmul_rn(x, x));
  float p;
  if (w < 5.0f) {
    w = __fsub_rn(w, 2.5f);
    p = 2.81022636e-08f;
    p = __fadd_rn( 3.43273939e-07f, __fmul_rn(p, w));
    p = __fadd_rn(-3.5233877e-06f,  __fmul_rn(p, w));
    p = __fadd_rn(-4.39150654e-06f, __fmul_rn(p, w));
    p = __fadd_rn( 0.00021858087f,  __fmul_rn(p, w));
    p = __fadd_rn(-0.00125372503f,  __fmul_rn(p, w));
    p = __fadd_rn(-0.00417768164f,  __fmul_rn(p, w));
    p = __fadd_rn( 0.246640727f,    __fmul_rn(p, w));
    p = __fadd_rn( 1.50140941f,     __fmul_rn(p, w));
  } else {
    w = __fsub_rn(sqrtf(w), 3.0f);
    p = -0.000200214257f;
    p = __fadd_rn( 0.000100950558f, __fmul_rn(p, w));
    p = __fadd_rn( 0.00134934322f,  __fmul_rn(p, w));
    p = __fadd_rn(-0.00367342844f,  __fmul_rn(p, w));
    p = __fadd_rn( 0.00573950773f,  __fmul_rn(p, w));
    p = __fadd_rn(-0.0076224613f,   __fmul_rn(p, w));
    p = __fadd_rn( 0.00943887047f,  __fmul_rn(p, w));
    p = __fadd_rn( 1.00167406f,     __fmul_rn(p, w));
    p = __fadd_rn( 2.83297682f,     __fmul_rn(p, w));
  }
  return __fmul_rn(p, x);
}

__device__ __forceinline__ float jax_normal(uint32_t bits)
{
  float f = __fsub_rn(__uint_as_float((bits >> 9) | 0x3F800000u), 1.0f);
  const float lo = -0.99999994f;
  float u = __fadd_rn(__fmul_rn(f, 2.0f), lo);
  u = fmaxf(lo, u);
  return __fmul_rn(1.41421356f, erfinv_xla(u));
}

__device__ __forceinline__ ushort_t f2bf(float x)
{
  uint32_t u = __float_as_uint(x);
  return (ushort_t)((u + 0x7FFFu + ((u >> 16) & 1u)) >> 16);
}

__device__ __forceinline__ void bfsplit(float x, ushort_t& hi, ushort_t& lo)
{
  uint32_t u = __float_as_uint(x);
  hi = (ushort_t)(u >> 16);
  float r = x - __uint_as_float(u & 0xFFFF0000u);
  lo = f2bf(r);
}

__device__ __forceinline__ float2 bn_coeff(float s, float q, float gv, float bev)
{
  float mn  = s * (1.0f / 512.0f);
  float var = q * (1.0f / 512.0f) - mn * mn;
  float inv = 1.0f / sqrtf(var + 1e-5f);
  float sc  = inv * gv;
  return make_float2(sc, bev - mn * sc);
}

// ---- G2/G3 phase (float4 staging; dual-acc MFMA) ----
template<int K, int CONC, int EPI>
__device__ __forceinline__ void ph_mfs(
    const float* __restrict__ Af, const float* __restrict__ Sf,
    const float* __restrict__ cIn, const float* __restrict__ g,
    const float* __restrict__ be,
    const ushort_t* __restrict__ Whi, const ushort_t* __restrict__ Wlo,
    const float* __restrict__ b0, const float* __restrict__ b1,
    float* __restrict__ Of32, float* __restrict__ paOut,
    float* __restrict__ ps, float* __restrict__ outp, int t,
    int task, char* smem)
{
  constexpr int KP = K + 8;
  const int tid = threadIdx.x;
  const int w = tid >> 6, l = tid & 63;
  const int mt = task >> 3, M0 = mt * 16;
  const int N0 = (task & 7) * 64 + w * 16;
  const int lm = l & 15, lk = l >> 4;

  ushort_t (*Ahi)[KP] = (ushort_t(*)[KP])smem;
  ushort_t (*Alo)[KP] = (ushort_t(*)[KP])(smem + SM_ALO);
  float2* scsh = (float2*)(smem + SM_SCSH);

  for (int c = tid; c < 512; c += 256)
    scsh[c] = bn_coeff(cIn[2 * c], cIn[2 * c + 1], g[c], be[c]);
  __syncthreads();

  constexpr int F4R = K / 4;
  constexpr int NF4 = 16 * F4R;
  for (int e = tid; e < NF4; e += 256) {
    int r = e / F4R;
    int c4 = (e - r * F4R) * 4;
    float4 v4;
    if constexpr (CONC) {
      if (c4 < 512) {
        v4 = *reinterpret_cast<const float4*>(&Af[(M0 + r) * 512 + c4]);
        float2 s0 = scsh[c4], s1 = scsh[c4 + 1], s2 = scsh[c4 + 2], s3 = scsh[c4 + 3];
        v4.x = __builtin_fmaf(v4.x, s0.x, s0.y);
        v4.y = __builtin_fmaf(v4.y, s1.x, s1.y);
        v4.z = __builtin_fmaf(v4.z, s2.x, s2.y);
        v4.w = __builtin_fmaf(v4.w, s3.x, s3.y);
      } else {
        v4 = *reinterpret_cast<const float4*>(&Sf[(M0 + r) * 64 + (c4 - 512)]);
      }
    } else {
      v4 = *reinterpret_cast<const float4*>(&Af[(M0 + r) * K + c4]);
      float2 s0 = scsh[c4], s1 = scsh[c4 + 1], s2 = scsh[c4 + 2], s3 = scsh[c4 + 3];
      v4.x = __builtin_fmaf(v4.x, s0.x, s0.y);
      v4.y = __builtin_fmaf(v4.y, s1.x, s1.y);
      v4.z = __builtin_fmaf(v4.z, s2.x, s2.y);
      v4.w = __builtin_fmaf(v4.w, s3.x, s3.y);
    }
    us4v h4, l4;
    ushort_t hh, ll;
    bfsplit(v4.x, hh, ll); h4[0] = hh; l4[0] = ll;
    bfsplit(v4.y, hh, ll); h4[1] = hh; l4[1] = ll;
    bfsplit(v4.z, hh, ll); h4[2] = hh; l4[2] = ll;
    bfsplit(v4.w, hh, ll); h4[3] = hh; l4[3] = ll;
    *reinterpret_cast<us4v*>(&Ahi[r][c4]) = h4;
    *reinterpret_cast<us4v*>(&Alo[r][c4]) = l4;
  }
  __syncthreads();

  const ushort_t* bhrow = Whi + (N0 + lm) * K;
  const ushort_t* blrow = Wlo + (N0 + lm) * K;
  f32x4 acc0 = {0.0f, 0.0f, 0.0f, 0.0f};
  f32x4 acc1 = {0.0f, 0.0f, 0.0f, 0.0f};
  #pragma unroll
  for (int ks = 0; ks < K / 32; ks += 2) {
    {
      const int kb = ks * 32 + lk * 8;
      short8v ah = *reinterpret_cast<const short8v*>(&Ahi[lm][kb]);
      short8v al = *reinterpret_cast<const short8v*>(&Alo[lm][kb]);
      short8v wh = *reinterpret_cast<const short8v*>(bhrow + kb);
      short8v wl = *reinterpret_cast<const short8v*>(blrow + kb);
      acc0 = __builtin_amdgcn_mfma_f32_16x16x32_bf16(ah, wh, acc0, 0, 0, 0);
      acc0 = __builtin_amdgcn_mfma_f32_16x16x32_bf16(ah, wl, acc0, 0, 0, 0);
      acc0 = __builtin_amdgcn_mfma_f32_16x16x32_bf16(al, wh, acc0, 0, 0, 0);
    }
    if (ks + 1 < K / 32) {
      const int kb = (ks + 1) * 32 + lk * 8;
      short8v ah = *reinterpret_cast<const short8v*>(&Ahi[lm][kb]);
      short8v al = *reinterpret_cast<const short8v*>(&Alo[lm][kb]);
      short8v wh = *reinterpret_cast<const short8v*>(bhrow + kb);
      short8v wl = *reinterpret_cast<const short8v*>(blrow + kb);
      acc1 = __builtin_amdgcn_mfma_f32_16x16x32_bf16(ah, wh, acc1, 0, 0, 0);
      acc1 = __builtin_amdgcn_mfma_f32_16x16x32_bf16(ah, wl, acc1, 0, 0, 0);
      acc1 = __builtin_amdgcn_mfma_f32_16x16x32_bf16(al, wh, acc1, 0, 0, 0);
    }
  }
  f32x4 acc;
  acc[0] = acc0[0] + acc1[0];
  acc[1] = acc0[1] + acc1[1];
  acc[2] = acc0[2] + acc1[2];
  acc[3] = acc0[3] + acc1[3];

  const int n = N0 + lm;
  if constexpr (EPI == 0) {
    float bias = b0[n];
    float s = 0.0f, q = 0.0f;
    #pragma unroll
    for (int j = 0; j < 4; ++j) {
      float xv = fmaxf(acc[j] + bias, 0.0f);
      s += xv; q += xv * xv;
      Of32[(M0 + lk * 4 + j) * 512 + n] = xv;
    }
    s += __shfl_xor(s, 16); s += __shfl_xor(s, 32);
    q += __shfl_xor(q, 16); q += __shfl_xor(q, 32);
    if (l < 16) { atomicAdd(&paOut[2 * n], s); atomicAdd(&paOut[2 * n + 1], q); }
  } else {
    if (N0 < 256) {
      float bias = b0[n];
      #pragma unroll
      for (int j = 0; j < 4; ++j) {
        float xv = acc[j] + bias;
        int m = M0 + lk * 4 + j;
        outp[MUO_OFF + (m * NT + t) * NH + n] = xv;
      }
    } else {
      float bias = b1[n - 256];
      float s = 0.0f, q = 0.0f;
      #pragma unroll
      for (int j = 0; j < 4; ++j) {
        float xv = acc[j] + bias;
        xv = (xv > 0.0f ? xv : expm1f(xv)) + 1.0f + 1e-12f;
        s += xv; q += xv * xv;
        ps[(M0 + lk * 4 + j) * NH + (n - 256)] = xv;
      }
      s += __shfl_xor(s, 16); s += __shfl_xor(s, 32);
      q += __shfl_xor(q, 16); q += __shfl_xor(q, 32);
      if (l < 16) { atomicAdd(&paOut[2 * (n - 256)], s);
                    atomicAdd(&paOut[2 * (n - 256) + 1], q); }
    }
  }
}

// ---- G5 phase (float4 staging; dual-acc) ----
__device__ __forceinline__ void ph_g5(
    const float* __restrict__ Ef, const ushort_t* __restrict__ Whi,
    const ushort_t* __restrict__ Wlo,
    const float* __restrict__ cIn, const float* __restrict__ g,
    const float* __restrict__ be,
    const float* __restrict__ bm, const float* __restrict__ bs,
    const float* __restrict__ ze, float* __restrict__ outp, int t,
    int task, char* smem)
{
  constexpr int K = 512, KP = 520;
  const int tid = threadIdx.x;
  const int w = tid >> 6, l = tid & 63;
  const int mt = task >> 2, jg = task & 3;
  const int M0 = mt * 16;
  const int lm = l & 15, lk = l >> 4;
  const bool isStd = (w >= 2);
  const int jl0 = (w & 1) * 16;
  const int N0 = (isStd ? 128 : 0) + jg * 32 + jl0;

  ushort_t (*Ahi)[KP] = (ushort_t(*)[KP])smem;
  ushort_t (*Alo)[KP] = (ushort_t(*)[KP])(smem + SM_ALO);
  float2* scsh = (float2*)(smem + SM_SCSH);
  float (*mean_s)[32] = (float(*)[32])(smem + SM_EXTRA);
  float (*std_s)[32]  = (float(*)[32])(smem + SM_EXTRA + 2048);

  for (int c = tid; c < 512; c += 256)
    scsh[c] = bn_coeff(cIn[2 * c], cIn[2 * c + 1], g[c], be[c]);
  __syncthreads();

  for (int e = tid; e < 2048; e += 256) {
    int r = e >> 7, c4 = (e & 127) << 2;
    float4 v4 = *reinterpret_cast<const float4*>(&Ef[(M0 + r) * 512 + c4]);
    float2 s0 = scsh[c4], s1 = scsh[c4 + 1], s2 = scsh[c4 + 2], s3 = scsh[c4 + 3];
    v4.x = __builtin_fmaf(v4.x, s0.x, s0.y);
    v4.y = __builtin_fmaf(v4.y, s1.x, s1.y);
    v4.z = __builtin_fmaf(v4.z, s2.x, s2.y);
    v4.w = __builtin_fmaf(v4.w, s3.x, s3.y);
    us4v h4, l4;
    ushort_t hh, ll;
    bfsplit(v4.x, hh, ll); h4[0] = hh; l4[0] = ll;
    bfsplit(v4.y, hh, ll); h4[1] = hh; l4[1] = ll;
    bfsplit(v4.z, hh, ll); h4[2] = hh; l4[2] = ll;
    bfsplit(v4.w, hh, ll); h4[3] = hh; l4[3] = ll;
    *reinterpret_cast<us4v*>(&Ahi[r][c4]) = h4;
    *reinterpret_cast<us4v*>(&Alo[r][c4]) = l4;
  }
  __syncthreads();

  const ushort_t* bhrow = Whi + (N0 + lm) * K;
  const ushort_t* blrow = Wlo + (N0 + lm) * K;
  f32x4 acc0 = {0.0f, 0.0f, 0.0f, 0.0f};
  f32x4 acc1 = {0.0f, 0.0f, 0.0f, 0.0f};
  #pragma unroll
  for (int ks = 0; ks < 16; ks += 2) {
    {
      const int kb = ks * 32 + lk * 8;
      short8v ah = *reinterpret_cast<const short8v*>(&Ahi[lm][kb]);
      short8v al = *reinterpret_cast<const short8v*>(&Alo[lm][kb]);
      short8v wh = *reinterpret_cast<const short8v*>(bhrow + kb);
      short8v wl = *reinterpret_cast<const short8v*>(blrow + kb);
      acc0 = __builtin_amdgcn_mfma_f32_16x16x32_bf16(ah, wh, acc0, 0, 0, 0);
      acc0 = __builtin_amdgcn_mfma_f32_16x16x32_bf16(ah, wl, acc0, 0, 0, 0);
      acc0 = __builtin_amdgcn_mfma_f32_16x16x32_bf16(al, wh, acc0, 0, 0, 0);
    }
    {
      const int kb = (ks + 1) * 32 + lk * 8;
      short8v ah = *reinterpret_cast<const short8v*>(&Ahi[lm][kb]);
      short8v al = *reinterpret_cast<const short8v*>(&Alo[lm][kb]);
      short8v wh = *reinterpret_cast<const short8v*>(bhrow + kb);
      short8v wl = *reinterpret_cast<const short8v*>(blrow + kb);
      acc1 = __builtin_amdgcn_mfma_f32_16x16x32_bf16(ah, wh, acc1, 0, 0, 0);
      acc1 = __builtin_amdgcn_mfma_f32_16x16x32_bf16(ah, wl, acc1, 0, 0, 0);
      acc1 = __builtin_amdgcn_mfma_f32_16x16x32_bf16(al, wh, acc1, 0, 0, 0);
    }
  }
  f32x4 acc;
  acc[0] = acc0[0] + acc1[0];
  acc[1] = acc0[1] + acc1[1];
  acc[2] = acc0[2] + acc1[2];
  acc[3] = acc0[3] + acc1[3];

  const int n = N0 + lm;
  float bias = isStd ? bs[n - 128] : bm[n];
  #pragma unroll
  for (int j = 0; j < 4; ++j) {
    float xv = acc[j] + bias;
    if (isStd) xv = (xv > 0.0f ? xv : expm1f(xv)) + 1.0f + 1e-12f;
    int r = lk * 4 + j, jl = jl0 + lm;
    if (isStd) std_s[r][jl] = xv; else mean_s[r][jl] = xv;
  }
  __syncthreads();

  for (int e = tid; e < 512; e += 256) {
    int r = e >> 5, jl = e & 31;
    int bb = M0 + r, j = jg * 32 + jl;
    float z = ze[(t - 1) * (NB * NO) + bb * NO + j];
    outp[(bb * NT + t) * NO + j] = __fadd_rn(mean_s[r][jl], __fmul_rn(std_s[r][jl], z));
  }
}

// ---------------- kernels ----------------

#define EWB 2048
#define NZH (19*NB*NH)
#define NZE (19*NB*NO)
#define NW4 237568   // total weight float4s
__global__ __launch_bounds__(256) void k_init(Params p)
{
  __shared__ float hgs[20][257];
  const int tid = threadIdx.x;
  if (blockIdx.x < EWB) {
    const int gtid = blockIdx.x * 256 + tid;
    const int gsz = EWB * 256;
    for (int i = gtid; i < NPACC; i += gsz) p.pa1[i] = 0.0f;
    {
      const float4* xs4 = (const float4*)p.x;
      float4* dst4 = (float4*)(p.out + NB * NT * NO);
      for (int i = gtid; i < NB * NT * NO / 4; i += gsz) dst4[i] = xs4[i];
    }
    for (int i = gtid; i < NB * NO / 4; i += gsz) {
      int b = i / 32, j = i % 32;
      ((float4*)(p.out + b * NT * NO))[j] = ((const float4*)(p.x + b * NT * NO))[j];
    }
    for (int i = gtid; i < NB * NH; i += gsz) {
      int b = i >> 8, h = i & 255;
      p.out[MUO_OFF  + (b * NT) * NH + h] = p.mu0[h];
      p.out[VARO_OFF + (b * NT) * NH + h] = p.var0[h];
    }
    // vectorized weight split: 1 float4 + 1 branch per 4 elements
    for (int i4 = gtid; i4 < NW4; i4 += gsz) {
      int j4 = i4 << 2;
      float4 v4;
      int ho, lo_;
      if (j4 < 131072) {
        v4 = *reinterpret_cast<const float4*>(&p.tW1[j4]);
        ho = U_WT1H + j4; lo_ = U_WT1L + j4;
      } else if (j4 < 425984) {
        int j = j4 - 131072;
        v4 = *reinterpret_cast<const float4*>(&p.tW2[j]);
        ho = U_WT2H + j; lo_ = U_WT2L + j;
      } else if (j4 < 688128) {
        int j = j4 - 425984;
        int n = j >> 9, k = j & 511;
        const float* src = (n < 256) ? &p.tWm[n * 512 + k] : &p.tWs[(n - 256) * 512 + k];
        v4 = *reinterpret_cast<const float4*>(src);
        ho = U_WMSH + j; lo_ = U_WMSL + j;
      } else if (j4 < 819200) {
        int j = j4 - 688128;
        v4 = *reinterpret_cast<const float4*>(&p.eW1[j]);
        ho = U_WE1H + j; lo_ = U_WE1L + j;
      } else {
        int j = j4 - 819200;
        int n = j >> 9, k = j & 511;
        const float* src = (n < 128) ? &p.eWm[n * 512 + k] : &p.eWs[(n - 128) * 512 + k];
        v4 = *reinterpret_cast<const float4*>(src);
        ho = U_WESH + j; lo_ = U_WESL + j;
      }
      us4v h4, l4;
      ushort_t hh, ll;
      bfsplit(v4.x, hh, ll); h4[0] = hh; l4[0] = ll;
      bfsplit(v4.y, hh, ll); h4[1] = hh; l4[1] = ll;
      bfsplit(v4.z, hh, ll); h4[2] = hh; l4[2] = ll;
      bfsplit(v4.w, hh, ll); h4[3] = hh; l4[3] = ll;
      *reinterpret_cast<us4v*>(&p.U[ho]) = h4;
      *reinterpret_cast<us4v*>(&p.U[lo_]) = l4;
    }
  } else {
    const int b = blockIdx.x - EWB;
    for (int i = tid; i < NT * NH; i += 256) {
      int r = i >> 8, c = i & 255;
      hgs[r][c] = p.h_gru[(b * NT + r) * NH + c];
    }
    __syncthreads();
    const int wid = tid >> 6, lane = tid & 63;
    for (int t = 1 + wid; t < NT; t += 4) {
      uint32_t kt0, kt1, k1a, k1b;
      tf2x32(0u, 42u, 0u, (uint32_t)t, kt0, kt1);
      tf2x32(kt0, kt1, 0u, 0u, k1a, k1b);
      float v = -__builtin_inff();
      int idx = 0x7FFFFFFF;
      if (lane < t) {
        float d = 0.0f;
        for (int h = 0; h < NH; ++h) d += hgs[t][h] * hgs[lane][h];
        float logit = d * 0.0625f;
        uint32_t bits = rbits(k1a, k1b, (uint32_t)(b * t + lane));
        float f = __fsub_rn(__uint_as_float((bits >> 9) | 0x3F800000u), 1.0f);
        const float tinyf = 1.1754943508222875e-38f;
        float u = fmaxf(tinyf, __fadd_rn(f, tinyf));
        float gmb = -logf(-logf(u));
        v = gmb + logit;
        idx = lane;
      }
      for (int off = 32; off; off >>= 1) {
        float ov = __shfl_xor(v, off);
        int oi = __shfl_xor(idx, off);
        if (ov > v || (ov == v && oi < idx)) { v = ov; idx = oi; }
      }
      if (lane == 0) p.pisA[t * NB + b] = idx;
    }
  }
}

// KA(t): blocks [0,256) = G3(t); blocks [256,448) = z-gen slot t-1
__global__ __launch_bounds__(256) void k_A(Params p, int t)
{
  if ((int)blockIdx.x >= 256) {
    const int tt = t - 1;
    const uint32_t ka2 = p.zk2[2 * tt], kb2 = p.zk2[2 * tt + 1];
    const uint32_t ka3 = p.zk3[2 * tt], kb3 = p.zk3[2 * tt + 1];
    float* zhS = p.zh + tt * (NB * NH);
    float* zeS = p.ze + tt * (NB * NO);
    const int base = ((int)blockIdx.x - 256) * 256 + (int)threadIdx.x;
    #pragma unroll
    for (int u = 0; u < 4; ++u) {
      int idx = base + u * 49152;
      if (idx < 131072) zhS[idx] = jax_normal(rbits(ka2, kb2, (uint32_t)idx));
      else zeS[idx - 131072] = jax_normal(rbits(ka3, kb3, (uint32_t)(idx - 131072)));
    }
    return;
  }
  __shared__ __align__(16) char smem[SM_BYTES];
  ph_mfs<512, 0, 1>(p.a2f, nullptr, p.pa2 + (t - 1) * 1024, p.tg2, p.tbe2,
                    p.U + U_WMSH, p.U + U_WMSL, p.tbm, p.tbs,
                    nullptr, p.paS + t * 512, p.psf, p.out, t, blockIdx.x, smem);
}

// KB(t): ht(t)-prologue (float4) + merged G1(t+1)/G4(t) MFMA sharing A-frags
template<int DOG1, int DOG4>
__global__ __launch_bounds__(256) void k_B(Params p, int t)
{
  __shared__ __align__(16) char smem[24576];
  constexpr int KP = 264;
  ushort_t (*Ahi)[KP] = (ushort_t(*)[KP])smem;
  ushort_t (*Alo)[KP] = (ushort_t(*)[KP])(smem + 16 * KP * 2);
  float2* scsh = (float2*)(smem + 2 * 16 * KP * 2);
  int* pis_s = (int*)(smem + 2 * 16 * KP * 2 + 2048);

  const int tid = threadIdx.x;
  const int mt = blockIdx.x >> 3, M0 = mt * 16, ng = blockIdx.x & 7;
  const int w = tid >> 6, l = tid & 63;
  const int lm = l & 15, lk = l >> 4;

  if (t == 0) {
    int c = tid;
    ushort_t hi, lo;
    bfsplit(p.h0[c], hi, lo);
    #pragma unroll
    for (int r = 0; r < 16; ++r) { Ahi[r][c] = hi; Alo[r][c] = lo; }
  } else {
    {
      int c = tid;
      const float* cS = p.paS + t * 512;
      scsh[c] = bn_coeff(cS[2 * c], cS[2 * c + 1], p.tgs[c], p.tbes[c]);
    }
    if (tid < 16) pis_s[tid] = p.pisA[t * NB + M0 + tid];
    __syncthreads();
    const bool wv = (ng == 0);
    for (int e = tid; e < 1024; e += 256) {
      int r = e >> 6, c4 = (e & 63) << 2;
      int b = M0 + r;
      float4 ps4 = *reinterpret_cast<const float4*>(&p.psf[b * NH + c4]);
      float2 s0 = scsh[c4], s1 = scsh[c4 + 1], s2 = scsh[c4 + 2], s3 = scsh[c4 + 3];
      float4 vt4;
      vt4.x = ps4.x * s0.x + s0.y;
      vt4.y = ps4.y * s1.x + s1.y;
      vt4.z = ps4.z * s2.x + s2.y;
      vt4.w = ps4.w * s3.x + s3.y;
      if (wv) *reinterpret_cast<float4*>(&p.out[VARO_OFF + (b * NT + t) * NH + c4]) = vt4;
      int pp = pis_s[r];
      float4 mu4 = *reinterpret_cast<const float4*>(&p.out[MUO_OFF + (b * NT + pp + 1) * NH + c4]);
      float4 sd4 = (pp == t - 1) ? vt4
        : *reinterpret_cast<const float4*>(&p.out[VARO_OFF + (b * NT + pp + 1) * NH + c4]);
      float4 z4 = *reinterpret_cast<const float4*>(&p.zh[(t - 1) * (NB * NH) + b * NH + c4]);
      us4v h4, l4;
      ushort_t hh, ll;
      bfsplit(__fadd_rn(mu4.x, __fmul_rn(sd4.x, z4.x)), hh, ll); h4[0] = hh; l4[0] = ll;
      bfsplit(__fadd_rn(mu4.y, __fmul_rn(sd4.y, z4.y)), hh, ll); h4[1] = hh; l4[1] = ll;
      bfsplit(__fadd_rn(mu4.z, __fmul_rn(sd4.z, z4.z)), hh, ll); h4[2] = hh; l4[2] = ll;
      bfsplit(__fadd_rn(mu4.w, __fmul_rn(sd4.w, z4.w)), hh, ll); h4[3] = hh; l4[3] = ll;
      *reinterpret_cast<us4v*>(&Ahi[r][c4]) = h4;
      *reinterpret_cast<us4v*>(&Alo[r][c4]) = l4;
    }
  }
  __syncthreads();

  const int N0 = ng * 64 + w * 16;
  const int n = N0 + lm;

  if constexpr (DOG1 && DOG4) {
    const ushort_t* bhT = p.U + U_WT1H + (N0 + lm) * 256;
    const ushort_t* blT = p.U + U_WT1L + (N0 + lm) * 256;
    const ushort_t* bhE = p.U + U_WE1H + (N0 + lm) * 256;
    const ushort_t* blE = p.U + U_WE1L + (N0 + lm) * 256;
    f32x4 accT = {0.0f, 0.0f, 0.0f, 0.0f};
    f32x4 accE = {0.0f, 0.0f, 0.0f, 0.0f};
    #pragma unroll
    for (int ks = 0; ks < 8; ++ks) {
      const int kb = ks * 32 + lk * 8;
      short8v ah = *reinterpret_cast<const short8v*>(&Ahi[lm][kb]);
      short8v al = *reinterpret_cast<const short8v*>(&Alo[lm][kb]);
      short8v whT = *reinterpret_cast<const short8v*>(bhT + kb);
      short8v wlT = *reinterpret_cast<const short8v*>(blT + kb);
      short8v whE = *reinterpret_cast<const short8v*>(bhE + kb);
      short8v wlE = *reinterpret_cast<const short8v*>(blE + kb);
      accT = __builtin_amdgcn_mfma_f32_16x16x32_bf16(ah, whT, accT, 0, 0, 0);
      accE = __builtin_amdgcn_mfma_f32_16x16x32_bf16(ah, whE, accE, 0, 0, 0);
      accT = __builtin_amdgcn_mfma_f32_16x16x32_bf16(ah, wlT, accT, 0, 0, 0);
      accE = __builtin_amdgcn_mfma_f32_16x16x32_bf16(ah, wlE, accE, 0, 0, 0);
      accT = __builtin_amdgcn_mfma_f32_16x16x32_bf16(al, whT, accT, 0, 0, 0);
      accE = __builtin_amdgcn_mfma_f32_16x16x32_bf16(al, whE, accE, 0, 0, 0);
    }
    {
      float bias = p.tb1[n];
      float s = 0.0f, q = 0.0f;
      #pragma unroll
      for (int j = 0; j < 4; ++j) {
        float xv = fmaxf(accT[j] + bias, 0.0f);
        s += xv; q += xv * xv;
        p.a1f[(M0 + lk * 4 + j) * 512 + n] = xv;
      }
      s += __shfl_xor(s, 16); s += __shfl_xor(s, 32);
      q += __shfl_xor(q, 16); q += __shfl_xor(q, 32);
      if (l < 16) { float* pa = p.pa1 + t * 1024;
        atomicAdd(&pa[2 * n], s); atomicAdd(&pa[2 * n + 1], q); }
    }
    {
      float bias = p.eb1[n];
      float s = 0.0f, q = 0.0f;
      #pragma unroll
      for (int j = 0; j < 4; ++j) {
        float xv = fmaxf(accE[j] + bias, 0.0f);
        s += xv; q += xv * xv;
        p.e1f[(M0 + lk * 4 + j) * 512 + n] = xv;
      }
      s += __shfl_xor(s, 16); s += __shfl_xor(s, 32);
      q += __shfl_xor(q, 16); q += __shfl_xor(q, 32);
      if (l < 16) { float* pa = p.paE + t * 1024;
        atomicAdd(&pa[2 * n], s); atomicAdd(&pa[2 * n + 1], q); }
    }
  } else if constexpr (DOG1) {
    const ushort_t* bhrow = p.U + U_WT1H + (N0 + lm) * 256;
    const ushort_t* blrow = p.U + U_WT1L + (N0 + lm) * 256;
    f32x4 acc = {0.0f, 0.0f, 0.0f, 0.0f};
    #pragma unroll
    for (int ks = 0; ks < 8; ++ks) {
      const int kb = ks * 32 + lk * 8;
      short8v ah = *reinterpret_cast<const short8v*>(&Ahi[lm][kb]);
      short8v al = *reinterpret_cast<const short8v*>(&Alo[lm][kb]);
      short8v wh = *reinterpret_cast<const short8v*>(bhrow + kb);
      short8v wl = *reinterpret_cast<const short8v*>(blrow + kb);
      acc = __builtin_amdgcn_mfma_f32_16x16x32_bf16(ah, wh, acc, 0, 0, 0);
      acc = __builtin_amdgcn_mfma_f32_16x16x32_bf16(ah, wl, acc, 0, 0, 0);
      acc = __builtin_amdgcn_mfma_f32_16x16x32_bf16(al, wh, acc, 0, 0, 0);
    }
    float bias = p.tb1[n];
    float s = 0.0f, q = 0.0f;
    #pragma unroll
    for (int j = 0; j < 4; ++j) {
      float xv = fmaxf(acc[j] + bias, 0.0f);
      s += xv; q += xv * xv;
      p.a1f[(M0 + lk * 4 + j) * 512 + n] = xv;
    }
    s += __shfl_xor(s, 16); s += __shfl_xor(s, 32);
    q += __shfl_xor(q, 16); q += __shfl_xor(q, 32);
    if (l < 16) { float* pa = p.pa1 + t * 1024;
      atomicAdd(&pa[2 * n], s); atomicAdd(&pa[2 * n + 1], q); }
  } else {
    const ushort_t* bhrow = p.U + U_WE1H + (N0 + lm) * 256;
    const ushort_t* blrow = p.U + U_WE1L + (N0 + lm) * 256;
    f32x4 acc = {0.0f, 0.0f, 0.0f, 0.0f};
    #pragma unroll
    for (int ks = 0; ks < 8; ++ks) {
      const int kb = ks * 32 + lk * 8;
      short8v ah = *reinterpret_cast<const short8v*>(&Ahi[lm][kb]);
      short8v al = *reinterpret_cast<const short8v*>(&Alo[lm][kb]);
      short8v wh = *reinterpret_cast<const short8v*>(bhrow + kb);
      short8v wl = *reinterpret_cast<const short8v*>(blrow + kb);
      acc = __builtin_amdgcn_mfma_f32_16x16x32_bf16(ah, wh, acc, 0, 0, 0);
      acc = __builtin_amdgcn_mfma_f32_16x16x32_bf16(ah, wl, acc, 0, 0, 0);
      acc = __builtin_amdgcn_mfma_f32_16x16x32_bf16(al, wh, acc, 0, 0, 0);
    }
    float bias = p.eb1[n];
    float s = 0.0f, q = 0.0f;
    #pragma unroll
    for (int j = 0; j < 4; ++j) {
      float xv = fmaxf(acc[j] + bias, 0.0f);
      s += xv; q += xv * xv;
      p.e1f[(M0 + lk * 4 + j) * 512 + n] = xv;
    }
    s += __shfl_xor(s, 16); s += __shfl_xor(s, 32);
    q += __shfl_xor(q, 16); q += __shfl_xor(q, 32);
    if (l < 16) { float* pa = p.paE + t * 1024;
      atomicAdd(&pa[2 * n], s); atomicAdd(&pa[2 * n + 1], q); }
  }
}

// KC(t): [G2(t+1)] and/or [G5(t)]
template<int HASG2, int HASG5>
__global__ __launch_bounds__(256) void k_C(Params p, int t)
{
  __shared__ __align__(16) char smem[SM_BYTES];
  const bool isG2 = HASG2 && ((int)blockIdx.x < 256);
  if (isG2) {
    ph_mfs<576, 1, 0>(p.a1f, p.s, p.pa1 + t * 1024, p.tg1, p.tbe1,
                      p.U + U_WT2H, p.U + U_WT2L, p.tb2, nullptr,
                      p.a2f, p.pa2 + t * 1024, nullptr, nullptr, 0, blockIdx.x, smem);
  } else {
    int task = blockIdx.x - (HASG2 ? 256 : 0);
    ph_g5(p.e1f, p.U + U_WESH, p.U + U_WESL, p.paE + t * 1024, p.eg1, p.ebe1,
          p.ebm, p.ebs, p.ze, p.out, t, task, smem);
  }
}

// ---------------- host ----------------

extern "C" void kernel_launch(void* const* d_in, const int* in_sizes, int n_in,
                              void* d_out, int out_size, void* d_ws, size_t ws_size,
                              hipStream_t stream)
{
  Params P;
  P.x    = (const float*)d_in[0];
  P.s    = (const float*)d_in[1];
  P.h_gru= (const float*)d_in[2];
  P.mu0  = (const float*)d_in[3];
  P.var0 = (const float*)d_in[4];
  P.h0   = (const float*)d_in[5];
  P.tW1  = (const float*)d_in[6];
  P.tb1  = (const float*)d_in[7];
  P.tg1  = (const float*)d_in[8];
  P.tbe1 = (const float*)d_in[9];
  P.tW2  = (const float*)d_in[10];
  P.tb2  = (const float*)d_in[11];
  P.tg2  = (const float*)d_in[12];
  P.tbe2 = (const float*)d_in[13];
  P.tWm  = (const float*)d_in[14];
  P.tbm  = (const float*)d_in[15];
  P.tWs  = (const float*)d_in[16];
  P.tbs  = (const float*)d_in[17];
  P.tgs  = (const float*)d_in[18];
  P.tbes = (const float*)d_in[19];
  P.eW1  = (const float*)d_in[20];
  P.eb1  = (const float*)d_in[21];
  P.eg1  = (const float*)d_in[22];
  P.ebe1 = (const float*)d_in[23];
  P.eWm  = (const float*)d_in[24];
  P.ebm  = (const float*)d_in[25];
  P.eWs  = (const float*)d_in[26];
  P.ebs  = (const float*)d_in[27];

  float* ws = (float*)d_ws;
  P.out   = (float*)d_out;
  P.psf   = ws + O_PS;
  P.a1f   = ws + O_A1;
  P.a2f   = ws + O_A2;
  P.e1f   = ws + O_E1;
  P.pa1   = ws + O_PA1;
  P.pa2   = ws + O_PA2;
  P.paS   = ws + O_PAS;
  P.paE   = ws + O_PAE;
  P.pisA  = (int*)(ws + O_PIS);
  P.zh    = ws + O_ZH;
  P.ze    = ws + O_ZE;
  P.U     = (ushort_t*)(ws + O_USH);

  for (int t = 1; t < NT; ++t) {
    uint32_t kt0, kt1, a, b;
    tf2x32_h(0u, 42u, 0u, (uint32_t)t, kt0, kt1);
    tf2x32_h(kt0, kt1, 0u, 1u, a, b);
    P.zk2[2 * (t - 1)] = a; P.zk2[2 * (t - 1) + 1] = b;
    tf2x32_h(kt0, kt1, 0u, 2u, a, b);
    P.zk3[2 * (t - 1)] = a; P.zk3[2 * (t - 1) + 1] = b;
  }

  k_init<<<EWB + NB, 256, 0, stream>>>(P);

  // t = 0: G1(1) from h0, then G2(1)
  k_B<1, 0><<<256, 256, 0, stream>>>(P, 0);
  k_C<1, 0><<<256, 256, 0, stream>>>(P, 0);

  for (int t = 1; t < NT; ++t) {
    k_A<<<448, 256, 0, stream>>>(P, t);      // 256 G3 + 192 z-gen(slot t-1)
    if (t < NT - 1) {
      k_B<1, 1><<<256, 256, 0, stream>>>(P, t);
      k_C<1, 1><<<384, 256, 0, stream>>>(P, t);
    } else {
      k_B<0, 1><<<256, 256, 0, stream>>>(P, t);
      k_C<0, 1><<<128, 256, 0, stream>>>(P, t);
    }
  }
}